// Round 1
// baseline (2173.607 us; speedup 1.0000x reference)
//
#include <hip/hip_runtime.h>
#include <math.h>

// Problem constants (match reference setup_inputs()).
#define NG   256        // graphs
#define NP   256        // nodes per graph
#define NN   65536      // total nodes
#define NE   1048576    // edges
#define EPG  4096       // edges per graph (contiguous, src/dst within graph)
#define INF  16         // input feats
#define HID  64         // hidden
#define ZD   128        // latent dim
#define KFLAT 16384     // NP*HID

// ---------------------------------------------------------------- degree ----
__global__ __launch_bounds__(256) void k_deg_count(const int* __restrict__ src,
                                                   const int* __restrict__ dst,
                                                   int* __restrict__ cs,
                                                   int* __restrict__ cd) {
    int e = blockIdx.x * 256 + threadIdx.x;
    atomicAdd(&cs[src[e]], 1);
    atomicAdd(&cd[dst[e]], 1);
}

__global__ __launch_bounds__(256) void k_norms(const int* __restrict__ cs,
                                               const int* __restrict__ cd,
                                               float* __restrict__ ns,
                                               float* __restrict__ nd) {
    int i = blockIdx.x * 256 + threadIdx.x;
    ns[i] = 1.0f / sqrtf((float)max(cs[i], 1));
    nd[i] = 1.0f / sqrtf((float)max(cd[i], 1));
}

// ------------------------------------------------------- per-graph scatter ----
// y[dst] = sum over edges of x[src]*ns[src], then *nd (optionally +bias, relu).
// One block per graph; accumulate in LDS (ds_add_f32), 2 feature halves of 32
// to stay <=64KB LDS. mode 0: y = acc*nd ; mode 1: y = relu(acc*nd + bias).
__global__ __launch_bounds__(512) void k_scatter64(const float* __restrict__ x,
                                                   const int* __restrict__ src,
                                                   const int* __restrict__ dst,
                                                   const float* __restrict__ ns,
                                                   const float* __restrict__ nd,
                                                   const float* __restrict__ bias,
                                                   int mode,
                                                   float* __restrict__ y) {
    __shared__ float  acc[NP * 33];   // 33-stride: bank spread for atomics
    __shared__ uchar2 eds[EPG];       // (src_local, dst_local)
    __shared__ float  nsl[NP], ndl[NP];
    const int g = blockIdx.x, t = threadIdx.x;
    const int base_e = g * EPG, base_n = g * NP;

    for (int i = t; i < EPG; i += 512)
        eds[i] = make_uchar2((unsigned char)(src[base_e + i] & 255),
                             (unsigned char)(dst[base_e + i] & 255));
    for (int i = t; i < NP; i += 512) { nsl[i] = ns[base_n + i]; ndl[i] = nd[base_n + i]; }

    const int e0 = t >> 3, l8 = t & 7;
    for (int h = 0; h < 2; ++h) {
        for (int i = t; i < NP * 33; i += 512) acc[i] = 0.f;
        __syncthreads();
        const int cbase = h * 32 + l8 * 4;
        for (int it = 0; it < 64; ++it) {
            uchar2 sd = eds[it * 64 + e0];
            const float4 v = *(const float4*)&x[(base_n + (int)sd.x) * HID + cbase];
            float sc = nsl[sd.x];
            float* a = &acc[(int)sd.y * 33 + l8 * 4];
            atomicAdd(&a[0], v.x * sc);
            atomicAdd(&a[1], v.y * sc);
            atomicAdd(&a[2], v.z * sc);
            atomicAdd(&a[3], v.w * sc);
        }
        __syncthreads();
        for (int idx = t; idx < NP * 32; idx += 512) {
            int i = idx >> 5, f = idx & 31;
            float v = acc[i * 33 + f] * ndl[i];
            if (mode) v = fmaxf(v + bias[h * 32 + f], 0.f);
            y[(base_n + i) * HID + h * 32 + f] = v;
        }
        __syncthreads();
    }
}

// 16-wide variant for conv1 input (raw). Always mode 0 (y = acc*nd).
__global__ __launch_bounds__(512) void k_scatter16(const float* __restrict__ x,
                                                   const int* __restrict__ src,
                                                   const int* __restrict__ dst,
                                                   const float* __restrict__ ns,
                                                   const float* __restrict__ nd,
                                                   float* __restrict__ y) {
    __shared__ float  acc[NP * 17];
    __shared__ uchar2 eds[EPG];
    __shared__ float  nsl[NP], ndl[NP];
    const int g = blockIdx.x, t = threadIdx.x;
    const int base_e = g * EPG, base_n = g * NP;

    for (int i = t; i < EPG; i += 512)
        eds[i] = make_uchar2((unsigned char)(src[base_e + i] & 255),
                             (unsigned char)(dst[base_e + i] & 255));
    for (int i = t; i < NP; i += 512) { nsl[i] = ns[base_n + i]; ndl[i] = nd[base_n + i]; }
    for (int i = t; i < NP * 17; i += 512) acc[i] = 0.f;
    __syncthreads();

    const int e0 = t >> 2, l4 = t & 3;
    for (int it = 0; it < 32; ++it) {
        uchar2 sd = eds[it * 128 + e0];
        const float4 v = *(const float4*)&x[(base_n + (int)sd.x) * INF + l4 * 4];
        float sc = nsl[sd.x];
        float* a = &acc[(int)sd.y * 17 + l4 * 4];
        atomicAdd(&a[0], v.x * sc);
        atomicAdd(&a[1], v.y * sc);
        atomicAdd(&a[2], v.z * sc);
        atomicAdd(&a[3], v.w * sc);
    }
    __syncthreads();
    for (int idx = t; idx < NP * INF; idx += 512) {
        int i = idx >> 4, f = idx & 15;
        y[(base_n + i) * INF + f] = acc[i * 17 + f] * ndl[i];
    }
}

// -------------------------------------------------- tiled node GEMM (->64) ----
// y[N,64] = act( concat(x0..x3)[N, w0+..+w3] @ W + bias ).  64-node tiles,
// X^T staged in LDS (stride 68: conflict-free b128), W chunk in LDS.
template<bool RELU>
__global__ __launch_bounds__(256) void k_gemm64(const float* __restrict__ x0, int w0,
                                                const float* __restrict__ x1, int w1,
                                                const float* __restrict__ x2, int w2,
                                                const float* __restrict__ x3, int w3,
                                                const float* __restrict__ W,
                                                const float* __restrict__ bias,
                                                float* __restrict__ y) {
    __shared__ float XT[64 * 68];
    __shared__ float WL[64 * 64];
    const int t = threadIdx.x;
    const int g0 = blockIdx.x * 64;
    const int ig = t >> 4, jg = t & 15;
    float acc[4][4] = {};
    const float* xs[4] = {x0, x1, x2, x3};
    const int    ww[4] = {w0, w1, w2, w3};
    int koff = 0;
    for (int p = 0; p < 4; ++p) {
        const int w = ww[p];
        if (w == 0) continue;
        const float* xp = xs[p];
        for (int idx4 = t * 4; idx4 < 64 * w; idx4 += 1024) {
            int r = idx4 / w, c = idx4 % w;
            float4 v = *(const float4*)&xp[(g0 + r) * w + c];
            XT[(c + 0) * 68 + r] = v.x;
            XT[(c + 1) * 68 + r] = v.y;
            XT[(c + 2) * 68 + r] = v.z;
            XT[(c + 3) * 68 + r] = v.w;
        }
        for (int idx4 = t * 4; idx4 < w * 64; idx4 += 1024) {
            int k = idx4 >> 6, j = idx4 & 63;
            *(float4*)&WL[k * 64 + j] = *(const float4*)&W[(koff + k) * 64 + j];
        }
        __syncthreads();
        for (int k = 0; k < w; ++k) {
            float4 a = *(const float4*)&XT[k * 68 + ig * 4];
            float4 b = *(const float4*)&WL[k * 64 + jg * 4];
            float av[4] = {a.x, a.y, a.z, a.w};
            float bv[4] = {b.x, b.y, b.z, b.w};
#pragma unroll
            for (int r = 0; r < 4; ++r)
#pragma unroll
                for (int c = 0; c < 4; ++c) acc[r][c] += av[r] * bv[c];
        }
        __syncthreads();
        koff += w;
    }
    float4 bb = make_float4(0.f, 0.f, 0.f, 0.f);
    if (bias) bb = *(const float4*)&bias[jg * 4];
#pragma unroll
    for (int r = 0; r < 4; ++r) {
        float4 v;
        v.x = acc[r][0] + bb.x; v.y = acc[r][1] + bb.y;
        v.z = acc[r][2] + bb.z; v.w = acc[r][3] + bb.w;
        if (RELU) {
            v.x = fmaxf(v.x, 0.f); v.y = fmaxf(v.y, 0.f);
            v.z = fmaxf(v.z, 0.f); v.w = fmaxf(v.w, 0.f);
        }
        *(float4*)&y[(g0 + ig * 4 + r) * HID + jg * 4] = v;
    }
}

// ----------------------------------------------- mu/logvar split-K GEMM ------
// [256,16384]@[16384,128] for Wmu and Wlv. Grid 512 = 16 m-tiles(16 g) x
// 32 k-chunks(512). Partials -> part[(kc*2+which)*32768 + g*128 + j].
__global__ __launch_bounds__(256) void k_mulv(const float* __restrict__ hflat,
                                              const float* __restrict__ Wmu,
                                              const float* __restrict__ Wlv,
                                              float* __restrict__ part) {
    __shared__ float hT[512 * 17];   // [k][g], stride 17: conflict-free staging
    const int bx = blockIdx.x;
    const int mt = bx >> 5, kc = bx & 31;
    const int t = threadIdx.x;
    for (int idx = t; idx < 16 * 512; idx += 256) {
        int gi = idx >> 9, kl = idx & 511;
        hT[kl * 17 + gi] = hflat[(mt * 16 + gi) * KFLAT + kc * 512 + kl];
    }
    __syncthreads();
    const int which = t >> 7, j4 = (t >> 2) & 31, g4 = t & 3;
    const float* Wsel = which ? Wlv : Wmu;
    const float* wp = &Wsel[(kc * 512) * ZD + j4 * 4];
    float acc[4][4] = {};
    for (int kl = 0; kl < 512; ++kl) {
        float4 b = *(const float4*)&wp[kl * ZD];
        const float* hp = &hT[kl * 17 + g4 * 4];
        float av[4] = {hp[0], hp[1], hp[2], hp[3]};
        float bv[4] = {b.x, b.y, b.z, b.w};
#pragma unroll
        for (int r = 0; r < 4; ++r)
#pragma unroll
            for (int c = 0; c < 4; ++c) acc[r][c] += av[r] * bv[c];
    }
    const int pb = (kc * 2 + which) << 15;
#pragma unroll
    for (int gi = 0; gi < 4; ++gi) {
        int g = mt * 16 + g4 * 4 + gi;
        *(float4*)&part[pb + g * ZD + j4 * 4] =
            make_float4(acc[gi][0], acc[gi][1], acc[gi][2], acc[gi][3]);
    }
}

// reduce partials -> mu, logvar (to d_out) and z (reparameterized) to ws.
__global__ __launch_bounds__(256) void k_reduce(const float* __restrict__ part,
                                                const float* __restrict__ bmu,
                                                const float* __restrict__ blv,
                                                const float* __restrict__ eps,
                                                float* __restrict__ out,
                                                float* __restrict__ z) {
    const int idx = blockIdx.x * 256 + threadIdx.x;  // 32768 = 256*128
    const int j = idx & 127;
    float mu = bmu[j], lv = blv[j];
    for (int kc = 0; kc < 32; ++kc) {
        mu += part[((kc * 2 + 0) << 15) + idx];
        lv += part[((kc * 2 + 1) << 15) + idx];
    }
    out[1048576 + idx] = mu;
    out[1048576 + 32768 + idx] = lv;
    z[idx] = mu + eps[idx] * expf(0.5f * lv);
}

// --------------------------------------------- latent = z @ Wdec + bdec ------
// [256,128]@[128,16384]. Grid 512 = 8 g-tiles(32) x 64 n-tiles(256).
__global__ __launch_bounds__(256) void k_dec(const float* __restrict__ z,
                                             const float* __restrict__ Wdec,
                                             const float* __restrict__ bdec,
                                             float* __restrict__ latent) {
    __shared__ float zT[ZD * 36];   // [k][g], stride 36: aligned b128, spread banks
    const int bx = blockIdx.x;
    const int gt = bx >> 6, nt = bx & 63;
    const int t = threadIdx.x;
    for (int idx = t; idx < 32 * ZD; idx += 256) {
        int gi = idx >> 7, k = idx & 127;
        zT[k * 36 + gi] = z[(gt * 32 + gi) * ZD + k];
    }
    __syncthreads();
    const int g4 = t >> 5, n8 = t & 31;
    const int n0 = nt * 256 + n8 * 8;
    float acc[4][8] = {};
    for (int k = 0; k < ZD; ++k) {
        float4 a = *(const float4*)&zT[k * 36 + g4 * 4];
        float4 b0 = *(const float4*)&Wdec[k * KFLAT + n0];
        float4 b1 = *(const float4*)&Wdec[k * KFLAT + n0 + 4];
        float av[4] = {a.x, a.y, a.z, a.w};
        float bv[8] = {b0.x, b0.y, b0.z, b0.w, b1.x, b1.y, b1.z, b1.w};
#pragma unroll
        for (int r = 0; r < 4; ++r)
#pragma unroll
            for (int c = 0; c < 8; ++c) acc[r][c] += av[r] * bv[c];
    }
    float4 bd0 = *(const float4*)&bdec[n0];
    float4 bd1 = *(const float4*)&bdec[n0 + 4];
#pragma unroll
    for (int r = 0; r < 4; ++r) {
        int g = gt * 32 + g4 * 4 + r;
        float4 v0 = make_float4(acc[r][0] + bd0.x, acc[r][1] + bd0.y,
                                acc[r][2] + bd0.z, acc[r][3] + bd0.w);
        float4 v1 = make_float4(acc[r][4] + bd1.x, acc[r][5] + bd1.y,
                                acc[r][6] + bd1.z, acc[r][7] + bd1.w);
        *(float4*)&latent[g * KFLAT + n0]     = v0;
        *(float4*)&latent[g * KFLAT + n0 + 4] = v1;
    }
}

// -------------------------------------------- recon = x@Wout + bout ----------
// 64->16, col 0 overridden with raw[:,0].
__global__ __launch_bounds__(256) void k_gemmout(const float* __restrict__ x,
                                                 const float* __restrict__ W,
                                                 const float* __restrict__ bias,
                                                 const float* __restrict__ raw,
                                                 float* __restrict__ out) {
    __shared__ float XT[64 * 68];
    __shared__ float WL[64 * 16];
    const int t = threadIdx.x, g0 = blockIdx.x * 64;
    for (int idx4 = t * 4; idx4 < 64 * 64; idx4 += 1024) {
        int r = idx4 >> 6, c = idx4 & 63;
        float4 v = *(const float4*)&x[(g0 + r) * 64 + c];
        XT[(c + 0) * 68 + r] = v.x;
        XT[(c + 1) * 68 + r] = v.y;
        XT[(c + 2) * 68 + r] = v.z;
        XT[(c + 3) * 68 + r] = v.w;
    }
    {
        int idx4 = t * 4;  // 1024 floats total, one pass
        int k = idx4 >> 4, j = idx4 & 15;
        *(float4*)&WL[k * 16 + j] = *(const float4*)&W[k * 16 + j];
    }
    __syncthreads();
    const int i = t & 63, jg = t >> 6;
    float acc[4] = {};
    for (int k = 0; k < 64; ++k) {
        float a = XT[k * 68 + i];
        float4 b = *(const float4*)&WL[k * 16 + jg * 4];
        acc[0] += a * b.x; acc[1] += a * b.y;
        acc[2] += a * b.z; acc[3] += a * b.w;
    }
    float4 bb = *(const float4*)&bias[jg * 4];
    float4 v = make_float4(acc[0] + bb.x, acc[1] + bb.y, acc[2] + bb.z, acc[3] + bb.w);
    if (jg == 0) v.x = raw[(g0 + i) * INF];   // recon[:, :1] = raw[:, :1]
    *(float4*)&out[(g0 + i) * INF + jg * 4] = v;
}

// ----------------------------------------------------------------- launch ----
extern "C" void kernel_launch(void* const* d_in, const int* in_sizes, int n_in,
                              void* d_out, int out_size, void* d_ws, size_t ws_size,
                              hipStream_t stream) {
    const float* raw  = (const float*)d_in[0];
    const int*   src  = (const int*)d_in[1];
    const int*   dst  = (const int*)d_in[2];
    const float* eps  = (const float*)d_in[3];
    const float* W1   = (const float*)d_in[4];
    const float* b1   = (const float*)d_in[5];
    const float* W2   = (const float*)d_in[6];
    const float* b2   = (const float*)d_in[7];
    const float* W3   = (const float*)d_in[8];
    const float* b3   = (const float*)d_in[9];
    const float* W4   = (const float*)d_in[10];
    const float* b4   = (const float*)d_in[11];
    const float* Wmu  = (const float*)d_in[12];
    const float* bmu  = (const float*)d_in[13];
    const float* Wlv  = (const float*)d_in[14];
    const float* blv  = (const float*)d_in[15];
    const float* Wdec = (const float*)d_in[16];
    const float* bdec = (const float*)d_in[17];
    const float* Wg1  = (const float*)d_in[18];
    const float* bg1  = (const float*)d_in[19];
    const float* Wg2  = (const float*)d_in[20];
    const float* bg2  = (const float*)d_in[21];
    const float* Wout = (const float*)d_in[22];
    const float* bout = (const float*)d_in[23];
    float* out = (float*)d_out;

    // ws layout (floats): ns | nd | agg(N*64, also deg-counts + mu/lv partials)
    //                     | h1 | h2 | h3 | h4(also latent) | z
    float* ws  = (float*)d_ws;
    float* ns  = ws;
    float* nd  = ws + NN;
    float* agg = ws + 2 * NN;
    float* h1  = agg + NN * HID;
    float* h2  = h1 + NN * HID;
    float* h3  = h2 + NN * HID;
    float* h4  = h3 + NN * HID;
    float* z   = h4 + NN * HID;   // 32768 floats

    // degrees -> norms
    int* cs = (int*)agg;
    int* cd = cs + NN;
    hipMemsetAsync(cs, 0, 2 * NN * sizeof(int), stream);
    k_deg_count<<<NE / 256, 256, 0, stream>>>(src, dst, cs, cd);
    k_norms<<<NN / 256, 256, 0, stream>>>(cs, cd, ns, nd);

    // conv1: scatter raw (16) -> agg ; h1 = relu(agg@W1 + b1)
    k_scatter16<<<NG, 512, 0, stream>>>(raw, src, dst, ns, nd, agg);
    k_gemm64<true><<<NN / 64, 256, 0, stream>>>(agg, 16, nullptr, 0, nullptr, 0, nullptr, 0,
                                                W1, b1, h1);
    // conv2..4
    k_scatter64<<<NG, 512, 0, stream>>>(h1, src, dst, ns, nd, nullptr, 0, agg);
    k_gemm64<true><<<NN / 64, 256, 0, stream>>>(agg, 64, nullptr, 0, nullptr, 0, nullptr, 0,
                                                W2, b2, h2);
    k_scatter64<<<NG, 512, 0, stream>>>(h2, src, dst, ns, nd, nullptr, 0, agg);
    k_gemm64<true><<<NN / 64, 256, 0, stream>>>(agg, 64, nullptr, 0, nullptr, 0, nullptr, 0,
                                                W3, b3, h3);
    k_scatter64<<<NG, 512, 0, stream>>>(h3, src, dst, ns, nd, nullptr, 0, agg);
    k_gemm64<true><<<NN / 64, 256, 0, stream>>>(agg, 64, nullptr, 0, nullptr, 0, nullptr, 0,
                                                W4, b4, h4);

    // mu/logvar (partials live in agg), then z; latent overwrites h4
    k_mulv<<<512, 256, 0, stream>>>(h4, Wmu, Wlv, agg);
    k_reduce<<<128, 256, 0, stream>>>(agg, bmu, blv, eps, out, z);
    k_dec<<<512, 256, 0, stream>>>(z, Wdec, bdec, h4);

    // g1: t = [latent|raw|h1|h3] @ Wg1 (no bias) -> h2 ;
    //     x1 = relu(scatter(t)*nd + bg1) -> agg
    k_gemm64<false><<<NN / 64, 256, 0, stream>>>(h4, 64, raw, 16, h1, 64, h3, 64,
                                                 Wg1, nullptr, h2);
    k_scatter64<<<NG, 512, 0, stream>>>(h2, src, dst, ns, nd, bg1, 1, agg);

    // g2: scatter x1 -> h2 ; x2 = relu(h2@Wg2 + bg2) -> h3
    k_scatter64<<<NG, 512, 0, stream>>>(agg, src, dst, ns, nd, nullptr, 0, h2);
    k_gemm64<true><<<NN / 64, 256, 0, stream>>>(h2, 64, nullptr, 0, nullptr, 0, nullptr, 0,
                                                Wg2, bg2, h3);

    // recon
    k_gemmout<<<NN / 64, 256, 0, stream>>>(h3, Wout, bout, raw, out);
}

// Round 2
// 551.073 us; speedup vs baseline: 3.9443x; 3.9443x over previous
//
#include <hip/hip_runtime.h>
#include <math.h>

// Problem constants (match reference setup_inputs()).
#define NG   256        // graphs
#define NP   256        // nodes per graph
#define NN   65536      // total nodes
#define NE   1048576    // edges
#define EPG  4096       // edges per graph (contiguous, src/dst within graph)
#define INF  16         // input feats
#define HID  64         // hidden
#define ZD   128        // latent dim
#define KFLAT 16384     // NP*HID

// ---------------------------------------------------------------- degree ----
__global__ __launch_bounds__(256) void k_deg_count(const int* __restrict__ src,
                                                   const int* __restrict__ dst,
                                                   int* __restrict__ cs,
                                                   int* __restrict__ cd) {
    int e = blockIdx.x * 256 + threadIdx.x;
    atomicAdd(&cs[src[e]], 1);
    atomicAdd(&cd[dst[e]], 1);
}

__global__ __launch_bounds__(256) void k_norms(const int* __restrict__ cs,
                                               const int* __restrict__ cd,
                                               float* __restrict__ ns,
                                               float* __restrict__ nd) {
    int i = blockIdx.x * 256 + threadIdx.x;
    ns[i] = 1.0f / sqrtf((float)max(cs[i], 1));
    nd[i] = 1.0f / sqrtf((float)max(cd[i], 1));
}

// -------------------------------------------------------------- CSR build ----
// rp[n] = exclusive scan of in-degree within each graph (+ g*EPG base).
__global__ __launch_bounds__(256) void k_scan(const int* __restrict__ cd,
                                              int* __restrict__ rp) {
    __shared__ int buf[NP];
    const int g = blockIdx.x, t = threadIdx.x;
    const int v0 = cd[g * NP + t];
    buf[t] = v0;
    __syncthreads();
    for (int off = 1; off < NP; off <<= 1) {
        int v = (t >= off) ? buf[t - off] : 0;
        __syncthreads();
        buf[t] += v;
        __syncthreads();
    }
    rp[g * NP + t] = g * EPG + buf[t] - v0;   // exclusive
    if (g == NG - 1 && t == NP - 1) rp[NN] = NE;
}

// cols8[rp[dst]+k] = local src index (dst-sorted edge list), one block/graph.
__global__ __launch_bounds__(256) void k_csr_fill(const int* __restrict__ src,
                                                  const int* __restrict__ dst,
                                                  const int* __restrict__ rp,
                                                  unsigned char* __restrict__ cols8) {
    __shared__ int cnt[NP];
    const int g = blockIdx.x, t = threadIdx.x;
    cnt[t] = 0;
    __syncthreads();
    const int base_e = g * EPG;
    for (int i = t; i < EPG; i += 256) {
        int s = src[base_e + i], d = dst[base_e + i];
        int p = atomicAdd(&cnt[d & (NP - 1)], 1);
        cols8[rp[d] + p] = (unsigned char)(s & (NP - 1));
    }
}

// ------------------------------------------------------------ CSR gathers ----
// y[n,f] = nd[n] * sum_{e in in(n)} ns[src_e] * x[src_e, f]
// 64-wide: 16 threads per node (float4 each). mode 1: +bias, relu.
__global__ __launch_bounds__(256) void k_gather64(const float* __restrict__ x,
                                                  const int* __restrict__ rp,
                                                  const unsigned char* __restrict__ cols8,
                                                  const float* __restrict__ ns,
                                                  const float* __restrict__ nd,
                                                  const float* __restrict__ bias,
                                                  int mode,
                                                  float* __restrict__ y) {
    const int idx = blockIdx.x * 256 + threadIdx.x;
    const int n = idx >> 4, f = (idx & 15) * 4;
    const int base_n = n & ~(NP - 1);
    int e = rp[n];
    const int end = rp[n + 1];
    float4 acc = make_float4(0.f, 0.f, 0.f, 0.f);
    for (; e + 1 < end; e += 2) {
        int s0 = base_n + cols8[e], s1 = base_n + cols8[e + 1];
        float w0 = ns[s0], w1 = ns[s1];
        float4 v0 = *(const float4*)&x[s0 * HID + f];
        float4 v1 = *(const float4*)&x[s1 * HID + f];
        acc.x += v0.x * w0 + v1.x * w1;
        acc.y += v0.y * w0 + v1.y * w1;
        acc.z += v0.z * w0 + v1.z * w1;
        acc.w += v0.w * w0 + v1.w * w1;
    }
    if (e < end) {
        int s0 = base_n + cols8[e];
        float w0 = ns[s0];
        float4 v0 = *(const float4*)&x[s0 * HID + f];
        acc.x += v0.x * w0; acc.y += v0.y * w0;
        acc.z += v0.z * w0; acc.w += v0.w * w0;
    }
    const float sc = nd[n];
    float4 v = make_float4(acc.x * sc, acc.y * sc, acc.z * sc, acc.w * sc);
    if (mode) {
        float4 bb = *(const float4*)&bias[f];
        v.x = fmaxf(v.x + bb.x, 0.f);
        v.y = fmaxf(v.y + bb.y, 0.f);
        v.z = fmaxf(v.z + bb.z, 0.f);
        v.w = fmaxf(v.w + bb.w, 0.f);
    }
    *(float4*)&y[n * HID + f] = v;
}

// 16-wide: 4 threads per node, for conv1 input (raw).
__global__ __launch_bounds__(256) void k_gather16(const float* __restrict__ x,
                                                  const int* __restrict__ rp,
                                                  const unsigned char* __restrict__ cols8,
                                                  const float* __restrict__ ns,
                                                  const float* __restrict__ nd,
                                                  float* __restrict__ y) {
    const int idx = blockIdx.x * 256 + threadIdx.x;
    const int n = idx >> 2, f = (idx & 3) * 4;
    const int base_n = n & ~(NP - 1);
    int e = rp[n];
    const int end = rp[n + 1];
    float4 acc = make_float4(0.f, 0.f, 0.f, 0.f);
    for (; e + 1 < end; e += 2) {
        int s0 = base_n + cols8[e], s1 = base_n + cols8[e + 1];
        float w0 = ns[s0], w1 = ns[s1];
        float4 v0 = *(const float4*)&x[s0 * INF + f];
        float4 v1 = *(const float4*)&x[s1 * INF + f];
        acc.x += v0.x * w0 + v1.x * w1;
        acc.y += v0.y * w0 + v1.y * w1;
        acc.z += v0.z * w0 + v1.z * w1;
        acc.w += v0.w * w0 + v1.w * w1;
    }
    if (e < end) {
        int s0 = base_n + cols8[e];
        float w0 = ns[s0];
        float4 v0 = *(const float4*)&x[s0 * INF + f];
        acc.x += v0.x * w0; acc.y += v0.y * w0;
        acc.z += v0.z * w0; acc.w += v0.w * w0;
    }
    const float sc = nd[n];
    y[n * INF + f + 0] = acc.x * sc;
    y[n * INF + f + 1] = acc.y * sc;
    y[n * INF + f + 2] = acc.z * sc;
    y[n * INF + f + 3] = acc.w * sc;
}

// -------------------------------------------------- tiled node GEMM (->64) ----
// y[N,64] = act( concat(x0..x3)[N, w0+..+w3] @ W + bias ).  64-node tiles,
// X^T staged in LDS (stride 68: conflict-free b128), W chunk in LDS.
template<bool RELU>
__global__ __launch_bounds__(256) void k_gemm64(const float* __restrict__ x0, int w0,
                                                const float* __restrict__ x1, int w1,
                                                const float* __restrict__ x2, int w2,
                                                const float* __restrict__ x3, int w3,
                                                const float* __restrict__ W,
                                                const float* __restrict__ bias,
                                                float* __restrict__ y) {
    __shared__ float XT[64 * 68];
    __shared__ float WL[64 * 64];
    const int t = threadIdx.x;
    const int g0 = blockIdx.x * 64;
    const int ig = t >> 4, jg = t & 15;
    float acc[4][4] = {};
    const float* xs[4] = {x0, x1, x2, x3};
    const int    ww[4] = {w0, w1, w2, w3};
    int koff = 0;
    for (int p = 0; p < 4; ++p) {
        const int w = ww[p];
        if (w == 0) continue;
        const float* xp = xs[p];
        for (int idx4 = t * 4; idx4 < 64 * w; idx4 += 1024) {
            int r = idx4 / w, c = idx4 % w;
            float4 v = *(const float4*)&xp[(g0 + r) * w + c];
            XT[(c + 0) * 68 + r] = v.x;
            XT[(c + 1) * 68 + r] = v.y;
            XT[(c + 2) * 68 + r] = v.z;
            XT[(c + 3) * 68 + r] = v.w;
        }
        for (int idx4 = t * 4; idx4 < w * 64; idx4 += 1024) {
            int k = idx4 >> 6, j = idx4 & 63;
            *(float4*)&WL[k * 64 + j] = *(const float4*)&W[(koff + k) * 64 + j];
        }
        __syncthreads();
        for (int k = 0; k < w; ++k) {
            float4 a = *(const float4*)&XT[k * 68 + ig * 4];
            float4 b = *(const float4*)&WL[k * 64 + jg * 4];
            float av[4] = {a.x, a.y, a.z, a.w};
            float bv[4] = {b.x, b.y, b.z, b.w};
#pragma unroll
            for (int r = 0; r < 4; ++r)
#pragma unroll
                for (int c = 0; c < 4; ++c) acc[r][c] += av[r] * bv[c];
        }
        __syncthreads();
        koff += w;
    }
    float4 bb = make_float4(0.f, 0.f, 0.f, 0.f);
    if (bias) bb = *(const float4*)&bias[jg * 4];
#pragma unroll
    for (int r = 0; r < 4; ++r) {
        float4 v;
        v.x = acc[r][0] + bb.x; v.y = acc[r][1] + bb.y;
        v.z = acc[r][2] + bb.z; v.w = acc[r][3] + bb.w;
        if (RELU) {
            v.x = fmaxf(v.x, 0.f); v.y = fmaxf(v.y, 0.f);
            v.z = fmaxf(v.z, 0.f); v.w = fmaxf(v.w, 0.f);
        }
        *(float4*)&y[(g0 + ig * 4 + r) * HID + jg * 4] = v;
    }
}

// ----------------------------------------------- mu/logvar split-K GEMM ------
// [256,16384]@[16384,128] for Wmu and Wlv. Grid 512 = 16 m-tiles(16 g) x
// 32 k-chunks(512). Partials -> part[(kc*2+which)*32768 + g*128 + j].
__global__ __launch_bounds__(256) void k_mulv(const float* __restrict__ hflat,
                                              const float* __restrict__ Wmu,
                                              const float* __restrict__ Wlv,
                                              float* __restrict__ part) {
    __shared__ float hT[512 * 17];   // [k][g], stride 17: conflict-free staging
    const int bx = blockIdx.x;
    const int mt = bx >> 5, kc = bx & 31;
    const int t = threadIdx.x;
    for (int idx = t; idx < 16 * 512; idx += 256) {
        int gi = idx >> 9, kl = idx & 511;
        hT[kl * 17 + gi] = hflat[(mt * 16 + gi) * KFLAT + kc * 512 + kl];
    }
    __syncthreads();
    const int which = t >> 7, j4 = (t >> 2) & 31, g4 = t & 3;
    const float* Wsel = which ? Wlv : Wmu;
    const float* wp = &Wsel[(kc * 512) * ZD + j4 * 4];
    float acc[4][4] = {};
    for (int kl = 0; kl < 512; ++kl) {
        float4 b = *(const float4*)&wp[kl * ZD];
        const float* hp = &hT[kl * 17 + g4 * 4];
        float av[4] = {hp[0], hp[1], hp[2], hp[3]};
        float bv[4] = {b.x, b.y, b.z, b.w};
#pragma unroll
        for (int r = 0; r < 4; ++r)
#pragma unroll
            for (int c = 0; c < 4; ++c) acc[r][c] += av[r] * bv[c];
    }
    const int pb = (kc * 2 + which) << 15;
#pragma unroll
    for (int gi = 0; gi < 4; ++gi) {
        int g = mt * 16 + g4 * 4 + gi;
        *(float4*)&part[pb + g * ZD + j4 * 4] =
            make_float4(acc[gi][0], acc[gi][1], acc[gi][2], acc[gi][3]);
    }
}

// reduce partials -> mu, logvar (to d_out) and z (reparameterized) to ws.
__global__ __launch_bounds__(256) void k_reduce(const float* __restrict__ part,
                                                const float* __restrict__ bmu,
                                                const float* __restrict__ blv,
                                                const float* __restrict__ eps,
                                                float* __restrict__ out,
                                                float* __restrict__ z) {
    const int idx = blockIdx.x * 256 + threadIdx.x;  // 32768 = 256*128
    const int j = idx & 127;
    float mu = bmu[j], lv = blv[j];
    for (int kc = 0; kc < 32; ++kc) {
        mu += part[((kc * 2 + 0) << 15) + idx];
        lv += part[((kc * 2 + 1) << 15) + idx];
    }
    out[1048576 + idx] = mu;
    out[1048576 + 32768 + idx] = lv;
    z[idx] = mu + eps[idx] * expf(0.5f * lv);
}

// --------------------------------------------- latent = z @ Wdec + bdec ------
// [256,128]@[128,16384]. Grid 512 = 8 g-tiles(32) x 64 n-tiles(256).
__global__ __launch_bounds__(256) void k_dec(const float* __restrict__ z,
                                             const float* __restrict__ Wdec,
                                             const float* __restrict__ bdec,
                                             float* __restrict__ latent) {
    __shared__ float zT[ZD * 36];   // [k][g], stride 36: aligned b128, spread banks
    const int bx = blockIdx.x;
    const int gt = bx >> 6, nt = bx & 63;
    const int t = threadIdx.x;
    for (int idx = t; idx < 32 * ZD; idx += 256) {
        int gi = idx >> 7, k = idx & 127;
        zT[k * 36 + gi] = z[(gt * 32 + gi) * ZD + k];
    }
    __syncthreads();
    const int g4 = t >> 5, n8 = t & 31;
    const int n0 = nt * 256 + n8 * 8;
    float acc[4][8] = {};
    for (int k = 0; k < ZD; ++k) {
        float4 a = *(const float4*)&zT[k * 36 + g4 * 4];
        float4 b0 = *(const float4*)&Wdec[k * KFLAT + n0];
        float4 b1 = *(const float4*)&Wdec[k * KFLAT + n0 + 4];
        float av[4] = {a.x, a.y, a.z, a.w};
        float bv[8] = {b0.x, b0.y, b0.z, b0.w, b1.x, b1.y, b1.z, b1.w};
#pragma unroll
        for (int r = 0; r < 4; ++r)
#pragma unroll
            for (int c = 0; c < 8; ++c) acc[r][c] += av[r] * bv[c];
    }
    float4 bd0 = *(const float4*)&bdec[n0];
    float4 bd1 = *(const float4*)&bdec[n0 + 4];
#pragma unroll
    for (int r = 0; r < 4; ++r) {
        int g = gt * 32 + g4 * 4 + r;
        float4 v0 = make_float4(acc[r][0] + bd0.x, acc[r][1] + bd0.y,
                                acc[r][2] + bd0.z, acc[r][3] + bd0.w);
        float4 v1 = make_float4(acc[r][4] + bd1.x, acc[r][5] + bd1.y,
                                acc[r][6] + bd1.z, acc[r][7] + bd1.w);
        *(float4*)&latent[g * KFLAT + n0]     = v0;
        *(float4*)&latent[g * KFLAT + n0 + 4] = v1;
    }
}

// -------------------------------------------- recon = x@Wout + bout ----------
// 64->16, col 0 overridden with raw[:,0].
__global__ __launch_bounds__(256) void k_gemmout(const float* __restrict__ x,
                                                 const float* __restrict__ W,
                                                 const float* __restrict__ bias,
                                                 const float* __restrict__ raw,
                                                 float* __restrict__ out) {
    __shared__ float XT[64 * 68];
    __shared__ float WL[64 * 16];
    const int t = threadIdx.x, g0 = blockIdx.x * 64;
    for (int idx4 = t * 4; idx4 < 64 * 64; idx4 += 1024) {
        int r = idx4 >> 6, c = idx4 & 63;
        float4 v = *(const float4*)&x[(g0 + r) * 64 + c];
        XT[(c + 0) * 68 + r] = v.x;
        XT[(c + 1) * 68 + r] = v.y;
        XT[(c + 2) * 68 + r] = v.z;
        XT[(c + 3) * 68 + r] = v.w;
    }
    {
        int idx4 = t * 4;  // 1024 floats total, one pass
        int k = idx4 >> 4, j = idx4 & 15;
        *(float4*)&WL[k * 16 + j] = *(const float4*)&W[k * 16 + j];
    }
    __syncthreads();
    const int i = t & 63, jg = t >> 6;
    float acc[4] = {};
    for (int k = 0; k < 64; ++k) {
        float a = XT[k * 68 + i];
        float4 b = *(const float4*)&WL[k * 16 + jg * 4];
        acc[0] += a * b.x; acc[1] += a * b.y;
        acc[2] += a * b.z; acc[3] += a * b.w;
    }
    float4 bb = *(const float4*)&bias[jg * 4];
    float4 v = make_float4(acc[0] + bb.x, acc[1] + bb.y, acc[2] + bb.z, acc[3] + bb.w);
    if (jg == 0) v.x = raw[(g0 + i) * INF];   // recon[:, :1] = raw[:, :1]
    *(float4*)&out[(g0 + i) * INF + jg * 4] = v;
}

// ----------------------------------------------------------------- launch ----
extern "C" void kernel_launch(void* const* d_in, const int* in_sizes, int n_in,
                              void* d_out, int out_size, void* d_ws, size_t ws_size,
                              hipStream_t stream) {
    const float* raw  = (const float*)d_in[0];
    const int*   src  = (const int*)d_in[1];
    const int*   dst  = (const int*)d_in[2];
    const float* eps  = (const float*)d_in[3];
    const float* W1   = (const float*)d_in[4];
    const float* b1   = (const float*)d_in[5];
    const float* W2   = (const float*)d_in[6];
    const float* b2   = (const float*)d_in[7];
    const float* W3   = (const float*)d_in[8];
    const float* b3   = (const float*)d_in[9];
    const float* W4   = (const float*)d_in[10];
    const float* b4   = (const float*)d_in[11];
    const float* Wmu  = (const float*)d_in[12];
    const float* bmu  = (const float*)d_in[13];
    const float* Wlv  = (const float*)d_in[14];
    const float* blv  = (const float*)d_in[15];
    const float* Wdec = (const float*)d_in[16];
    const float* bdec = (const float*)d_in[17];
    const float* Wg1  = (const float*)d_in[18];
    const float* bg1  = (const float*)d_in[19];
    const float* Wg2  = (const float*)d_in[20];
    const float* bg2  = (const float*)d_in[21];
    const float* Wout = (const float*)d_in[22];
    const float* bout = (const float*)d_in[23];
    float* out = (float*)d_out;

    // ws layout (floats): ns | nd | rp | cols8 | agg | h1 | h2 | h3 | h4
    // agg doubles as: cs/cd (deg ints) before CSR, mu/lv partials after conv4,
    // z at agg+3M during reduce/dec.
    float* ws   = (float*)d_ws;
    float* ns   = ws;
    float* nd   = ns + NN;
    int*   rp   = (int*)(nd + NN);                       // NN+1 ints (pad 65792)
    unsigned char* cols8 = (unsigned char*)(rp + 65792); // NE bytes
    float* agg  = (float*)(cols8 + NE);
    float* h1   = agg + (size_t)NN * HID;
    float* h2   = h1 + (size_t)NN * HID;
    float* h3   = h2 + (size_t)NN * HID;
    float* h4   = h3 + (size_t)NN * HID;
    float* z    = agg + 3 * 1024 * 1024;                 // 32768 floats, free region

    // degrees -> norms -> CSR (once per launch; src/dst identical every call)
    int* cs = (int*)agg;
    int* cd = cs + NN;
    hipMemsetAsync(cs, 0, 2 * NN * sizeof(int), stream);
    k_deg_count<<<NE / 256, 256, 0, stream>>>(src, dst, cs, cd);
    k_norms<<<NN / 256, 256, 0, stream>>>(cs, cd, ns, nd);
    k_scan<<<NG, 256, 0, stream>>>(cd, rp);
    k_csr_fill<<<NG, 256, 0, stream>>>(src, dst, rp, cols8);

    // conv1: gather raw (16) -> agg ; h1 = relu(agg@W1 + b1)
    k_gather16<<<NN * 4 / 256, 256, 0, stream>>>(raw, rp, cols8, ns, nd, agg);
    k_gemm64<true><<<NN / 64, 256, 0, stream>>>(agg, 16, nullptr, 0, nullptr, 0, nullptr, 0,
                                                W1, b1, h1);
    // conv2..4
    k_gather64<<<NN * 16 / 256, 256, 0, stream>>>(h1, rp, cols8, ns, nd, nullptr, 0, agg);
    k_gemm64<true><<<NN / 64, 256, 0, stream>>>(agg, 64, nullptr, 0, nullptr, 0, nullptr, 0,
                                                W2, b2, h2);
    k_gather64<<<NN * 16 / 256, 256, 0, stream>>>(h2, rp, cols8, ns, nd, nullptr, 0, agg);
    k_gemm64<true><<<NN / 64, 256, 0, stream>>>(agg, 64, nullptr, 0, nullptr, 0, nullptr, 0,
                                                W3, b3, h3);
    k_gather64<<<NN * 16 / 256, 256, 0, stream>>>(h3, rp, cols8, ns, nd, nullptr, 0, agg);
    k_gemm64<true><<<NN / 64, 256, 0, stream>>>(agg, 64, nullptr, 0, nullptr, 0, nullptr, 0,
                                                W4, b4, h4);

    // mu/logvar (partials in agg[0..2M)), z at agg+3M; latent overwrites h4
    k_mulv<<<512, 256, 0, stream>>>(h4, Wmu, Wlv, agg);
    k_reduce<<<128, 256, 0, stream>>>(agg, bmu, blv, eps, out, z);
    k_dec<<<512, 256, 0, stream>>>(z, Wdec, bdec, h4);

    // g1: t = [latent|raw|h1|h3] @ Wg1 (no bias) -> h2 ;
    //     x1 = relu(gather(t)*nd + bg1) -> agg
    k_gemm64<false><<<NN / 64, 256, 0, stream>>>(h4, 64, raw, 16, h1, 64, h3, 64,
                                                 Wg1, nullptr, h2);
    k_gather64<<<NN * 16 / 256, 256, 0, stream>>>(h2, rp, cols8, ns, nd, bg1, 1, agg);

    // g2: gather x1 -> h2 ; x2 = relu(h2@Wg2 + bg2) -> h3
    k_gather64<<<NN * 16 / 256, 256, 0, stream>>>(agg, rp, cols8, ns, nd, nullptr, 0, h2);
    k_gemm64<true><<<NN / 64, 256, 0, stream>>>(h2, 64, nullptr, 0, nullptr, 0, nullptr, 0,
                                                Wg2, bg2, h3);

    // recon
    k_gemmout<<<NN / 64, 256, 0, stream>>>(h3, Wout, bout, raw, out);
}

// Round 3
// 534.176 us; speedup vs baseline: 4.0691x; 1.0316x over previous
//
#include <hip/hip_runtime.h>
#include <math.h>

// Problem constants (match reference setup_inputs()).
#define NG   256        // graphs
#define NP   256        // nodes per graph
#define NN   65536      // total nodes
#define NE   1048576    // edges
#define EPG  4096       // edges per graph (contiguous, src/dst within graph)
#define INF  16         // input feats
#define HID  64         // hidden
#define ZD   128        // latent dim
#define KFLAT 16384     // NP*HID

// ---------------------------------------------------------------- degree ----
__global__ __launch_bounds__(256) void k_deg_count(const int* __restrict__ src,
                                                   const int* __restrict__ dst,
                                                   int* __restrict__ cs,
                                                   int* __restrict__ cd) {
    int e = blockIdx.x * 256 + threadIdx.x;
    atomicAdd(&cs[src[e]], 1);
    atomicAdd(&cd[dst[e]], 1);
}

__global__ __launch_bounds__(256) void k_norms(const int* __restrict__ cs,
                                               const int* __restrict__ cd,
                                               float* __restrict__ ns,
                                               float* __restrict__ nd) {
    int i = blockIdx.x * 256 + threadIdx.x;
    ns[i] = 1.0f / sqrtf((float)max(cs[i], 1));
    nd[i] = 1.0f / sqrtf((float)max(cd[i], 1));
}

// -------------------------------------------------------------- CSR build ----
// rp[n] = exclusive scan of in-degree within each graph (+ g*EPG base).
__global__ __launch_bounds__(256) void k_scan(const int* __restrict__ cd,
                                              int* __restrict__ rp) {
    __shared__ int buf[NP];
    const int g = blockIdx.x, t = threadIdx.x;
    const int v0 = cd[g * NP + t];
    buf[t] = v0;
    __syncthreads();
    for (int off = 1; off < NP; off <<= 1) {
        int v = (t >= off) ? buf[t - off] : 0;
        __syncthreads();
        buf[t] += v;
        __syncthreads();
    }
    rp[g * NP + t] = g * EPG + buf[t] - v0;   // exclusive
    if (g == NG - 1 && t == NP - 1) rp[NN] = NE;
}

// cols8[rp[dst]+k] = local src index (dst-sorted edge list), one block/graph.
__global__ __launch_bounds__(256) void k_csr_fill(const int* __restrict__ src,
                                                  const int* __restrict__ dst,
                                                  const int* __restrict__ rp,
                                                  unsigned char* __restrict__ cols8) {
    __shared__ int cnt[NP];
    const int g = blockIdx.x, t = threadIdx.x;
    cnt[t] = 0;
    __syncthreads();
    const int base_e = g * EPG;
    for (int i = t; i < EPG; i += 256) {
        int s = src[base_e + i], d = dst[base_e + i];
        int p = atomicAdd(&cnt[d & (NP - 1)], 1);
        cols8[rp[d] + p] = (unsigned char)(s & (NP - 1));
    }
}

// ------------------------------------------------------------ CSR gathers ----
// y[n,f] = nd[n] * sum_{e in in(n)} ns[src_e] * x[src_e, f]
// 64-wide: 16 threads per node (float4 each). mode 1: +bias, relu.
__global__ __launch_bounds__(256) void k_gather64(const float* __restrict__ x,
                                                  const int* __restrict__ rp,
                                                  const unsigned char* __restrict__ cols8,
                                                  const float* __restrict__ ns,
                                                  const float* __restrict__ nd,
                                                  const float* __restrict__ bias,
                                                  int mode,
                                                  float* __restrict__ y) {
    const int idx = blockIdx.x * 256 + threadIdx.x;
    const int n = idx >> 4, f = (idx & 15) * 4;
    const int base_n = n & ~(NP - 1);
    int e = rp[n];
    const int end = rp[n + 1];
    float4 acc = make_float4(0.f, 0.f, 0.f, 0.f);
    for (; e + 1 < end; e += 2) {
        int s0 = base_n + cols8[e], s1 = base_n + cols8[e + 1];
        float w0 = ns[s0], w1 = ns[s1];
        float4 v0 = *(const float4*)&x[s0 * HID + f];
        float4 v1 = *(const float4*)&x[s1 * HID + f];
        acc.x += v0.x * w0 + v1.x * w1;
        acc.y += v0.y * w0 + v1.y * w1;
        acc.z += v0.z * w0 + v1.z * w1;
        acc.w += v0.w * w0 + v1.w * w1;
    }
    if (e < end) {
        int s0 = base_n + cols8[e];
        float w0 = ns[s0];
        float4 v0 = *(const float4*)&x[s0 * HID + f];
        acc.x += v0.x * w0; acc.y += v0.y * w0;
        acc.z += v0.z * w0; acc.w += v0.w * w0;
    }
    const float sc = nd[n];
    float4 v = make_float4(acc.x * sc, acc.y * sc, acc.z * sc, acc.w * sc);
    if (mode) {
        float4 bb = *(const float4*)&bias[f];
        v.x = fmaxf(v.x + bb.x, 0.f);
        v.y = fmaxf(v.y + bb.y, 0.f);
        v.z = fmaxf(v.z + bb.z, 0.f);
        v.w = fmaxf(v.w + bb.w, 0.f);
    }
    *(float4*)&y[n * HID + f] = v;
}

// 16-wide: 4 threads per node, for conv1 input (raw).
__global__ __launch_bounds__(256) void k_gather16(const float* __restrict__ x,
                                                  const int* __restrict__ rp,
                                                  const unsigned char* __restrict__ cols8,
                                                  const float* __restrict__ ns,
                                                  const float* __restrict__ nd,
                                                  float* __restrict__ y) {
    const int idx = blockIdx.x * 256 + threadIdx.x;
    const int n = idx >> 2, f = (idx & 3) * 4;
    const int base_n = n & ~(NP - 1);
    int e = rp[n];
    const int end = rp[n + 1];
    float4 acc = make_float4(0.f, 0.f, 0.f, 0.f);
    for (; e + 1 < end; e += 2) {
        int s0 = base_n + cols8[e], s1 = base_n + cols8[e + 1];
        float w0 = ns[s0], w1 = ns[s1];
        float4 v0 = *(const float4*)&x[s0 * INF + f];
        float4 v1 = *(const float4*)&x[s1 * INF + f];
        acc.x += v0.x * w0 + v1.x * w1;
        acc.y += v0.y * w0 + v1.y * w1;
        acc.z += v0.z * w0 + v1.z * w1;
        acc.w += v0.w * w0 + v1.w * w1;
    }
    if (e < end) {
        int s0 = base_n + cols8[e];
        float w0 = ns[s0];
        float4 v0 = *(const float4*)&x[s0 * INF + f];
        acc.x += v0.x * w0; acc.y += v0.y * w0;
        acc.z += v0.z * w0; acc.w += v0.w * w0;
    }
    const float sc = nd[n];
    y[n * INF + f + 0] = acc.x * sc;
    y[n * INF + f + 1] = acc.y * sc;
    y[n * INF + f + 2] = acc.z * sc;
    y[n * INF + f + 3] = acc.w * sc;
}

// -------------------------------------------------- tiled node GEMM (->64) ----
// y[N,64] = act( concat(x0..x3)[N, w0+..+w3] @ W + bias ).  64-node tiles,
// X^T staged in LDS (stride 68: conflict-free b128), W chunk in LDS.
template<bool RELU>
__global__ __launch_bounds__(256) void k_gemm64(const float* __restrict__ x0, int w0,
                                                const float* __restrict__ x1, int w1,
                                                const float* __restrict__ x2, int w2,
                                                const float* __restrict__ x3, int w3,
                                                const float* __restrict__ W,
                                                const float* __restrict__ bias,
                                                float* __restrict__ y) {
    __shared__ float XT[64 * 68];
    __shared__ float WL[64 * 64];
    const int t = threadIdx.x;
    const int g0 = blockIdx.x * 64;
    const int ig = t >> 4, jg = t & 15;
    float acc[4][4] = {};
    const float* xs[4] = {x0, x1, x2, x3};
    const int    ww[4] = {w0, w1, w2, w3};
    int koff = 0;
    for (int p = 0; p < 4; ++p) {
        const int w = ww[p];
        if (w == 0) continue;
        const float* xp = xs[p];
        for (int idx4 = t * 4; idx4 < 64 * w; idx4 += 1024) {
            int r = idx4 / w, c = idx4 % w;
            float4 v = *(const float4*)&xp[(g0 + r) * w + c];
            XT[(c + 0) * 68 + r] = v.x;
            XT[(c + 1) * 68 + r] = v.y;
            XT[(c + 2) * 68 + r] = v.z;
            XT[(c + 3) * 68 + r] = v.w;
        }
        for (int idx4 = t * 4; idx4 < w * 64; idx4 += 1024) {
            int k = idx4 >> 6, j = idx4 & 63;
            *(float4*)&WL[k * 64 + j] = *(const float4*)&W[(koff + k) * 64 + j];
        }
        __syncthreads();
        for (int k = 0; k < w; ++k) {
            float4 a = *(const float4*)&XT[k * 68 + ig * 4];
            float4 b = *(const float4*)&WL[k * 64 + jg * 4];
            float av[4] = {a.x, a.y, a.z, a.w};
            float bv[4] = {b.x, b.y, b.z, b.w};
#pragma unroll
            for (int r = 0; r < 4; ++r)
#pragma unroll
                for (int c = 0; c < 4; ++c) acc[r][c] += av[r] * bv[c];
        }
        __syncthreads();
        koff += w;
    }
    float4 bb = make_float4(0.f, 0.f, 0.f, 0.f);
    if (bias) bb = *(const float4*)&bias[jg * 4];
#pragma unroll
    for (int r = 0; r < 4; ++r) {
        float4 v;
        v.x = acc[r][0] + bb.x; v.y = acc[r][1] + bb.y;
        v.z = acc[r][2] + bb.z; v.w = acc[r][3] + bb.w;
        if (RELU) {
            v.x = fmaxf(v.x, 0.f); v.y = fmaxf(v.y, 0.f);
            v.z = fmaxf(v.z, 0.f); v.w = fmaxf(v.w, 0.f);
        }
        *(float4*)&y[(g0 + ig * 4 + r) * HID + jg * 4] = v;
    }
}

// ----------------------------------------------- mu/logvar split-K GEMM ------
// [256,16384]@[16384,128] for Wmu and Wlv. Grid 1024 = 16 m-tiles(16 g) x
// 64 k-chunks(256). 4x unrolled k-loop: 4 independent W loads in flight.
// Partials -> part[(kc*2+which)*32768 + g*128 + j].  (part = 4M floats = agg)
__global__ __launch_bounds__(256) void k_mulv(const float* __restrict__ hflat,
                                              const float* __restrict__ Wmu,
                                              const float* __restrict__ Wlv,
                                              float* __restrict__ part) {
    __shared__ float hT[256 * 17];   // [k][g], stride 17: conflict-free
    const int bx = blockIdx.x;
    const int mt = bx >> 6, kc = bx & 63;
    const int t = threadIdx.x;
    for (int p = 0; p < 16; ++p) {
        // idx = p*256 + t : gi = p, kl = t  -> coalesced 1KB reads
        hT[t * 17 + p] = hflat[(mt * 16 + p) * KFLAT + kc * 256 + t];
    }
    __syncthreads();
    const int which = t >> 7, j4 = (t >> 2) & 31, g4 = t & 3;
    const float* Wsel = which ? Wlv : Wmu;
    const float* wp = &Wsel[(kc * 256) * ZD + j4 * 4];
    float acc[4][4] = {};
    for (int kl = 0; kl < 256; kl += 4) {
        float4 b0 = *(const float4*)&wp[(kl + 0) * ZD];
        float4 b1 = *(const float4*)&wp[(kl + 1) * ZD];
        float4 b2 = *(const float4*)&wp[(kl + 2) * ZD];
        float4 b3 = *(const float4*)&wp[(kl + 3) * ZD];
        const float* h0 = &hT[(kl + 0) * 17 + g4 * 4];
        const float* h1 = &hT[(kl + 1) * 17 + g4 * 4];
        const float* h2 = &hT[(kl + 2) * 17 + g4 * 4];
        const float* h3 = &hT[(kl + 3) * 17 + g4 * 4];
#pragma unroll
        for (int r = 0; r < 4; ++r) {
            float a0 = h0[r], a1 = h1[r], a2 = h2[r], a3 = h3[r];
            acc[r][0] += a0 * b0.x + a1 * b1.x + a2 * b2.x + a3 * b3.x;
            acc[r][1] += a0 * b0.y + a1 * b1.y + a2 * b2.y + a3 * b3.y;
            acc[r][2] += a0 * b0.z + a1 * b1.z + a2 * b2.z + a3 * b3.z;
            acc[r][3] += a0 * b0.w + a1 * b1.w + a2 * b2.w + a3 * b3.w;
        }
    }
    const int pb = (kc * 2 + which) << 15;
#pragma unroll
    for (int gi = 0; gi < 4; ++gi) {
        int g = mt * 16 + g4 * 4 + gi;
        *(float4*)&part[pb + g * ZD + j4 * 4] =
            make_float4(acc[gi][0], acc[gi][1], acc[gi][2], acc[gi][3]);
    }
}

// reduce partials -> mu, logvar (to d_out) and z (reparameterized) to ws.
__global__ __launch_bounds__(256) void k_reduce(const float* __restrict__ part,
                                                const float* __restrict__ bmu,
                                                const float* __restrict__ blv,
                                                const float* __restrict__ eps,
                                                float* __restrict__ out,
                                                float* __restrict__ z) {
    const int idx = blockIdx.x * 256 + threadIdx.x;  // 32768 = 256*128
    const int j = idx & 127;
    float mu = bmu[j], lv = blv[j];
    for (int kc = 0; kc < 64; ++kc) {
        mu += part[((kc * 2 + 0) << 15) + idx];
        lv += part[((kc * 2 + 1) << 15) + idx];
    }
    out[1048576 + idx] = mu;
    out[1048576 + 32768 + idx] = lv;
    z[idx] = mu + eps[idx] * expf(0.5f * lv);
}

// --------------------------------------------- latent = z @ Wdec + bdec ------
// [256,128]@[128,16384]. Grid 512 = 8 g-tiles(32) x 64 n-tiles(256).
__global__ __launch_bounds__(256) void k_dec(const float* __restrict__ z,
                                             const float* __restrict__ Wdec,
                                             const float* __restrict__ bdec,
                                             float* __restrict__ latent) {
    __shared__ float zT[ZD * 36];   // [k][g], stride 36: aligned b128, spread banks
    const int bx = blockIdx.x;
    const int gt = bx >> 6, nt = bx & 63;
    const int t = threadIdx.x;
    for (int idx = t; idx < 32 * ZD; idx += 256) {
        int gi = idx >> 7, k = idx & 127;
        zT[k * 36 + gi] = z[(gt * 32 + gi) * ZD + k];
    }
    __syncthreads();
    const int g4 = t >> 5, n8 = t & 31;
    const int n0 = nt * 256 + n8 * 8;
    float acc[4][8] = {};
    for (int k = 0; k < ZD; ++k) {
        float4 a = *(const float4*)&zT[k * 36 + g4 * 4];
        float4 b0 = *(const float4*)&Wdec[k * KFLAT + n0];
        float4 b1 = *(const float4*)&Wdec[k * KFLAT + n0 + 4];
        float av[4] = {a.x, a.y, a.z, a.w};
        float bv[8] = {b0.x, b0.y, b0.z, b0.w, b1.x, b1.y, b1.z, b1.w};
#pragma unroll
        for (int r = 0; r < 4; ++r)
#pragma unroll
            for (int c = 0; c < 8; ++c) acc[r][c] += av[r] * bv[c];
    }
    float4 bd0 = *(const float4*)&bdec[n0];
    float4 bd1 = *(const float4*)&bdec[n0 + 4];
#pragma unroll
    for (int r = 0; r < 4; ++r) {
        int g = gt * 32 + g4 * 4 + r;
        float4 v0 = make_float4(acc[r][0] + bd0.x, acc[r][1] + bd0.y,
                                acc[r][2] + bd0.z, acc[r][3] + bd0.w);
        float4 v1 = make_float4(acc[r][4] + bd1.x, acc[r][5] + bd1.y,
                                acc[r][6] + bd1.z, acc[r][7] + bd1.w);
        *(float4*)&latent[g * KFLAT + n0]     = v0;
        *(float4*)&latent[g * KFLAT + n0 + 4] = v1;
    }
}

// -------------------------------------------- recon = x@Wout + bout ----------
// 64->16, col 0 overridden with raw[:,0].
__global__ __launch_bounds__(256) void k_gemmout(const float* __restrict__ x,
                                                 const float* __restrict__ W,
                                                 const float* __restrict__ bias,
                                                 const float* __restrict__ raw,
                                                 float* __restrict__ out) {
    __shared__ float XT[64 * 68];
    __shared__ float WL[64 * 16];
    const int t = threadIdx.x, g0 = blockIdx.x * 64;
    for (int idx4 = t * 4; idx4 < 64 * 64; idx4 += 1024) {
        int r = idx4 >> 6, c = idx4 & 63;
        float4 v = *(const float4*)&x[(g0 + r) * 64 + c];
        XT[(c + 0) * 68 + r] = v.x;
        XT[(c + 1) * 68 + r] = v.y;
        XT[(c + 2) * 68 + r] = v.z;
        XT[(c + 3) * 68 + r] = v.w;
    }
    {
        int idx4 = t * 4;  // 1024 floats total, one pass
        int k = idx4 >> 4, j = idx4 & 15;
        *(float4*)&WL[k * 16 + j] = *(const float4*)&W[k * 16 + j];
    }
    __syncthreads();
    const int i = t & 63, jg = t >> 6;
    float acc[4] = {};
    for (int k = 0; k < 64; ++k) {
        float a = XT[k * 68 + i];
        float4 b = *(const float4*)&WL[k * 16 + jg * 4];
        acc[0] += a * b.x; acc[1] += a * b.y;
        acc[2] += a * b.z; acc[3] += a * b.w;
    }
    float4 bb = *(const float4*)&bias[jg * 4];
    float4 v = make_float4(acc[0] + bb.x, acc[1] + bb.y, acc[2] + bb.z, acc[3] + bb.w);
    if (jg == 0) v.x = raw[(g0 + i) * INF];   // recon[:, :1] = raw[:, :1]
    *(float4*)&out[(g0 + i) * INF + jg * 4] = v;
}

// ----------------------------------------------------------------- launch ----
extern "C" void kernel_launch(void* const* d_in, const int* in_sizes, int n_in,
                              void* d_out, int out_size, void* d_ws, size_t ws_size,
                              hipStream_t stream) {
    const float* raw  = (const float*)d_in[0];
    const int*   src  = (const int*)d_in[1];
    const int*   dst  = (const int*)d_in[2];
    const float* eps  = (const float*)d_in[3];
    const float* W1   = (const float*)d_in[4];
    const float* b1   = (const float*)d_in[5];
    const float* W2   = (const float*)d_in[6];
    const float* b2   = (const float*)d_in[7];
    const float* W3   = (const float*)d_in[8];
    const float* b3   = (const float*)d_in[9];
    const float* W4   = (const float*)d_in[10];
    const float* b4   = (const float*)d_in[11];
    const float* Wmu  = (const float*)d_in[12];
    const float* bmu  = (const float*)d_in[13];
    const float* Wlv  = (const float*)d_in[14];
    const float* blv  = (const float*)d_in[15];
    const float* Wdec = (const float*)d_in[16];
    const float* bdec = (const float*)d_in[17];
    const float* Wg1  = (const float*)d_in[18];
    const float* bg1  = (const float*)d_in[19];
    const float* Wg2  = (const float*)d_in[20];
    const float* bg2  = (const float*)d_in[21];
    const float* Wout = (const float*)d_in[22];
    const float* bout = (const float*)d_in[23];
    float* out = (float*)d_out;

    // ws layout (floats): ns | nd | rp | cols8 | agg | h1 | h2 | h3 | h4
    // agg doubles as: cs/cd (deg ints) before CSR, mu/lv partials (full 4M
    // floats, 64kc x 2 x 32768) after conv4. z (32K floats) lives in h2,
    // which is dead between the conv3 gather and the g1 GEMM that rewrites it.
    float* ws   = (float*)d_ws;
    float* ns   = ws;
    float* nd   = ns + NN;
    int*   rp   = (int*)(nd + NN);                       // NN+1 ints (pad 65792)
    unsigned char* cols8 = (unsigned char*)(rp + 65792); // NE bytes
    float* agg  = (float*)(cols8 + NE);
    float* h1   = agg + (size_t)NN * HID;
    float* h2   = h1 + (size_t)NN * HID;
    float* h3   = h2 + (size_t)NN * HID;
    float* h4   = h3 + (size_t)NN * HID;
    float* z    = h2;                                    // 32768 floats, dead region

    // degrees -> norms -> CSR (once per launch; src/dst identical every call)
    int* cs = (int*)agg;
    int* cd = cs + NN;
    hipMemsetAsync(cs, 0, 2 * NN * sizeof(int), stream);
    k_deg_count<<<NE / 256, 256, 0, stream>>>(src, dst, cs, cd);
    k_norms<<<NN / 256, 256, 0, stream>>>(cs, cd, ns, nd);
    k_scan<<<NG, 256, 0, stream>>>(cd, rp);
    k_csr_fill<<<NG, 256, 0, stream>>>(src, dst, rp, cols8);

    // conv1: gather raw (16) -> agg ; h1 = relu(agg@W1 + b1)
    k_gather16<<<NN * 4 / 256, 256, 0, stream>>>(raw, rp, cols8, ns, nd, agg);
    k_gemm64<true><<<NN / 64, 256, 0, stream>>>(agg, 16, nullptr, 0, nullptr, 0, nullptr, 0,
                                                W1, b1, h1);
    // conv2..4
    k_gather64<<<NN * 16 / 256, 256, 0, stream>>>(h1, rp, cols8, ns, nd, nullptr, 0, agg);
    k_gemm64<true><<<NN / 64, 256, 0, stream>>>(agg, 64, nullptr, 0, nullptr, 0, nullptr, 0,
                                                W2, b2, h2);
    k_gather64<<<NN * 16 / 256, 256, 0, stream>>>(h2, rp, cols8, ns, nd, nullptr, 0, agg);
    k_gemm64<true><<<NN / 64, 256, 0, stream>>>(agg, 64, nullptr, 0, nullptr, 0, nullptr, 0,
                                                W3, b3, h3);
    k_gather64<<<NN * 16 / 256, 256, 0, stream>>>(h3, rp, cols8, ns, nd, nullptr, 0, agg);
    k_gemm64<true><<<NN / 64, 256, 0, stream>>>(agg, 64, nullptr, 0, nullptr, 0, nullptr, 0,
                                                W4, b4, h4);

    // mu/logvar (partials fill agg: 64kc x 2 x 32768 floats = 4M), z -> h2
    k_mulv<<<1024, 256, 0, stream>>>(h4, Wmu, Wlv, agg);
    k_reduce<<<128, 256, 0, stream>>>(agg, bmu, blv, eps, out, z);
    k_dec<<<512, 256, 0, stream>>>(z, Wdec, bdec, h4);

    // g1: t = [latent|raw|h1|h3] @ Wg1 (no bias) -> h2 (overwrites dead z);
    //     x1 = relu(gather(t)*nd + bg1) -> agg
    k_gemm64<false><<<NN / 64, 256, 0, stream>>>(h4, 64, raw, 16, h1, 64, h3, 64,
                                                 Wg1, nullptr, h2);
    k_gather64<<<NN * 16 / 256, 256, 0, stream>>>(h2, rp, cols8, ns, nd, bg1, 1, agg);

    // g2: gather x1 -> h2 ; x2 = relu(h2@Wg2 + bg2) -> h3
    k_gather64<<<NN * 16 / 256, 256, 0, stream>>>(agg, rp, cols8, ns, nd, nullptr, 0, h2);
    k_gemm64<true><<<NN / 64, 256, 0, stream>>>(h2, 64, nullptr, 0, nullptr, 0, nullptr, 0,
                                                Wg2, bg2, h3);

    // recon
    k_gemmout<<<NN / 64, 256, 0, stream>>>(h3, Wout, bout, raw, out);
}

// Round 5
// 487.655 us; speedup vs baseline: 4.4573x; 1.0954x over previous
//
#include <hip/hip_runtime.h>
#include <math.h>

// Problem constants (match reference setup_inputs()).
#define NG   256        // graphs
#define NP   256        // nodes per graph
#define NN   65536      // total nodes
#define NE   1048576    // edges
#define EPG  4096       // edges per graph (contiguous, src/dst within graph)
#define INF  16         // input feats
#define HID  64         // hidden
#define ZD   128        // latent dim
#define KFLAT 16384     // NP*HID

// ---------------------------------------------------------------- degree ----
__global__ __launch_bounds__(256) void k_deg_count(const int* __restrict__ src,
                                                   const int* __restrict__ dst,
                                                   int* __restrict__ cs,
                                                   int* __restrict__ cd) {
    int e = blockIdx.x * 256 + threadIdx.x;
    atomicAdd(&cs[src[e]], 1);
    atomicAdd(&cd[dst[e]], 1);
}

__global__ __launch_bounds__(256) void k_norms(const int* __restrict__ cs,
                                               const int* __restrict__ cd,
                                               float* __restrict__ ns,
                                               float* __restrict__ nd) {
    int i = blockIdx.x * 256 + threadIdx.x;
    ns[i] = 1.0f / sqrtf((float)max(cs[i], 1));
    nd[i] = 1.0f / sqrtf((float)max(cd[i], 1));
}

// -------------------------------------------------------------- CSR build ----
// rp[n] = exclusive scan of in-degree within each graph (+ g*EPG base).
__global__ __launch_bounds__(256) void k_scan(const int* __restrict__ cd,
                                              int* __restrict__ rp) {
    __shared__ int buf[NP];
    const int g = blockIdx.x, t = threadIdx.x;
    const int v0 = cd[g * NP + t];
    buf[t] = v0;
    __syncthreads();
    for (int off = 1; off < NP; off <<= 1) {
        int v = (t >= off) ? buf[t - off] : 0;
        __syncthreads();
        buf[t] += v;
        __syncthreads();
    }
    rp[g * NP + t] = g * EPG + buf[t] - v0;   // exclusive
    if (g == NG - 1 && t == NP - 1) rp[NN] = NE;
}

// cols8[rp[dst]+k] = local src index (dst-sorted edge list), one block/graph.
__global__ __launch_bounds__(256) void k_csr_fill(const int* __restrict__ src,
                                                  const int* __restrict__ dst,
                                                  const int* __restrict__ rp,
                                                  unsigned char* __restrict__ cols8) {
    __shared__ int cnt[NP];
    const int g = blockIdx.x, t = threadIdx.x;
    cnt[t] = 0;
    __syncthreads();
    const int base_e = g * EPG;
    for (int i = t; i < EPG; i += 256) {
        int s = src[base_e + i], d = dst[base_e + i];
        int p = atomicAdd(&cnt[d & (NP - 1)], 1);
        cols8[rp[d] + p] = (unsigned char)(s & (NP - 1));
    }
}

// ------------------------------------------------------------ CSR gathers ----
// y[n,f] = nd[n] * sum_{e in in(n)} ns[src_e] * x[src_e, f]
// 64-wide: 16 threads per node (float4 each); 4-way unrolled edge loop for
// independent load chains. mode 1: +bias, relu.
__global__ __launch_bounds__(256) void k_gather64(const float* __restrict__ x,
                                                  const int* __restrict__ rp,
                                                  const unsigned char* __restrict__ cols8,
                                                  const float* __restrict__ ns,
                                                  const float* __restrict__ nd,
                                                  const float* __restrict__ bias,
                                                  int mode,
                                                  float* __restrict__ y) {
    const int idx = blockIdx.x * 256 + threadIdx.x;
    const int n = idx >> 4, f = (idx & 15) * 4;
    const int base_n = n & ~(NP - 1);
    int e = rp[n];
    const int end = rp[n + 1];
    float4 acc = make_float4(0.f, 0.f, 0.f, 0.f);
    for (; e + 3 < end; e += 4) {
        int s0 = base_n + cols8[e + 0];
        int s1 = base_n + cols8[e + 1];
        int s2 = base_n + cols8[e + 2];
        int s3 = base_n + cols8[e + 3];
        float w0 = ns[s0], w1 = ns[s1], w2 = ns[s2], w3 = ns[s3];
        float4 v0 = *(const float4*)&x[s0 * HID + f];
        float4 v1 = *(const float4*)&x[s1 * HID + f];
        float4 v2 = *(const float4*)&x[s2 * HID + f];
        float4 v3 = *(const float4*)&x[s3 * HID + f];
        acc.x += v0.x * w0 + v1.x * w1 + v2.x * w2 + v3.x * w3;
        acc.y += v0.y * w0 + v1.y * w1 + v2.y * w2 + v3.y * w3;
        acc.z += v0.z * w0 + v1.z * w1 + v2.z * w2 + v3.z * w3;
        acc.w += v0.w * w0 + v1.w * w1 + v2.w * w2 + v3.w * w3;
    }
    for (; e < end; ++e) {
        int s0 = base_n + cols8[e];
        float w0 = ns[s0];
        float4 v0 = *(const float4*)&x[s0 * HID + f];
        acc.x += v0.x * w0; acc.y += v0.y * w0;
        acc.z += v0.z * w0; acc.w += v0.w * w0;
    }
    const float sc = nd[n];
    float4 v = make_float4(acc.x * sc, acc.y * sc, acc.z * sc, acc.w * sc);
    if (mode) {
        float4 bb = *(const float4*)&bias[f];
        v.x = fmaxf(v.x + bb.x, 0.f);
        v.y = fmaxf(v.y + bb.y, 0.f);
        v.z = fmaxf(v.z + bb.z, 0.f);
        v.w = fmaxf(v.w + bb.w, 0.f);
    }
    *(float4*)&y[n * HID + f] = v;
}

// 16-wide: 4 threads per node, for conv1 input (raw).
__global__ __launch_bounds__(256) void k_gather16(const float* __restrict__ x,
                                                  const int* __restrict__ rp,
                                                  const unsigned char* __restrict__ cols8,
                                                  const float* __restrict__ ns,
                                                  const float* __restrict__ nd,
                                                  float* __restrict__ y) {
    const int idx = blockIdx.x * 256 + threadIdx.x;
    const int n = idx >> 2, f = (idx & 3) * 4;
    const int base_n = n & ~(NP - 1);
    int e = rp[n];
    const int end = rp[n + 1];
    float4 acc = make_float4(0.f, 0.f, 0.f, 0.f);
    for (; e + 3 < end; e += 4) {
        int s0 = base_n + cols8[e + 0];
        int s1 = base_n + cols8[e + 1];
        int s2 = base_n + cols8[e + 2];
        int s3 = base_n + cols8[e + 3];
        float w0 = ns[s0], w1 = ns[s1], w2 = ns[s2], w3 = ns[s3];
        float4 v0 = *(const float4*)&x[s0 * INF + f];
        float4 v1 = *(const float4*)&x[s1 * INF + f];
        float4 v2 = *(const float4*)&x[s2 * INF + f];
        float4 v3 = *(const float4*)&x[s3 * INF + f];
        acc.x += v0.x * w0 + v1.x * w1 + v2.x * w2 + v3.x * w3;
        acc.y += v0.y * w0 + v1.y * w1 + v2.y * w2 + v3.y * w3;
        acc.z += v0.z * w0 + v1.z * w1 + v2.z * w2 + v3.z * w3;
        acc.w += v0.w * w0 + v1.w * w1 + v2.w * w2 + v3.w * w3;
    }
    for (; e < end; ++e) {
        int s0 = base_n + cols8[e];
        float w0 = ns[s0];
        float4 v0 = *(const float4*)&x[s0 * INF + f];
        acc.x += v0.x * w0; acc.y += v0.y * w0;
        acc.z += v0.z * w0; acc.w += v0.w * w0;
    }
    const float sc = nd[n];
    y[n * INF + f + 0] = acc.x * sc;
    y[n * INF + f + 1] = acc.y * sc;
    y[n * INF + f + 2] = acc.z * sc;
    y[n * INF + f + 3] = acc.w * sc;
}

// -------------------------------------------------- tiled node GEMM (->64) ----
// y[N,64] = act( concat(x0..x3)[N, w0+..+w3] @ W + bias ).  64-node tiles,
// X^T staged in LDS (stride 68: conflict-free b128), W chunk in LDS.
template<bool RELU>
__global__ __launch_bounds__(256) void k_gemm64(const float* __restrict__ x0, int w0,
                                                const float* __restrict__ x1, int w1,
                                                const float* __restrict__ x2, int w2,
                                                const float* __restrict__ x3, int w3,
                                                const float* __restrict__ W,
                                                const float* __restrict__ bias,
                                                float* __restrict__ y) {
    __shared__ float XT[64 * 68];
    __shared__ float WL[64 * 64];
    const int t = threadIdx.x;
    const int g0 = blockIdx.x * 64;
    const int ig = t >> 4, jg = t & 15;
    float acc[4][4] = {};
    const float* xs[4] = {x0, x1, x2, x3};
    const int    ww[4] = {w0, w1, w2, w3};
    int koff = 0;
    for (int p = 0; p < 4; ++p) {
        const int w = ww[p];
        if (w == 0) continue;
        const float* xp = xs[p];
        for (int idx4 = t * 4; idx4 < 64 * w; idx4 += 1024) {
            int r = idx4 / w, c = idx4 % w;
            float4 v = *(const float4*)&xp[(g0 + r) * w + c];
            XT[(c + 0) * 68 + r] = v.x;
            XT[(c + 1) * 68 + r] = v.y;
            XT[(c + 2) * 68 + r] = v.z;
            XT[(c + 3) * 68 + r] = v.w;
        }
        for (int idx4 = t * 4; idx4 < w * 64; idx4 += 1024) {
            int k = idx4 >> 6, j = idx4 & 63;
            *(float4*)&WL[k * 64 + j] = *(const float4*)&W[(koff + k) * 64 + j];
        }
        __syncthreads();
        for (int k = 0; k < w; ++k) {
            float4 a = *(const float4*)&XT[k * 68 + ig * 4];
            float4 b = *(const float4*)&WL[k * 64 + jg * 4];
            float av[4] = {a.x, a.y, a.z, a.w};
            float bv[4] = {b.x, b.y, b.z, b.w};
#pragma unroll
            for (int r = 0; r < 4; ++r)
#pragma unroll
                for (int c = 0; c < 4; ++c) acc[r][c] += av[r] * bv[c];
        }
        __syncthreads();
        koff += w;
    }
    float4 bb = make_float4(0.f, 0.f, 0.f, 0.f);
    if (bias) bb = *(const float4*)&bias[jg * 4];
#pragma unroll
    for (int r = 0; r < 4; ++r) {
        float4 v;
        v.x = acc[r][0] + bb.x; v.y = acc[r][1] + bb.y;
        v.z = acc[r][2] + bb.z; v.w = acc[r][3] + bb.w;
        if (RELU) {
            v.x = fmaxf(v.x, 0.f); v.y = fmaxf(v.y, 0.f);
            v.z = fmaxf(v.z, 0.f); v.w = fmaxf(v.w, 0.f);
        }
        *(float4*)&y[(g0 + ig * 4 + r) * HID + jg * 4] = v;
    }
}

// ----------------------------------------------- mu/logvar split-K GEMM ------
// [256,16384]@[16384,128] for Wmu and Wlv. Grid 1024 = 16 m-tiles(16 g) x
// 64 k-chunks(256). 4x unrolled k-loop: 4 independent W loads in flight.
// Partials -> part[(kc*2+which)*32768 + g*128 + j].  (part = 4M floats = agg)
__global__ __launch_bounds__(256) void k_mulv(const float* __restrict__ hflat,
                                              const float* __restrict__ Wmu,
                                              const float* __restrict__ Wlv,
                                              float* __restrict__ part) {
    __shared__ float hT[256 * 17];   // [k][g], stride 17: conflict-free
    const int bx = blockIdx.x;
    const int mt = bx >> 6, kc = bx & 63;
    const int t = threadIdx.x;
    for (int p = 0; p < 16; ++p) {
        // idx = p*256 + t : gi = p, kl = t  -> coalesced 1KB reads
        hT[t * 17 + p] = hflat[(mt * 16 + p) * KFLAT + kc * 256 + t];
    }
    __syncthreads();
    const int which = t >> 7, j4 = (t >> 2) & 31, g4 = t & 3;
    const float* Wsel = which ? Wlv : Wmu;
    const float* wp = &Wsel[(kc * 256) * ZD + j4 * 4];
    float acc[4][4] = {};
    for (int kl = 0; kl < 256; kl += 4) {
        float4 b0 = *(const float4*)&wp[(kl + 0) * ZD];
        float4 b1 = *(const float4*)&wp[(kl + 1) * ZD];
        float4 b2 = *(const float4*)&wp[(kl + 2) * ZD];
        float4 b3 = *(const float4*)&wp[(kl + 3) * ZD];
        const float* h0 = &hT[(kl + 0) * 17 + g4 * 4];
        const float* h1 = &hT[(kl + 1) * 17 + g4 * 4];
        const float* h2 = &hT[(kl + 2) * 17 + g4 * 4];
        const float* h3 = &hT[(kl + 3) * 17 + g4 * 4];
#pragma unroll
        for (int r = 0; r < 4; ++r) {
            float a0 = h0[r], a1 = h1[r], a2 = h2[r], a3 = h3[r];
            acc[r][0] += a0 * b0.x + a1 * b1.x + a2 * b2.x + a3 * b3.x;
            acc[r][1] += a0 * b0.y + a1 * b1.y + a2 * b2.y + a3 * b3.y;
            acc[r][2] += a0 * b0.z + a1 * b1.z + a2 * b2.z + a3 * b3.z;
            acc[r][3] += a0 * b0.w + a1 * b1.w + a2 * b2.w + a3 * b3.w;
        }
    }
    const int pb = (kc * 2 + which) << 15;
#pragma unroll
    for (int gi = 0; gi < 4; ++gi) {
        int g = mt * 16 + g4 * 4 + gi;
        *(float4*)&part[pb + g * ZD + j4 * 4] =
            make_float4(acc[gi][0], acc[gi][1], acc[gi][2], acc[gi][3]);
    }
}

// reduce partials -> mu, logvar (to d_out) and z (reparameterized) to ws.
__global__ __launch_bounds__(256) void k_reduce(const float* __restrict__ part,
                                                const float* __restrict__ bmu,
                                                const float* __restrict__ blv,
                                                const float* __restrict__ eps,
                                                float* __restrict__ out,
                                                float* __restrict__ z) {
    const int idx = blockIdx.x * 256 + threadIdx.x;  // 32768 = 256*128
    const int j = idx & 127;
    float mu = bmu[j], lv = blv[j];
    for (int kc = 0; kc < 64; ++kc) {
        mu += part[((kc * 2 + 0) << 15) + idx];
        lv += part[((kc * 2 + 1) << 15) + idx];
    }
    out[1048576 + idx] = mu;
    out[1048576 + 32768 + idx] = lv;
    z[idx] = mu + eps[idx] * expf(0.5f * lv);
}

// --------------------------------------------- latent = z @ Wdec + bdec ------
// [256,128]@[128,16384]. Grid 1024 = 8 g-tiles(32) x 128 n-tiles(128 cols).
// Each thread: 4 graphs x 4 cols; k-loop unrolled x8 -> 8 independent Wdec
// float4 loads in flight (covers L2 latency). 4 blocks/CU.
__global__ __launch_bounds__(256) void k_dec(const float* __restrict__ z,
                                             const float* __restrict__ Wdec,
                                             const float* __restrict__ bdec,
                                             float* __restrict__ latent) {
    __shared__ float zT[ZD * 36];   // [k][g], stride 36: aligned b128
    const int bx = blockIdx.x;
    const int gt = bx >> 7, nt = bx & 127;
    const int t = threadIdx.x;
    for (int idx = t; idx < 32 * ZD; idx += 256) {
        int gi = idx >> 7, k = idx & 127;
        zT[k * 36 + gi] = z[(gt * 32 + gi) * ZD + k];
    }
    __syncthreads();
    const int g4 = t >> 5, n4 = t & 31;
    const int n0 = nt * 128 + n4 * 4;
    const float* wp = &Wdec[n0];
    float acc[4][4] = {};
#pragma unroll
    for (int k = 0; k < ZD; k += 8) {
        float4 b[8];
#pragma unroll
        for (int u = 0; u < 8; ++u)
            b[u] = *(const float4*)&wp[(k + u) * KFLAT];
#pragma unroll
        for (int u = 0; u < 8; ++u) {
            float4 a = *(const float4*)&zT[(k + u) * 36 + g4 * 4];
            float av[4] = {a.x, a.y, a.z, a.w};
#pragma unroll
            for (int r = 0; r < 4; ++r) {
                acc[r][0] += av[r] * b[u].x;
                acc[r][1] += av[r] * b[u].y;
                acc[r][2] += av[r] * b[u].z;
                acc[r][3] += av[r] * b[u].w;
            }
        }
    }
    float4 bd = *(const float4*)&bdec[n0];
#pragma unroll
    for (int r = 0; r < 4; ++r) {
        int g = gt * 32 + g4 * 4 + r;
        float4 v = make_float4(acc[r][0] + bd.x, acc[r][1] + bd.y,
                               acc[r][2] + bd.z, acc[r][3] + bd.w);
        *(float4*)&latent[g * KFLAT + n0] = v;
    }
}

// -------------------------------------------- recon = x@Wout + bout ----------
// 64->16, col 0 overridden with raw[:,0].
__global__ __launch_bounds__(256) void k_gemmout(const float* __restrict__ x,
                                                 const float* __restrict__ W,
                                                 const float* __restrict__ bias,
                                                 const float* __restrict__ raw,
                                                 float* __restrict__ out) {
    __shared__ float XT[64 * 68];
    __shared__ float WL[64 * 16];
    const int t = threadIdx.x, g0 = blockIdx.x * 64;
    for (int idx4 = t * 4; idx4 < 64 * 64; idx4 += 1024) {
        int r = idx4 >> 6, c = idx4 & 63;
        float4 v = *(const float4*)&x[(g0 + r) * 64 + c];
        XT[(c + 0) * 68 + r] = v.x;
        XT[(c + 1) * 68 + r] = v.y;
        XT[(c + 2) * 68 + r] = v.z;
        XT[(c + 3) * 68 + r] = v.w;
    }
    {
        int idx4 = t * 4;  // 1024 floats total, one pass
        int k = idx4 >> 4, j = idx4 & 15;
        *(float4*)&WL[k * 16 + j] = *(const float4*)&W[k * 16 + j];
    }
    __syncthreads();
    const int i = t & 63, jg = t >> 6;
    float acc[4] = {};
    for (int k = 0; k < 64; ++k) {
        float a = XT[k * 68 + i];
        float4 b = *(const float4*)&WL[k * 16 + jg * 4];
        acc[0] += a * b.x; acc[1] += a * b.y;
        acc[2] += a * b.z; acc[3] += a * b.w;
    }
    float4 bb = *(const float4*)&bias[jg * 4];
    float4 v = make_float4(acc[0] + bb.x, acc[1] + bb.y, acc[2] + bb.z, acc[3] + bb.w);
    if (jg == 0) v.x = raw[(g0 + i) * INF];   // recon[:, :1] = raw[:, :1]
    *(float4*)&out[(g0 + i) * INF + jg * 4] = v;
}

// ----------------------------------------------------------------- launch ----
extern "C" void kernel_launch(void* const* d_in, const int* in_sizes, int n_in,
                              void* d_out, int out_size, void* d_ws, size_t ws_size,
                              hipStream_t stream) {
    const float* raw  = (const float*)d_in[0];
    const int*   src  = (const int*)d_in[1];
    const int*   dst  = (const int*)d_in[2];
    const float* eps  = (const float*)d_in[3];
    const float* W1   = (const float*)d_in[4];
    const float* b1   = (const float*)d_in[5];
    const float* W2   = (const float*)d_in[6];
    const float* b2   = (const float*)d_in[7];
    const float* W3   = (const float*)d_in[8];
    const float* b3   = (const float*)d_in[9];
    const float* W4   = (const float*)d_in[10];
    const float* b4   = (const float*)d_in[11];
    const float* Wmu  = (const float*)d_in[12];
    const float* bmu  = (const float*)d_in[13];
    const float* Wlv  = (const float*)d_in[14];
    const float* blv  = (const float*)d_in[15];
    const float* Wdec = (const float*)d_in[16];
    const float* bdec = (const float*)d_in[17];
    const float* Wg1  = (const float*)d_in[18];
    const float* bg1  = (const float*)d_in[19];
    const float* Wg2  = (const float*)d_in[20];
    const float* bg2  = (const float*)d_in[21];
    const float* Wout = (const float*)d_in[22];
    const float* bout = (const float*)d_in[23];
    float* out = (float*)d_out;

    // ws layout (floats): ns | nd | rp | cols8 | agg | h1 | h2 | h3 | h4
    // agg doubles as: cs/cd (deg ints) before CSR, mu/lv partials (full 4M
    // floats, 64kc x 2 x 32768) after conv4. z (32K floats) lives in h2,
    // which is dead between the conv3 gather and the g1 GEMM that rewrites it.
    float* ws   = (float*)d_ws;
    float* ns   = ws;
    float* nd   = ns + NN;
    int*   rp   = (int*)(nd + NN);                       // NN+1 ints (pad 65792)
    unsigned char* cols8 = (unsigned char*)(rp + 65792); // NE bytes
    float* agg  = (float*)(cols8 + NE);
    float* h1   = agg + (size_t)NN * HID;
    float* h2   = h1 + (size_t)NN * HID;
    float* h3   = h2 + (size_t)NN * HID;
    float* h4   = h3 + (size_t)NN * HID;
    float* z    = h2;                                    // 32768 floats, dead region

    // degrees -> norms -> CSR (once per launch; src/dst identical every call)
    int* cs = (int*)agg;
    int* cd = cs + NN;
    hipMemsetAsync(cs, 0, 2 * NN * sizeof(int), stream);
    k_deg_count<<<NE / 256, 256, 0, stream>>>(src, dst, cs, cd);
    k_norms<<<NN / 256, 256, 0, stream>>>(cs, cd, ns, nd);
    k_scan<<<NG, 256, 0, stream>>>(cd, rp);
    k_csr_fill<<<NG, 256, 0, stream>>>(src, dst, rp, cols8);

    // conv1: gather raw (16) -> agg ; h1 = relu(agg@W1 + b1)
    k_gather16<<<NN * 4 / 256, 256, 0, stream>>>(raw, rp, cols8, ns, nd, agg);
    k_gemm64<true><<<NN / 64, 256, 0, stream>>>(agg, 16, nullptr, 0, nullptr, 0, nullptr, 0,
                                                W1, b1, h1);
    // conv2..4
    k_gather64<<<NN * 16 / 256, 256, 0, stream>>>(h1, rp, cols8, ns, nd, nullptr, 0, agg);
    k_gemm64<true><<<NN / 64, 256, 0, stream>>>(agg, 64, nullptr, 0, nullptr, 0, nullptr, 0,
                                                W2, b2, h2);
    k_gather64<<<NN * 16 / 256, 256, 0, stream>>>(h2, rp, cols8, ns, nd, nullptr, 0, agg);
    k_gemm64<true><<<NN / 64, 256, 0, stream>>>(agg, 64, nullptr, 0, nullptr, 0, nullptr, 0,
                                                W3, b3, h3);
    k_gather64<<<NN * 16 / 256, 256, 0, stream>>>(h3, rp, cols8, ns, nd, nullptr, 0, agg);
    k_gemm64<true><<<NN / 64, 256, 0, stream>>>(agg, 64, nullptr, 0, nullptr, 0, nullptr, 0,
                                                W4, b4, h4);

    // mu/logvar (partials fill agg: 64kc x 2 x 32768 floats = 4M), z -> h2
    k_mulv<<<1024, 256, 0, stream>>>(h4, Wmu, Wlv, agg);
    k_reduce<<<128, 256, 0, stream>>>(agg, bmu, blv, eps, out, z);
    k_dec<<<1024, 256, 0, stream>>>(z, Wdec, bdec, h4);

    // g1: t = [latent|raw|h1|h3] @ Wg1 (no bias) -> h2 (overwrites dead z);
    //     x1 = relu(gather(t)*nd + bg1) -> agg
    k_gemm64<false><<<NN / 64, 256, 0, stream>>>(h4, 64, raw, 16, h1, 64, h3, 64,
                                                 Wg1, nullptr, h2);
    k_gather64<<<NN * 16 / 256, 256, 0, stream>>>(h2, rp, cols8, ns, nd, bg1, 1, agg);

    // g2: gather x1 -> h2 ; x2 = relu(h2@Wg2 + bg2) -> h3
    k_gather64<<<NN * 16 / 256, 256, 0, stream>>>(agg, rp, cols8, ns, nd, nullptr, 0, h2);
    k_gemm64<true><<<NN / 64, 256, 0, stream>>>(h2, 64, nullptr, 0, nullptr, 0, nullptr, 0,
                                                Wg2, bg2, h3);

    // recon
    k_gemmout<<<NN / 64, 256, 0, stream>>>(h3, Wout, bout, raw, out);
}

// Round 6
// 459.756 us; speedup vs baseline: 4.7277x; 1.0607x over previous
//
#include <hip/hip_runtime.h>
#include <math.h>

// Problem constants (match reference setup_inputs()).
#define NG   256        // graphs
#define NP   256        // nodes per graph
#define NN   65536      // total nodes
#define NE   1048576    // edges
#define EPG  4096       // edges per graph (contiguous, src/dst within graph)
#define INF  16         // input feats
#define HID  64         // hidden
#define ZD   128        // latent dim
#define KFLAT 16384     // NP*HID

typedef float f32x4 __attribute__((ext_vector_type(4)));
typedef __bf16 bf16x8 __attribute__((ext_vector_type(8)));
typedef __bf16 bf16x4 __attribute__((ext_vector_type(4)));

// ---------------------------------------------------------------- degree ----
__global__ __launch_bounds__(256) void k_deg_count(const int* __restrict__ src,
                                                   const int* __restrict__ dst,
                                                   int* __restrict__ cs,
                                                   int* __restrict__ cd) {
    int e = blockIdx.x * 256 + threadIdx.x;
    atomicAdd(&cs[src[e]], 1);
    atomicAdd(&cd[dst[e]], 1);
}

__global__ __launch_bounds__(256) void k_norms(const int* __restrict__ cs,
                                               const int* __restrict__ cd,
                                               float* __restrict__ ns,
                                               float* __restrict__ nd) {
    int i = blockIdx.x * 256 + threadIdx.x;
    ns[i] = 1.0f / sqrtf((float)max(cs[i], 1));
    nd[i] = 1.0f / sqrtf((float)max(cd[i], 1));
}

// -------------------------------------------------------------- CSR build ----
__global__ __launch_bounds__(256) void k_scan(const int* __restrict__ cd,
                                              int* __restrict__ rp) {
    __shared__ int buf[NP];
    const int g = blockIdx.x, t = threadIdx.x;
    const int v0 = cd[g * NP + t];
    buf[t] = v0;
    __syncthreads();
    for (int off = 1; off < NP; off <<= 1) {
        int v = (t >= off) ? buf[t - off] : 0;
        __syncthreads();
        buf[t] += v;
        __syncthreads();
    }
    rp[g * NP + t] = g * EPG + buf[t] - v0;   // exclusive
    if (g == NG - 1 && t == NP - 1) rp[NN] = NE;
}

__global__ __launch_bounds__(256) void k_csr_fill(const int* __restrict__ src,
                                                  const int* __restrict__ dst,
                                                  const int* __restrict__ rp,
                                                  unsigned char* __restrict__ cols8) {
    __shared__ int cnt[NP];
    const int g = blockIdx.x, t = threadIdx.x;
    cnt[t] = 0;
    __syncthreads();
    const int base_e = g * EPG;
    for (int i = t; i < EPG; i += 256) {
        int s = src[base_e + i], d = dst[base_e + i];
        int p = atomicAdd(&cnt[d & (NP - 1)], 1);
        cols8[rp[d] + p] = (unsigned char)(s & (NP - 1));
    }
}

// ------------------------------------------------------------ CSR gathers ----
__global__ __launch_bounds__(256) void k_gather64(const float* __restrict__ x,
                                                  const int* __restrict__ rp,
                                                  const unsigned char* __restrict__ cols8,
                                                  const float* __restrict__ ns,
                                                  const float* __restrict__ nd,
                                                  const float* __restrict__ bias,
                                                  int mode,
                                                  float* __restrict__ y) {
    const int idx = blockIdx.x * 256 + threadIdx.x;
    const int n = idx >> 4, f = (idx & 15) * 4;
    const int base_n = n & ~(NP - 1);
    int e = rp[n];
    const int end = rp[n + 1];
    float4 acc = make_float4(0.f, 0.f, 0.f, 0.f);
    for (; e + 3 < end; e += 4) {
        int s0 = base_n + cols8[e + 0];
        int s1 = base_n + cols8[e + 1];
        int s2 = base_n + cols8[e + 2];
        int s3 = base_n + cols8[e + 3];
        float w0 = ns[s0], w1 = ns[s1], w2 = ns[s2], w3 = ns[s3];
        float4 v0 = *(const float4*)&x[s0 * HID + f];
        float4 v1 = *(const float4*)&x[s1 * HID + f];
        float4 v2 = *(const float4*)&x[s2 * HID + f];
        float4 v3 = *(const float4*)&x[s3 * HID + f];
        acc.x += v0.x * w0 + v1.x * w1 + v2.x * w2 + v3.x * w3;
        acc.y += v0.y * w0 + v1.y * w1 + v2.y * w2 + v3.y * w3;
        acc.z += v0.z * w0 + v1.z * w1 + v2.z * w2 + v3.z * w3;
        acc.w += v0.w * w0 + v1.w * w1 + v2.w * w2 + v3.w * w3;
    }
    for (; e < end; ++e) {
        int s0 = base_n + cols8[e];
        float w0 = ns[s0];
        float4 v0 = *(const float4*)&x[s0 * HID + f];
        acc.x += v0.x * w0; acc.y += v0.y * w0;
        acc.z += v0.z * w0; acc.w += v0.w * w0;
    }
    const float sc = nd[n];
    float4 v = make_float4(acc.x * sc, acc.y * sc, acc.z * sc, acc.w * sc);
    if (mode) {
        float4 bb = *(const float4*)&bias[f];
        v.x = fmaxf(v.x + bb.x, 0.f);
        v.y = fmaxf(v.y + bb.y, 0.f);
        v.z = fmaxf(v.z + bb.z, 0.f);
        v.w = fmaxf(v.w + bb.w, 0.f);
    }
    *(float4*)&y[n * HID + f] = v;
}

__global__ __launch_bounds__(256) void k_gather16(const float* __restrict__ x,
                                                  const int* __restrict__ rp,
                                                  const unsigned char* __restrict__ cols8,
                                                  const float* __restrict__ ns,
                                                  const float* __restrict__ nd,
                                                  float* __restrict__ y) {
    const int idx = blockIdx.x * 256 + threadIdx.x;
    const int n = idx >> 2, f = (idx & 3) * 4;
    const int base_n = n & ~(NP - 1);
    int e = rp[n];
    const int end = rp[n + 1];
    float4 acc = make_float4(0.f, 0.f, 0.f, 0.f);
    for (; e + 3 < end; e += 4) {
        int s0 = base_n + cols8[e + 0];
        int s1 = base_n + cols8[e + 1];
        int s2 = base_n + cols8[e + 2];
        int s3 = base_n + cols8[e + 3];
        float w0 = ns[s0], w1 = ns[s1], w2 = ns[s2], w3 = ns[s3];
        float4 v0 = *(const float4*)&x[s0 * INF + f];
        float4 v1 = *(const float4*)&x[s1 * INF + f];
        float4 v2 = *(const float4*)&x[s2 * INF + f];
        float4 v3 = *(const float4*)&x[s3 * INF + f];
        acc.x += v0.x * w0 + v1.x * w1 + v2.x * w2 + v3.x * w3;
        acc.y += v0.y * w0 + v1.y * w1 + v2.y * w2 + v3.y * w3;
        acc.z += v0.z * w0 + v1.z * w1 + v2.z * w2 + v3.z * w3;
        acc.w += v0.w * w0 + v1.w * w1 + v2.w * w2 + v3.w * w3;
    }
    for (; e < end; ++e) {
        int s0 = base_n + cols8[e];
        float w0 = ns[s0];
        float4 v0 = *(const float4*)&x[s0 * INF + f];
        acc.x += v0.x * w0; acc.y += v0.y * w0;
        acc.z += v0.z * w0; acc.w += v0.w * w0;
    }
    const float sc = nd[n];
    y[n * INF + f + 0] = acc.x * sc;
    y[n * INF + f + 1] = acc.y * sc;
    y[n * INF + f + 2] = acc.z * sc;
    y[n * INF + f + 3] = acc.w * sc;
}

// -------------------------------------------------- tiled node GEMM (->64) ----
// y[N,64] = act( concat(x0..x3)[N, w0+..+w3] @ W + bias ).
// OUTBF16: write y as bf16 (for h4 -> MFMA consumer).
template<bool RELU, bool OUTBF16>
__global__ __launch_bounds__(256) void k_gemm64(const float* __restrict__ x0, int w0,
                                                const float* __restrict__ x1, int w1,
                                                const float* __restrict__ x2, int w2,
                                                const float* __restrict__ x3, int w3,
                                                const float* __restrict__ W,
                                                const float* __restrict__ bias,
                                                float* __restrict__ y) {
    __shared__ float XT[64 * 68];
    __shared__ float WL[64 * 64];
    const int t = threadIdx.x;
    const int g0 = blockIdx.x * 64;
    const int ig = t >> 4, jg = t & 15;
    float acc[4][4] = {};
    const float* xs[4] = {x0, x1, x2, x3};
    const int    ww[4] = {w0, w1, w2, w3};
    int koff = 0;
    for (int p = 0; p < 4; ++p) {
        const int w = ww[p];
        if (w == 0) continue;
        const float* xp = xs[p];
        for (int idx4 = t * 4; idx4 < 64 * w; idx4 += 1024) {
            int r = idx4 / w, c = idx4 % w;
            float4 v = *(const float4*)&xp[(g0 + r) * w + c];
            XT[(c + 0) * 68 + r] = v.x;
            XT[(c + 1) * 68 + r] = v.y;
            XT[(c + 2) * 68 + r] = v.z;
            XT[(c + 3) * 68 + r] = v.w;
        }
        for (int idx4 = t * 4; idx4 < w * 64; idx4 += 1024) {
            int k = idx4 >> 6, j = idx4 & 63;
            *(float4*)&WL[k * 64 + j] = *(const float4*)&W[(koff + k) * 64 + j];
        }
        __syncthreads();
        for (int k = 0; k < w; ++k) {
            float4 a = *(const float4*)&XT[k * 68 + ig * 4];
            float4 b = *(const float4*)&WL[k * 64 + jg * 4];
            float av[4] = {a.x, a.y, a.z, a.w};
            float bv[4] = {b.x, b.y, b.z, b.w};
#pragma unroll
            for (int r = 0; r < 4; ++r)
#pragma unroll
                for (int c = 0; c < 4; ++c) acc[r][c] += av[r] * bv[c];
        }
        __syncthreads();
        koff += w;
    }
    float4 bb = make_float4(0.f, 0.f, 0.f, 0.f);
    if (bias) bb = *(const float4*)&bias[jg * 4];
#pragma unroll
    for (int r = 0; r < 4; ++r) {
        float4 v;
        v.x = acc[r][0] + bb.x; v.y = acc[r][1] + bb.y;
        v.z = acc[r][2] + bb.z; v.w = acc[r][3] + bb.w;
        if (RELU) {
            v.x = fmaxf(v.x, 0.f); v.y = fmaxf(v.y, 0.f);
            v.z = fmaxf(v.z, 0.f); v.w = fmaxf(v.w, 0.f);
        }
        if (OUTBF16) {
            __bf16* yb = (__bf16*)y;
            bf16x4 vb = {(__bf16)v.x, (__bf16)v.y, (__bf16)v.z, (__bf16)v.w};
            *(bf16x4*)&yb[(g0 + ig * 4 + r) * HID + jg * 4] = vb;
        } else {
            *(float4*)&y[(g0 + ig * 4 + r) * HID + jg * 4] = v;
        }
    }
}

// ------------------------------- Wmu|Wlv -> WT bf16 [256 jj][16384 k] --------
// 32x32 transpose tiles; jj<128 = Wmu col jj, else Wlv col jj-128.
__global__ __launch_bounds__(256) void k_wcast(const float* __restrict__ Wmu,
                                               const float* __restrict__ Wlv,
                                               __bf16* __restrict__ WT) {
    __shared__ float tile[32][33];
    const int bx = blockIdx.x;          // 512 k-tiles x 8 j-tiles
    const int kt = bx >> 3, jt = bx & 7;
    const int k0 = kt * 32, j0 = (jt & 3) * 32;
    const float* Wsel = (jt < 4) ? Wmu : Wlv;
    const int t = threadIdx.x;
    const int jl = t & 31, kl0 = t >> 5;
    for (int p = 0; p < 4; ++p) {
        int kl = kl0 + p * 8;
        tile[kl][jl] = Wsel[(k0 + kl) * ZD + j0 + jl];
    }
    __syncthreads();
    const int kl2 = t & 31, jl0 = t >> 5;
    for (int p = 0; p < 4; ++p) {
        int jw = jl0 + p * 8;
        WT[(size_t)(jt * 32 + jw) * KFLAT + k0 + kl2] = (__bf16)tile[kl2][jw];
    }
}

// ------------------------------------- mu/logvar MFMA split-K GEMM -----------
// C[256 g][256 jj] = h4b[256][16384] . WT[256 jj][16384]^T, split K 64 ways.
// Grid 1024 = gt(4) x jt(4) x kc(64); block = 4 waves, 64g x 64jj tile.
// Partials -> part[kc*65536 + g*256 + jj] (4M floats = agg region).
#define BKP 136   // LDS row pitch in bf16: 272B, 16B-aligned, 2-way-conflict reads
__global__ __launch_bounds__(256) void k_mulv_mfma(const __bf16* __restrict__ h4b,
                                                   const __bf16* __restrict__ WT,
                                                   float* __restrict__ part) {
    __shared__ __bf16 Ab[64 * BKP];
    __shared__ __bf16 Bb[64 * BKP];
    const int bx = blockIdx.x;
    const int kc = bx & 63, jt = (bx >> 6) & 3, gt = bx >> 8;
    const int t = threadIdx.x;
    const int w = t >> 6, lane = t & 63;
    const int m16 = lane & 15, q = lane >> 4;
    f32x4 acc[4] = {};
    const int k0base = kc * 256;
    for (int ks = 0; ks < 2; ++ks) {
        const int k0 = k0base + ks * 128;
#pragma unroll
        for (int p = 0; p < 4; ++p) {
            int oct = t + p * 256;          // 0..1023
            int r = oct >> 4, c8 = oct & 15;
            *(bf16x8*)&Ab[r * BKP + c8 * 8] =
                *(const bf16x8*)&h4b[(size_t)(gt * 64 + r) * KFLAT + k0 + c8 * 8];
            *(bf16x8*)&Bb[r * BKP + c8 * 8] =
                *(const bf16x8*)&WT[(size_t)(jt * 64 + r) * KFLAT + k0 + c8 * 8];
        }
        __syncthreads();
#pragma unroll
        for (int kk = 0; kk < 4; ++kk) {
            bf16x8 a = *(const bf16x8*)&Ab[(w * 16 + m16) * BKP + kk * 32 + q * 8];
#pragma unroll
            for (int nt = 0; nt < 4; ++nt) {
                bf16x8 b = *(const bf16x8*)&Bb[(nt * 16 + m16) * BKP + kk * 32 + q * 8];
                acc[nt] = __builtin_amdgcn_mfma_f32_16x16x32_bf16(a, b, acc[nt], 0, 0, 0);
            }
        }
        __syncthreads();
    }
    const int pb = kc << 16;
#pragma unroll
    for (int nt = 0; nt < 4; ++nt) {
        const int jj = jt * 64 + nt * 16 + m16;
#pragma unroll
        for (int r = 0; r < 4; ++r) {
            int g = gt * 64 + w * 16 + q * 4 + r;   // C/D: col=lane&15, row=q*4+reg
            part[pb + g * 256 + jj] = acc[nt][r];
        }
    }
}

// reduce partials -> mu, logvar (to d_out) and z (reparameterized).
__global__ __launch_bounds__(256) void k_reduce(const float* __restrict__ part,
                                                const float* __restrict__ bmu,
                                                const float* __restrict__ blv,
                                                const float* __restrict__ eps,
                                                float* __restrict__ out,
                                                float* __restrict__ z) {
    const int idx = blockIdx.x * 256 + threadIdx.x;  // 32768 = 256*128
    const int g = idx >> 7, j = idx & 127;
    float mu = bmu[j], lv = blv[j];
    for (int kc = 0; kc < 64; ++kc) {
        mu += part[(kc << 16) + g * 256 + j];
        lv += part[(kc << 16) + g * 256 + 128 + j];
    }
    out[1048576 + idx] = mu;
    out[1048576 + 32768 + idx] = lv;
    z[idx] = mu + eps[idx] * expf(0.5f * lv);
}

// --------------------------------------------- latent = z @ Wdec + bdec ------
__global__ __launch_bounds__(256) void k_dec(const float* __restrict__ z,
                                             const float* __restrict__ Wdec,
                                             const float* __restrict__ bdec,
                                             float* __restrict__ latent) {
    __shared__ float zT[ZD * 36];
    const int bx = blockIdx.x;
    const int gt = bx >> 7, nt = bx & 127;
    const int t = threadIdx.x;
    for (int idx = t; idx < 32 * ZD; idx += 256) {
        int gi = idx >> 7, k = idx & 127;
        zT[k * 36 + gi] = z[(gt * 32 + gi) * ZD + k];
    }
    __syncthreads();
    const int g4 = t >> 5, n4 = t & 31;
    const int n0 = nt * 128 + n4 * 4;
    const float* wp = &Wdec[n0];
    float acc[4][4] = {};
#pragma unroll
    for (int k = 0; k < ZD; k += 8) {
        float4 b[8];
#pragma unroll
        for (int u = 0; u < 8; ++u)
            b[u] = *(const float4*)&wp[(k + u) * KFLAT];
#pragma unroll
        for (int u = 0; u < 8; ++u) {
            float4 a = *(const float4*)&zT[(k + u) * 36 + g4 * 4];
            float av[4] = {a.x, a.y, a.z, a.w};
#pragma unroll
            for (int r = 0; r < 4; ++r) {
                acc[r][0] += av[r] * b[u].x;
                acc[r][1] += av[r] * b[u].y;
                acc[r][2] += av[r] * b[u].z;
                acc[r][3] += av[r] * b[u].w;
            }
        }
    }
    float4 bd = *(const float4*)&bdec[n0];
#pragma unroll
    for (int r = 0; r < 4; ++r) {
        int g = gt * 32 + g4 * 4 + r;
        float4 v = make_float4(acc[r][0] + bd.x, acc[r][1] + bd.y,
                               acc[r][2] + bd.z, acc[r][3] + bd.w);
        *(float4*)&latent[g * KFLAT + n0] = v;
    }
}

// -------------------------------------------- recon = x@Wout + bout ----------
__global__ __launch_bounds__(256) void k_gemmout(const float* __restrict__ x,
                                                 const float* __restrict__ W,
                                                 const float* __restrict__ bias,
                                                 const float* __restrict__ raw,
                                                 float* __restrict__ out) {
    __shared__ float XT[64 * 68];
    __shared__ float WL[64 * 16];
    const int t = threadIdx.x, g0 = blockIdx.x * 64;
    for (int idx4 = t * 4; idx4 < 64 * 64; idx4 += 1024) {
        int r = idx4 >> 6, c = idx4 & 63;
        float4 v = *(const float4*)&x[(g0 + r) * 64 + c];
        XT[(c + 0) * 68 + r] = v.x;
        XT[(c + 1) * 68 + r] = v.y;
        XT[(c + 2) * 68 + r] = v.z;
        XT[(c + 3) * 68 + r] = v.w;
    }
    {
        int idx4 = t * 4;
        int k = idx4 >> 4, j = idx4 & 15;
        *(float4*)&WL[k * 16 + j] = *(const float4*)&W[k * 16 + j];
    }
    __syncthreads();
    const int i = t & 63, jg = t >> 6;
    float acc[4] = {};
    for (int k = 0; k < 64; ++k) {
        float a = XT[k * 68 + i];
        float4 b = *(const float4*)&WL[k * 16 + jg * 4];
        acc[0] += a * b.x; acc[1] += a * b.y;
        acc[2] += a * b.z; acc[3] += a * b.w;
    }
    float4 bb = *(const float4*)&bias[jg * 4];
    float4 v = make_float4(acc[0] + bb.x, acc[1] + bb.y, acc[2] + bb.z, acc[3] + bb.w);
    if (jg == 0) v.x = raw[(g0 + i) * INF];
    *(float4*)&out[(g0 + i) * INF + jg * 4] = v;
}

// ----------------------------------------------------------------- launch ----
extern "C" void kernel_launch(void* const* d_in, const int* in_sizes, int n_in,
                              void* d_out, int out_size, void* d_ws, size_t ws_size,
                              hipStream_t stream) {
    const float* raw  = (const float*)d_in[0];
    const int*   src  = (const int*)d_in[1];
    const int*   dst  = (const int*)d_in[2];
    const float* eps  = (const float*)d_in[3];
    const float* W1   = (const float*)d_in[4];
    const float* b1   = (const float*)d_in[5];
    const float* W2   = (const float*)d_in[6];
    const float* b2   = (const float*)d_in[7];
    const float* W3   = (const float*)d_in[8];
    const float* b3   = (const float*)d_in[9];
    const float* W4   = (const float*)d_in[10];
    const float* b4   = (const float*)d_in[11];
    const float* Wmu  = (const float*)d_in[12];
    const float* bmu  = (const float*)d_in[13];
    const float* Wlv  = (const float*)d_in[14];
    const float* blv  = (const float*)d_in[15];
    const float* Wdec = (const float*)d_in[16];
    const float* bdec = (const float*)d_in[17];
    const float* Wg1  = (const float*)d_in[18];
    const float* bg1  = (const float*)d_in[19];
    const float* Wg2  = (const float*)d_in[20];
    const float* bg2  = (const float*)d_in[21];
    const float* Wout = (const float*)d_in[22];
    const float* bout = (const float*)d_in[23];
    float* out = (float*)d_out;

    // ws layout (floats): ns | nd | rp | cols8 | agg | h1 | h2 | h3 | h4
    // agg: cs/cd ints pre-CSR; mu/lv MFMA partials (64x65536 = 4M floats) later.
    // h2 region: z at [0,32768) + WT bf16 (4M bf16 = 2M floats) at +65536 —
    //   both dead before the g1 GEMM rewrites h2.
    // h4 region: bf16 h4b from conv4 (2 MB of 16 MB), then latent fp32 (k_dec).
    float* ws   = (float*)d_ws;
    float* ns   = ws;
    float* nd   = ns + NN;
    int*   rp   = (int*)(nd + NN);                       // NN+1 ints (pad 65792)
    unsigned char* cols8 = (unsigned char*)(rp + 65792); // NE bytes
    float* agg  = (float*)(cols8 + NE);
    float* h1   = agg + (size_t)NN * HID;
    float* h2   = h1 + (size_t)NN * HID;
    float* h3   = h2 + (size_t)NN * HID;
    float* h4   = h3 + (size_t)NN * HID;
    float* z    = h2;                                    // 32768 floats
    __bf16* WT  = (__bf16*)(h2 + 65536);                 // 4M bf16
    __bf16* h4b = (__bf16*)h4;                           // 1M bf16

    // degrees -> norms -> CSR (once per launch; src/dst identical every call)
    int* cs = (int*)agg;
    int* cd = cs + NN;
    hipMemsetAsync(cs, 0, 2 * NN * sizeof(int), stream);
    k_deg_count<<<NE / 256, 256, 0, stream>>>(src, dst, cs, cd);
    k_norms<<<NN / 256, 256, 0, stream>>>(cs, cd, ns, nd);
    k_scan<<<NG, 256, 0, stream>>>(cd, rp);
    k_csr_fill<<<NG, 256, 0, stream>>>(src, dst, rp, cols8);

    // conv1
    k_gather16<<<NN * 4 / 256, 256, 0, stream>>>(raw, rp, cols8, ns, nd, agg);
    k_gemm64<true, false><<<NN / 64, 256, 0, stream>>>(agg, 16, nullptr, 0, nullptr, 0,
                                                       nullptr, 0, W1, b1, h1);
    // conv2
    k_gather64<<<NN * 16 / 256, 256, 0, stream>>>(h1, rp, cols8, ns, nd, nullptr, 0, agg);
    k_gemm64<true, false><<<NN / 64, 256, 0, stream>>>(agg, 64, nullptr, 0, nullptr, 0,
                                                       nullptr, 0, W2, b2, h2);
    // conv3 (h2 consumed here; WT build can start right after)
    k_gather64<<<NN * 16 / 256, 256, 0, stream>>>(h2, rp, cols8, ns, nd, nullptr, 0, agg);
    k_wcast<<<4096, 256, 0, stream>>>(Wmu, Wlv, WT);
    k_gemm64<true, false><<<NN / 64, 256, 0, stream>>>(agg, 64, nullptr, 0, nullptr, 0,
                                                       nullptr, 0, W3, b3, h3);
    // conv4 -> h4 in bf16 (consumed only by mu/lv MFMA)
    k_gather64<<<NN * 16 / 256, 256, 0, stream>>>(h3, rp, cols8, ns, nd, nullptr, 0, agg);
    k_gemm64<true, true><<<NN / 64, 256, 0, stream>>>(agg, 64, nullptr, 0, nullptr, 0,
                                                      nullptr, 0, W4, b4, h4);

    // mu/logvar via MFMA (partials in agg), z -> h2; latent overwrites h4
    k_mulv_mfma<<<1024, 256, 0, stream>>>(h4b, WT, agg);
    k_reduce<<<128, 256, 0, stream>>>(agg, bmu, blv, eps, out, z);
    k_dec<<<1024, 256, 0, stream>>>(z, Wdec, bdec, h4);

    // g1
    k_gemm64<false, false><<<NN / 64, 256, 0, stream>>>(h4, 64, raw, 16, h1, 64, h3, 64,
                                                        Wg1, nullptr, h2);
    k_gather64<<<NN * 16 / 256, 256, 0, stream>>>(h2, rp, cols8, ns, nd, bg1, 1, agg);

    // g2
    k_gather64<<<NN * 16 / 256, 256, 0, stream>>>(agg, rp, cols8, ns, nd, nullptr, 0, h2);
    k_gemm64<true, false><<<NN / 64, 256, 0, stream>>>(h2, 64, nullptr, 0, nullptr, 0,
                                                       nullptr, 0, Wg2, bg2, h3);

    // recon
    k_gemmout<<<NN / 64, 256, 0, stream>>>(h3, Wout, bout, raw, out);
}

// Round 8
// 359.107 us; speedup vs baseline: 6.0528x; 1.2803x over previous
//
#include <hip/hip_runtime.h>
#include <math.h>

// Problem constants (match reference setup_inputs()).
#define NG   256        // graphs
#define NP   256        // nodes per graph
#define NN   65536      // total nodes
#define NE   1048576    // edges
#define EPG  4096       // edges per graph
#define INF  16         // input feats
#define HID  64         // hidden
#define ZD   128        // latent dim
#define KFLAT 16384     // NP*HID

typedef _Float16 f16;
typedef f16  f16x8 __attribute__((ext_vector_type(8)));
typedef f16  f16x4 __attribute__((ext_vector_type(4)));
typedef float f32x4 __attribute__((ext_vector_type(4)));

#define PCH 72   // LDS pitch (f16) for 64-wide tiles: 2-way-conflict (free) b128 reads

// ---------------------------------------------------------------- degree ----
__global__ __launch_bounds__(256) void k_deg_count(const int* __restrict__ src,
                                                   const int* __restrict__ dst,
                                                   int* __restrict__ cs,
                                                   int* __restrict__ cd) {
    int e = blockIdx.x * 256 + threadIdx.x;
    atomicAdd(&cs[src[e]], 1);
    atomicAdd(&cd[dst[e]], 1);
}

__global__ __launch_bounds__(256) void k_norms(const int* __restrict__ cs,
                                               const int* __restrict__ cd,
                                               float* __restrict__ ns,
                                               float* __restrict__ nd) {
    int i = blockIdx.x * 256 + threadIdx.x;
    ns[i] = 1.0f / sqrtf((float)max(cs[i], 1));
    nd[i] = 1.0f / sqrtf((float)max(cd[i], 1));
}

// -------------------------------------------------------------- CSR build ----
__global__ __launch_bounds__(256) void k_scan(const int* __restrict__ cd,
                                              int* __restrict__ rp) {
    __shared__ int buf[NP];
    const int g = blockIdx.x, t = threadIdx.x;
    const int v0 = cd[g * NP + t];
    buf[t] = v0;
    __syncthreads();
    for (int off = 1; off < NP; off <<= 1) {
        int v = (t >= off) ? buf[t - off] : 0;
        __syncthreads();
        buf[t] += v;
        __syncthreads();
    }
    rp[g * NP + t] = g * EPG + buf[t] - v0;
    if (g == NG - 1 && t == NP - 1) rp[NN] = NE;
}

__global__ __launch_bounds__(256) void k_csr_fill(const int* __restrict__ src,
                                                  const int* __restrict__ dst,
                                                  const int* __restrict__ rp,
                                                  unsigned char* __restrict__ cols8) {
    __shared__ int cnt[NP];
    const int g = blockIdx.x, t = threadIdx.x;
    cnt[t] = 0;
    __syncthreads();
    const int base_e = g * EPG;
    for (int i = t; i < EPG; i += 256) {
        int s = src[base_e + i], d = dst[base_e + i];
        int p = atomicAdd(&cnt[d & (NP - 1)], 1);
        cols8[rp[d] + p] = (unsigned char)(s & (NP - 1));
    }
}

// ------------------------- dense normalized adjacency, f16 -------------------
// Ahat[g][d][s] = nd[g,d] * sum_{edges s->d} ns[g,s]
__global__ __launch_bounds__(256) void k_build_ahat(const int* __restrict__ rp,
                                                    const unsigned char* __restrict__ cols8,
                                                    const float* __restrict__ ns,
                                                    const float* __restrict__ nd,
                                                    f16* __restrict__ Ahat) {
    __shared__ float acc[32 * 256];
    const int g = blockIdx.x >> 3, ch = blockIdx.x & 7;
    const int t = threadIdx.x;
    for (int idx = t; idx < 8192; idx += 256) acc[idx] = 0.f;
    __syncthreads();
    {
        int dl = t >> 3, j = t & 7;
        int gn = g * 256 + ch * 32 + dl;
        int e1 = rp[gn + 1];
        for (int e = rp[gn] + j; e < e1; e += 8) {
            int s = cols8[e];
            atomicAdd(&acc[dl * 256 + s], ns[g * 256 + s]);
        }
    }
    __syncthreads();
    for (int idx = t; idx < 8192; idx += 256) {
        int dl = idx >> 8, s = idx & 255;
        float v = acc[idx] * nd[g * 256 + ch * 32 + dl];
        Ahat[(((size_t)(g * 256 + ch * 32 + dl)) << 8) | s] = (f16)v;
    }
}

// --------------------- fp32 [node][F] -> f16 feat-major [g][F][256] ----------
template<int F>
__global__ __launch_bounds__(256) void k_xpose(const float* __restrict__ src,
                                               f16* __restrict__ dst) {
    __shared__ float ls[64 * (F + 1)];
    const int g = blockIdx.x >> 2, nb = blockIdx.x & 3;
    const int t = threadIdx.x;
    for (int idx = t; idx < 64 * F; idx += 256) {
        int n = idx / F, f = idx % F;
        ls[n * (F + 1) + f] = src[((size_t)(g * 256 + nb * 64 + n)) * F + f];
    }
    __syncthreads();
    constexpr int TPF = 256 / F;       // threads per feature row
    constexpr int NPT = 64 / TPF;      // nodes per thread
    int f = t / TPF, n0 = (t % TPF) * NPT;
    for (int i = 0; i < NPT; i += 4) {
        f16x4 v;
        for (int j = 0; j < 4; ++j) v[j] = (f16)ls[(n0 + i + j) * (F + 1) + f];
        *(f16x4*)&dst[((size_t)g * F + f) * 256 + nb * 64 + n0 + i] = v;
    }
}

// --------------------- small weights -> f16 transposed [of][K2pad] -----------
// layout in wb: W1t[64][32]@0, W2t[64][64]@2048, W3t@6144, W4t@10240,
//               Wg2t@14336, Wg1t[64][224]@18432 (rows>=srcK zero-padded)
__global__ __launch_bounds__(256) void k_wtr(const float* __restrict__ W1,
                                             const float* __restrict__ W2,
                                             const float* __restrict__ W3,
                                             const float* __restrict__ W4,
                                             const float* __restrict__ Wg2,
                                             const float* __restrict__ Wg1,
                                             f16* __restrict__ wb) {
    int idx = blockIdx.x * 256 + threadIdx.x;   // grid 128 -> 32768
    const float* src; int off, K2, srcK;
    if (idx < 2048)       { src = W1;  off = 0;     K2 = 32;  srcK = 16;  }
    else if (idx < 6144)  { src = W2;  off = 2048;  K2 = 64;  srcK = 64;  }
    else if (idx < 10240) { src = W3;  off = 6144;  K2 = 64;  srcK = 64;  }
    else if (idx < 14336) { src = W4;  off = 10240; K2 = 64;  srcK = 64;  }
    else if (idx < 18432) { src = Wg2; off = 14336; K2 = 64;  srcK = 64;  }
    else                  { src = Wg1; off = 18432; K2 = 224; srcK = 208; }
    int l = idx - off, of = l / K2, k = l % K2;
    wb[idx] = (k < srcK) ? (f16)src[k * 64 + of] : (f16)0.f;
}

// ----------------- fused GraphConv: y^T = relu((Ahat@x)@W + b) ---------------
// feat-major in/out. Grid NG*4 (64-dst chunks), 256 thr (4 waves).
// MTILES: input feat tiles (1->16f, 4->64f). STAGE2: apply W (else bias+relu
// directly on the aggregation — g1's gather-only). OUT_NM: node-major output
// (for h4 -> mulv).
template<int MTILES, bool STAGE2, bool OUT_NM>
__global__ __launch_bounds__(256) void k_conv(const f16* __restrict__ xin,
                                              const f16* __restrict__ Ahat,
                                              const f16* __restrict__ wt,
                                              const float* __restrict__ bias,
                                              f16* __restrict__ outp) {
    constexpr int FIN = MTILES * 16;
    constexpr int K2 = (MTILES == 1) ? 32 : 64;
    __shared__ f16 Xs[FIN * PCH];
    __shared__ f16 As[64 * PCH];            // aliased as yT in epilogue
    __shared__ f16 Ws[STAGE2 ? 64 * PCH : 1];
    __shared__ f16 Pt[STAGE2 ? 64 * PCH : 1];
    __shared__ float bs[64];
    const int g = blockIdx.x >> 2, nb = blockIdx.x & 3;
    const int t = threadIdx.x;
    const int w = t >> 6, lane = t & 63, m16 = lane & 15, q = lane >> 4;
    if (t < 64) bs[t] = bias[t];
    if constexpr (STAGE2) {
        for (int idx = t * 4; idx < 64 * K2; idx += 1024) {
            int of = idx / K2, k = idx % K2;
            *(f16x4*)&Ws[of * PCH + k] = *(const f16x4*)&wt[of * K2 + k];
        }
        if constexpr (MTILES == 1)          // zero K-pad cols 16..31 of Pt
            for (int idx = t; idx < 64 * 16; idx += 256)
                Pt[(idx >> 4) * PCH + 16 + (idx & 15)] = (f16)0.f;
    }
    f32x4 acc1[MTILES] = {};
    for (int kc = 0; kc < 4; ++kc) {        // K=256 src in chunks of 64
        for (int idx = t * 4; idx < FIN * 64; idx += 1024) {
            int f = idx >> 6, c = idx & 63;
            *(f16x4*)&Xs[f * PCH + c] =
                *(const f16x4*)&xin[((size_t)g * FIN + f) * 256 + kc * 64 + c];
        }
        for (int idx = t * 4; idx < 64 * 64; idx += 1024) {
            int d = idx >> 6, s = idx & 63;
            *(f16x4*)&As[d * PCH + s] =
                *(const f16x4*)&Ahat[((size_t)(g * 256 + nb * 64 + d)) * 256 + kc * 64 + s];
        }
        __syncthreads();
#pragma unroll
        for (int ks = 0; ks < 2; ++ks) {
            f16x8 b = *(const f16x8*)&As[(w * 16 + m16) * PCH + ks * 32 + q * 8];
#pragma unroll
            for (int mt = 0; mt < MTILES; ++mt) {
                f16x8 a = *(const f16x8*)&Xs[(mt * 16 + m16) * PCH + ks * 32 + q * 8];
                acc1[mt] = __builtin_amdgcn_mfma_f32_16x16x32_f16(a, b, acc1[mt], 0, 0, 0);
            }
        }
        __syncthreads();
    }
    // acc1: C1[m=f (mt*16+q*4+r)][n=d (w*16+m16)]
    f32x4 accF[4];
    if constexpr (STAGE2) {
#pragma unroll
        for (int mt = 0; mt < MTILES; ++mt) {
            f16x4 v = {(f16)acc1[mt][0], (f16)acc1[mt][1], (f16)acc1[mt][2], (f16)acc1[mt][3]};
            *(f16x4*)&Pt[(w * 16 + m16) * PCH + mt * 16 + q * 4] = v;   // Pt[d][f]
        }
        __syncthreads();
        f32x4 acc2[4] = {};
#pragma unroll
        for (int ks = 0; ks < K2 / 32; ++ks) {
            f16x8 b = *(const f16x8*)&Pt[(w * 16 + m16) * PCH + ks * 32 + q * 8];
#pragma unroll
            for (int mt = 0; mt < 4; ++mt) {
                f16x8 a = *(const f16x8*)&Ws[(mt * 16 + m16) * PCH + ks * 32 + q * 8];
                acc2[mt] = __builtin_amdgcn_mfma_f32_16x16x32_f16(a, b, acc2[mt], 0, 0, 0);
            }
        }
#pragma unroll
        for (int mt = 0; mt < 4; ++mt) accF[mt] = acc2[mt];
    } else {
#pragma unroll
        for (int mt = 0; mt < 4; ++mt) accF[mt] = acc1[mt % MTILES];
    }
    f16* yT = As;   // safe: As unread during stage2; all-waves sync already passed
#pragma unroll
    for (int mt = 0; mt < 4; ++mt)
#pragma unroll
        for (int r = 0; r < 4; ++r) {
            int of = mt * 16 + q * 4 + r;
            float v = fmaxf(accF[mt][r] + bs[of], 0.f);
            yT[of * PCH + w * 16 + m16] = (f16)v;
        }
    __syncthreads();
    if constexpr (!OUT_NM) {
        for (int idx = t * 4; idx < 4096; idx += 1024) {
            int of = idx >> 6, n = idx & 63;
            *(f16x4*)&outp[((size_t)g * 64 + of) * 256 + nb * 64 + n] =
                *(const f16x4*)&yT[of * PCH + n];
        }
    } else {
        int n = t >> 2, of0 = (t & 3) * 16;
        f16x8 v0, v1;
        for (int i = 0; i < 8; ++i) v0[i] = yT[(of0 + i) * PCH + n];
        for (int i = 0; i < 8; ++i) v1[i] = yT[(of0 + 8 + i) * PCH + n];
        size_t base = ((size_t)(g * 256 + nb * 64 + n)) * 64 + of0;
        *(f16x8*)&outp[base] = v0;
        *(f16x8*)&outp[base + 8] = v1;
    }
}

// --------------- t^T[g][64][256] = Wg1t[64][224] . cat^T[224][256] -----------
// cat^T rows: latent_t(0-63) | rawT(64-79) | h1t(80-143) | h3t(144-207) | 0-pad
#define PB 40
__global__ __launch_bounds__(256) void k_catgemm(const f16* __restrict__ lat,
                                                 const f16* __restrict__ rawT,
                                                 const f16* __restrict__ h1t,
                                                 const f16* __restrict__ h3t,
                                                 const f16* __restrict__ wg1t,
                                                 f16* __restrict__ tt) {
    __shared__ f16 Wsb[64 * PB];
    __shared__ f16 Bt[64 * PB];
    __shared__ f16 yT[64 * PCH];
    const int g = blockIdx.x >> 2, nb = blockIdx.x & 3;
    const int t = threadIdx.x, w = t >> 6, lane = t & 63, m16 = lane & 15, q = lane >> 4;
    f32x4 acc[4] = {};
    for (int kc = 0; kc < 7; ++kc) {
        for (int idx = t * 4; idx < 2048; idx += 1024) {
            int of = idx >> 5, k = idx & 31;
            *(f16x4*)&Wsb[of * PB + k] = *(const f16x4*)&wg1t[of * 224 + kc * 32 + k];
        }
        {
            int kr = t >> 3, n8 = (t & 7) * 8;
            int kin = kc * 32 + kr;
            const f16* sp = nullptr;
            if (kin < 64)       sp = lat  + ((size_t)g * 64 + kin) * 256;
            else if (kin < 80)  sp = rawT + ((size_t)g * 16 + (kin - 64)) * 256;
            else if (kin < 144) sp = h1t  + ((size_t)g * 64 + (kin - 80)) * 256;
            else if (kin < 208) sp = h3t  + ((size_t)g * 64 + (kin - 144)) * 256;
            f16x8 v = {};
            if (sp) v = *(const f16x8*)&sp[nb * 64 + n8];
            for (int i = 0; i < 8; ++i) Bt[(n8 + i) * PB + kr] = v[i];
        }
        __syncthreads();
        f16x8 b = *(const f16x8*)&Bt[(w * 16 + m16) * PB + q * 8];
#pragma unroll
        for (int mt = 0; mt < 4; ++mt) {
            f16x8 a = *(const f16x8*)&Wsb[(mt * 16 + m16) * PB + q * 8];
            acc[mt] = __builtin_amdgcn_mfma_f32_16x16x32_f16(a, b, acc[mt], 0, 0, 0);
        }
        __syncthreads();
    }
#pragma unroll
    for (int mt = 0; mt < 4; ++mt)
#pragma unroll
        for (int r = 0; r < 4; ++r)
            yT[(mt * 16 + q * 4 + r) * PCH + w * 16 + m16] = (f16)acc[mt][r];
    __syncthreads();
    for (int idx = t * 4; idx < 4096; idx += 1024) {
        int of = idx >> 6, n = idx & 63;
        *(f16x4*)&tt[((size_t)g * 64 + of) * 256 + nb * 64 + n] =
            *(const f16x4*)&yT[of * PCH + n];
    }
}

// ------------------------------- Wmu|Wlv -> WT f16 [256 jj][16384 k] ---------
__global__ __launch_bounds__(256) void k_wcast(const float* __restrict__ Wmu,
                                               const float* __restrict__ Wlv,
                                               f16* __restrict__ WT) {
    __shared__ float tile[32][33];
    const int bx = blockIdx.x;          // 512 k-tiles x 8 j-tiles
    const int kt = bx >> 3, jt = bx & 7;
    const int k0 = kt * 32, j0 = (jt & 3) * 32;
    const float* Wsel = (jt < 4) ? Wmu : Wlv;
    const int t = threadIdx.x;
    const int jl = t & 31, kl0 = t >> 5;
    for (int p = 0; p < 4; ++p) {
        int kl = kl0 + p * 8;
        tile[kl][jl] = Wsel[(size_t)(k0 + kl) * ZD + j0 + jl];
    }
    __syncthreads();
    const int kl2 = t & 31, jl0 = t >> 5;
    for (int p = 0; p < 4; ++p) {
        int jw = jl0 + p * 8;
        WT[(size_t)(jt * 32 + jw) * KFLAT + k0 + kl2] = (f16)tile[kl2][jw];
    }
}

// ------------------------------------- mu/logvar MFMA split-K GEMM -----------
#define BKP 136
__global__ __launch_bounds__(256) void k_mulv_mfma(const f16* __restrict__ h4b,
                                                   const f16* __restrict__ WT,
                                                   float* __restrict__ part) {
    __shared__ f16 Ab[64 * BKP];
    __shared__ f16 Bb[64 * BKP];
    const int bx = blockIdx.x;
    const int kc = bx & 63, jt = (bx >> 6) & 3, gt = bx >> 8;
    const int t = threadIdx.x;
    const int w = t >> 6, lane = t & 63;
    const int m16 = lane & 15, q = lane >> 4;
    f32x4 acc[4] = {};
    const int k0base = kc * 256;
    for (int ks = 0; ks < 2; ++ks) {
        const int k0 = k0base + ks * 128;
#pragma unroll
        for (int p = 0; p < 4; ++p) {
            int oct = t + p * 256;
            int r = oct >> 4, c8 = oct & 15;
            *(f16x8*)&Ab[r * BKP + c8 * 8] =
                *(const f16x8*)&h4b[(size_t)(gt * 64 + r) * KFLAT + k0 + c8 * 8];
            *(f16x8*)&Bb[r * BKP + c8 * 8] =
                *(const f16x8*)&WT[(size_t)(jt * 64 + r) * KFLAT + k0 + c8 * 8];
        }
        __syncthreads();
#pragma unroll
        for (int kk = 0; kk < 4; ++kk) {
            f16x8 a = *(const f16x8*)&Ab[(w * 16 + m16) * BKP + kk * 32 + q * 8];
#pragma unroll
            for (int nt = 0; nt < 4; ++nt) {
                f16x8 b = *(const f16x8*)&Bb[(nt * 16 + m16) * BKP + kk * 32 + q * 8];
                acc[nt] = __builtin_amdgcn_mfma_f32_16x16x32_f16(a, b, acc[nt], 0, 0, 0);
            }
        }
        __syncthreads();
    }
    const int pb = kc << 16;
#pragma unroll
    for (int nt = 0; nt < 4; ++nt) {
        const int jj = jt * 64 + nt * 16 + m16;
#pragma unroll
        for (int r = 0; r < 4; ++r) {
            int g = gt * 64 + w * 16 + q * 4 + r;
            part[pb + g * 256 + jj] = acc[nt][r];
        }
    }
}

// reduce partials -> mu, logvar (d_out) and z.
__global__ __launch_bounds__(256) void k_reduce(const float* __restrict__ part,
                                                const float* __restrict__ bmu,
                                                const float* __restrict__ blv,
                                                const float* __restrict__ eps,
                                                float* __restrict__ out,
                                                float* __restrict__ z) {
    const int idx = blockIdx.x * 256 + threadIdx.x;
    const int g = idx >> 7, j = idx & 127;
    float mu = bmu[j], lv = blv[j];
    for (int kc = 0; kc < 64; ++kc) {
        mu += part[(kc << 16) + g * 256 + j];
        lv += part[(kc << 16) + g * 256 + 128 + j];
    }
    out[1048576 + idx] = mu;
    out[1048576 + 32768 + idx] = lv;
    z[idx] = mu + eps[idx] * expf(0.5f * lv);
}

// --------------------------------------------- latent = z @ Wdec + bdec ------
__global__ __launch_bounds__(256) void k_dec(const float* __restrict__ z,
                                             const float* __restrict__ Wdec,
                                             const float* __restrict__ bdec,
                                             float* __restrict__ latent) {
    __shared__ float zT[ZD * 36];
    const int bx = blockIdx.x;
    const int gt = bx >> 7, nt = bx & 127;
    const int t = threadIdx.x;
    for (int idx = t; idx < 32 * ZD; idx += 256) {
        int gi = idx >> 7, k = idx & 127;
        zT[k * 36 + gi] = z[(gt * 32 + gi) * ZD + k];
    }
    __syncthreads();
    const int g4 = t >> 5, n4 = t & 31;
    const int n0 = nt * 128 + n4 * 4;
    const float* wp = &Wdec[n0];
    float acc[4][4] = {};
#pragma unroll
    for (int k = 0; k < ZD; k += 8) {
        float4 b[8];
#pragma unroll
        for (int u = 0; u < 8; ++u) b[u] = *(const float4*)&wp[(size_t)(k + u) * KFLAT];
#pragma unroll
        for (int u = 0; u < 8; ++u) {
            float4 a = *(const float4*)&zT[(k + u) * 36 + g4 * 4];
            float av[4] = {a.x, a.y, a.z, a.w};
#pragma unroll
            for (int r = 0; r < 4; ++r) {
                acc[r][0] += av[r] * b[u].x;
                acc[r][1] += av[r] * b[u].y;
                acc[r][2] += av[r] * b[u].z;
                acc[r][3] += av[r] * b[u].w;
            }
        }
    }
    float4 bd = *(const float4*)&bdec[n0];
#pragma unroll
    for (int r = 0; r < 4; ++r) {
        int g = gt * 32 + g4 * 4 + r;
        *(float4*)&latent[(size_t)g * KFLAT + n0] =
            make_float4(acc[r][0] + bd.x, acc[r][1] + bd.y, acc[r][2] + bd.z, acc[r][3] + bd.w);
    }
}

// ---------------------- recon = x2^T @ Wout + bout (col0 = raw) --------------
__global__ __launch_bounds__(256) void k_gemmout(const f16* __restrict__ x2t,
                                                 const float* __restrict__ Wout,
                                                 const float* __restrict__ bout,
                                                 const float* __restrict__ raw,
                                                 float* __restrict__ out) {
    __shared__ float WL[1024];
    const int g = blockIdx.x, t = threadIdx.x;
    for (int i = t; i < 1024; i += 256) WL[i] = Wout[i];
    __syncthreads();
    float acc[16];
    for (int of = 0; of < 16; ++of) acc[of] = bout[of];
    const f16* xp = x2t + (size_t)g * 64 * 256 + t;
#pragma unroll 4
    for (int f = 0; f < 64; ++f) {
        float xv = (float)xp[f * 256];
        for (int of = 0; of < 16; ++of) acc[of] += xv * WL[f * 16 + of];
    }
    size_t ob = ((size_t)(g * 256 + t)) * 16;
    acc[0] = raw[ob];
    for (int of4 = 0; of4 < 16; of4 += 4)
        *(float4*)&out[ob + of4] = make_float4(acc[of4], acc[of4 + 1], acc[of4 + 2], acc[of4 + 3]);
}

// ----------------------------------------------------------------- launch ----
extern "C" void kernel_launch(void* const* d_in, const int* in_sizes, int n_in,
                              void* d_out, int out_size, void* d_ws, size_t ws_size,
                              hipStream_t stream) {
    const float* raw  = (const float*)d_in[0];
    const int*   src  = (const int*)d_in[1];
    const int*   dst  = (const int*)d_in[2];
    const float* eps  = (const float*)d_in[3];
    const float* W1   = (const float*)d_in[4];
    const float* b1   = (const float*)d_in[5];
    const float* W2   = (const float*)d_in[6];
    const float* b2   = (const float*)d_in[7];
    const float* W3   = (const float*)d_in[8];
    const float* b3   = (const float*)d_in[9];
    const float* W4   = (const float*)d_in[10];
    const float* b4   = (const float*)d_in[11];
    const float* Wmu  = (const float*)d_in[12];
    const float* bmu  = (const float*)d_in[13];
    const float* Wlv  = (const float*)d_in[14];
    const float* blv  = (const float*)d_in[15];
    const float* Wdec = (const float*)d_in[16];
    const float* bdec = (const float*)d_in[17];
    const float* Wg1  = (const float*)d_in[18];
    const float* bg1  = (const float*)d_in[19];
    const float* Wg2  = (const float*)d_in[20];
    const float* bg2  = (const float*)d_in[21];
    const float* Wout = (const float*)d_in[22];
    const float* bout = (const float*)d_in[23];
    float* out = (float*)d_out;

    // workspace carve-up (~140 MB)
    char* p = (char*)d_ws;
    float* ns = (float*)p;            p += (size_t)NN * 4;
    float* nd = (float*)p;            p += (size_t)NN * 4;
    int*   rp = (int*)p;              p += (size_t)65792 * 4;
    unsigned char* cols8 = (unsigned char*)p;  p += NE;
    f16* Ahat = (f16*)p;              p += (size_t)NG * 256 * 256 * 2;   // 32 MB
    f16* WT   = (f16*)p;              p += (size_t)256 * KFLAT * 2;      // 8 MB
    f16* wb   = (f16*)p;              p += 65536;                        // 64 KB
    f16* rawT = (f16*)p;              p += (size_t)NG * 16 * 256 * 2;    // 2 MB
    f16* h1t  = (f16*)p;              p += (size_t)NN * 64 * 2;          // 8 MB
    f16* h2t  = (f16*)p;              p += (size_t)NN * 64 * 2;
    f16* h3t  = (f16*)p;              p += (size_t)NN * 64 * 2;
    f16* h4b  = (f16*)p;              p += (size_t)NN * 64 * 2;
    f16* latt = (f16*)p;              p += (size_t)NN * 64 * 2;
    f16* tt   = (f16*)p;              p += (size_t)NN * 64 * 2;
    f16* x1t  = (f16*)p;              p += (size_t)NN * 64 * 2;
    f16* x2t  = (f16*)p;              p += (size_t)NN * 64 * 2;
    float* latf = (float*)p;          p += (size_t)NG * KFLAT * 4;       // 16 MB
    float* z  = (float*)p;            p += (size_t)32768 * 4;
    float* part = (float*)p;          p += (size_t)64 * 65536 * 4;       // 16 MB

    f16* w1t  = wb;
    f16* w2t  = wb + 2048;
    f16* w3t  = wb + 6144;
    f16* w4t  = wb + 10240;
    f16* wg2t = wb + 14336;
    f16* wg1t = wb + 18432;

    // degrees -> norms -> CSR -> dense normalized adjacency (f16)
    int* cs = (int*)part;
    int* cd = cs + NN;
    hipMemsetAsync(cs, 0, 2 * NN * sizeof(int), stream);
    k_deg_count<<<NE / 256, 256, 0, stream>>>(src, dst, cs, cd);
    k_norms<<<NN / 256, 256, 0, stream>>>(cs, cd, ns, nd);
    k_scan<<<NG, 256, 0, stream>>>(cd, rp);
    k_csr_fill<<<NG, 256, 0, stream>>>(src, dst, rp, cols8);
    k_build_ahat<<<NG * 8, 256, 0, stream>>>(rp, cols8, ns, nd, Ahat);

    // one-time casts / transposes
    k_xpose<16><<<NG * 4, 256, 0, stream>>>(raw, rawT);
    k_wtr<<<128, 256, 0, stream>>>(W1, W2, W3, W4, Wg2, Wg1, wb);
    k_wcast<<<4096, 256, 0, stream>>>(Wmu, Wlv, WT);

    // encoder convs (fused gather+gemm, feat-major f16)
    k_conv<1, true, false><<<NG * 4, 256, 0, stream>>>(rawT, Ahat, w1t, b1, h1t);
    k_conv<4, true, false><<<NG * 4, 256, 0, stream>>>(h1t, Ahat, w2t, b2, h2t);
    k_conv<4, true, false><<<NG * 4, 256, 0, stream>>>(h2t, Ahat, w3t, b3, h3t);
    k_conv<4, true, true ><<<NG * 4, 256, 0, stream>>>(h3t, Ahat, w4t, b4, h4b);

    // mu/logvar -> z -> latent
    k_mulv_mfma<<<1024, 256, 0, stream>>>(h4b, WT, part);
    k_reduce<<<128, 256, 0, stream>>>(part, bmu, blv, eps, out, z);
    k_dec<<<1024, 256, 0, stream>>>(z, Wdec, bdec, latf);
    k_xpose<64><<<NG * 4, 256, 0, stream>>>(latf, latt);

    // decoder: t = cat @ Wg1 ; x1 = relu(Ahat@t + bg1) ; g2 conv ; out gemm
    k_catgemm<<<NG * 4, 256, 0, stream>>>(latt, rawT, h1t, h3t, wg1t, tt);
    k_conv<4, false, false><<<NG * 4, 256, 0, stream>>>(tt, Ahat, nullptr, bg1, x1t);
    k_conv<4, true, false><<<NG * 4, 256, 0, stream>>>(x1t, Ahat, wg2t, bg2, x2t);
    k_gemmout<<<NG, 256, 0, stream>>>(x2t, Wout, bout, raw, out);
}

// Round 9
// 291.843 us; speedup vs baseline: 7.4479x; 1.2305x over previous
//
#include <hip/hip_runtime.h>
#include <math.h>

// Problem constants (match reference setup_inputs()).
#define NG   256        // graphs
#define NP   256        // nodes per graph
#define NN   65536      // total nodes
#define NE   1048576    // edges
#define EPG  4096       // edges per graph
#define INF  16         // input feats
#define HID  64         // hidden
#define ZD   128        // latent dim
#define KFLAT 16384     // NP*HID

typedef _Float16 f16;
typedef f16  f16x8 __attribute__((ext_vector_type(8)));
typedef f16  f16x4 __attribute__((ext_vector_type(4)));
typedef float f32x4 __attribute__((ext_vector_type(4)));

#define PCH 72   // LDS pitch (f16) for 64-wide tiles: 2-way-conflict (free) b128 reads

// ---------------- fused per-graph preprocessing: degrees, norms, CSR ---------
// One block per graph. All atomics in LDS.
__global__ __launch_bounds__(256) void k_graph(const int* __restrict__ src,
                                               const int* __restrict__ dst,
                                               float* __restrict__ ns,
                                               float* __restrict__ nd,
                                               int* __restrict__ rp,
                                               unsigned char* __restrict__ cols8) {
    __shared__ unsigned short eds[EPG];   // (s<<8)|d
    __shared__ int cs_l[NP], cd_l[NP], buf[NP], cnt[NP];
    const int g = blockIdx.x, t = threadIdx.x;
    cs_l[t] = 0; cd_l[t] = 0;
    __syncthreads();
    for (int i = t; i < EPG; i += 256) {
        int s = src[g * EPG + i] & 255, d = dst[g * EPG + i] & 255;
        eds[i] = (unsigned short)((s << 8) | d);
        atomicAdd(&cs_l[s], 1);
        atomicAdd(&cd_l[d], 1);
    }
    __syncthreads();
    ns[g * NP + t] = rsqrtf((float)max(cs_l[t], 1));
    nd[g * NP + t] = rsqrtf((float)max(cd_l[t], 1));
    // exclusive scan of cd_l
    const int v0 = cd_l[t];
    buf[t] = v0;
    __syncthreads();
    for (int off = 1; off < NP; off <<= 1) {
        int v = (t >= off) ? buf[t - off] : 0;
        __syncthreads();
        buf[t] += v;
        __syncthreads();
    }
    const int rpl = buf[t] - v0;
    rp[g * NP + t] = g * EPG + rpl;
    if (g == NG - 1 && t == NP - 1) rp[NN] = NE;
    cd_l[t] = rpl;     // reuse as local row-pointer
    cnt[t] = 0;
    __syncthreads();
    for (int i = t; i < EPG; i += 256) {
        int e = eds[i], s = e >> 8, d = e & 255;
        int p = atomicAdd(&cnt[d], 1);
        cols8[g * EPG + cd_l[d] + p] = (unsigned char)s;
    }
}

// ------------------------- dense normalized adjacency, f16 -------------------
// Ahat[g][d][s] = nd[g,d] * sum_{edges s->d} ns[g,s]
__global__ __launch_bounds__(256) void k_build_ahat(const int* __restrict__ rp,
                                                    const unsigned char* __restrict__ cols8,
                                                    const float* __restrict__ ns,
                                                    const float* __restrict__ nd,
                                                    f16* __restrict__ Ahat) {
    __shared__ float acc[32 * 256];
    const int g = blockIdx.x >> 3, ch = blockIdx.x & 7;
    const int t = threadIdx.x;
    for (int idx = t; idx < 8192; idx += 256) acc[idx] = 0.f;
    __syncthreads();
    {
        int dl = t >> 3, j = t & 7;
        int gn = g * 256 + ch * 32 + dl;
        int e1 = rp[gn + 1];
        for (int e = rp[gn] + j; e < e1; e += 8) {
            int s = cols8[e];
            atomicAdd(&acc[dl * 256 + s], ns[g * 256 + s]);
        }
    }
    __syncthreads();
    for (int idx = t; idx < 8192; idx += 256) {
        int dl = idx >> 8, s = idx & 255;
        float v = acc[idx] * nd[g * 256 + ch * 32 + dl];
        Ahat[(((size_t)(g * 256 + ch * 32 + dl)) << 8) | s] = (f16)v;
    }
}

// --------------------- fp32 [node][F] -> f16 feat-major [g][F][256] ----------
template<int F>
__global__ __launch_bounds__(256) void k_xpose(const float* __restrict__ src,
                                               f16* __restrict__ dst) {
    __shared__ float ls[64 * (F + 1)];
    const int g = blockIdx.x >> 2, nb = blockIdx.x & 3;
    const int t = threadIdx.x;
    for (int idx = t; idx < 64 * F; idx += 256) {
        int n = idx / F, f = idx % F;
        ls[n * (F + 1) + f] = src[((size_t)(g * 256 + nb * 64 + n)) * F + f];
    }
    __syncthreads();
    constexpr int TPF = 256 / F;
    constexpr int NPT = 64 / TPF;
    int f = t / TPF, n0 = (t % TPF) * NPT;
    for (int i = 0; i < NPT; i += 4) {
        f16x4 v;
        for (int j = 0; j < 4; ++j) v[j] = (f16)ls[(n0 + i + j) * (F + 1) + f];
        *(f16x4*)&dst[((size_t)g * F + f) * 256 + nb * 64 + n0 + i] = v;
    }
}

// --------------------- small weights -> f16 transposed [of][K2pad] -----------
__global__ __launch_bounds__(256) void k_wtr(const float* __restrict__ W1,
                                             const float* __restrict__ W2,
                                             const float* __restrict__ W3,
                                             const float* __restrict__ W4,
                                             const float* __restrict__ Wg2,
                                             const float* __restrict__ Wg1,
                                             f16* __restrict__ wb) {
    int idx = blockIdx.x * 256 + threadIdx.x;   // grid 128 -> 32768
    const float* src; int off, K2, srcK;
    if (idx < 2048)       { src = W1;  off = 0;     K2 = 32;  srcK = 16;  }
    else if (idx < 6144)  { src = W2;  off = 2048;  K2 = 64;  srcK = 64;  }
    else if (idx < 10240) { src = W3;  off = 6144;  K2 = 64;  srcK = 64;  }
    else if (idx < 14336) { src = W4;  off = 10240; K2 = 64;  srcK = 64;  }
    else if (idx < 18432) { src = Wg2; off = 14336; K2 = 64;  srcK = 64;  }
    else                  { src = Wg1; off = 18432; K2 = 224; srcK = 208; }
    int l = idx - off, of = l / K2, k = l % K2;
    wb[idx] = (k < srcK) ? (f16)src[k * 64 + of] : (f16)0.f;
}

// ----------------- fused GraphConv: y^T = relu((Ahat@x)@W + b) ---------------
// 1024 threads, 4 wave-groups (one per 64-dst chunk); Xs/Ws shared across
// groups (x read once per graph). Pt and yT alias As[wg]. Grid NG.
template<int MTILES, bool STAGE2, bool OUT_NM>
__global__ __launch_bounds__(1024) void k_conv(const f16* __restrict__ xin,
                                               const f16* __restrict__ Ahat,
                                               const f16* __restrict__ wt,
                                               const float* __restrict__ bias,
                                               f16* __restrict__ outp) {
    constexpr int FIN = MTILES * 16;
    constexpr int K2 = (MTILES == 1) ? 32 : 64;
    __shared__ f16 Xs[FIN * PCH];
    __shared__ f16 As[4][64 * PCH];    // per group; aliased as Pt then yT
    __shared__ f16 Ws[STAGE2 ? 64 * PCH : 1];
    __shared__ float bs[64];
    const int g = blockIdx.x;
    const int t = threadIdx.x;
    const int wg = t >> 8;             // dst chunk 0..3
    const int tl = t & 255;
    const int wl = (t >> 6) & 3;       // wave within group
    const int lane = t & 63, m16 = lane & 15, q = lane >> 4;
    if (t < 64) bs[t] = bias[t];
    if constexpr (STAGE2) {
        for (int idx = t * 4; idx < 64 * K2; idx += 4096) {
            int of = idx / K2, k = idx % K2;
            *(f16x4*)&Ws[of * PCH + k] = *(const f16x4*)&wt[of * K2 + k];
        }
    }
    f32x4 acc1[MTILES] = {};
    for (int kc = 0; kc < 4; ++kc) {
        for (int idx = t * 4; idx < FIN * 64; idx += 4096) {
            int f = idx >> 6, c = idx & 63;
            *(f16x4*)&Xs[f * PCH + c] =
                *(const f16x4*)&xin[((size_t)g * FIN + f) * 256 + kc * 64 + c];
        }
        for (int idx = tl * 4; idx < 4096; idx += 1024) {
            int d = idx >> 6, s = idx & 63;
            *(f16x4*)&As[wg][d * PCH + s] =
                *(const f16x4*)&Ahat[((size_t)(g * 256 + wg * 64 + d)) * 256 + kc * 64 + s];
        }
        __syncthreads();
#pragma unroll
        for (int ks = 0; ks < 2; ++ks) {
            f16x8 b = *(const f16x8*)&As[wg][(wl * 16 + m16) * PCH + ks * 32 + q * 8];
#pragma unroll
            for (int mt = 0; mt < MTILES; ++mt) {
                f16x8 a = *(const f16x8*)&Xs[(mt * 16 + m16) * PCH + ks * 32 + q * 8];
                acc1[mt] = __builtin_amdgcn_mfma_f32_16x16x32_f16(a, b, acc1[mt], 0, 0, 0);
            }
        }
        __syncthreads();
    }
    // acc1: C1[m=f][n=d]; d = wl*16+m16 within chunk wg
    f32x4 accF[4];
    if constexpr (STAGE2) {
        f16* Pt = As[wg];              // safe: last As reads done (loop-end sync)
        if constexpr (MTILES == 1)     // zero K-pad cols 16..31
            for (int idx = tl; idx < 64 * 16; idx += 256)
                Pt[(idx >> 4) * PCH + 16 + (idx & 15)] = (f16)0.f;
#pragma unroll
        for (int mt = 0; mt < MTILES; ++mt) {
            f16x4 v = {(f16)acc1[mt][0], (f16)acc1[mt][1], (f16)acc1[mt][2], (f16)acc1[mt][3]};
            *(f16x4*)&Pt[(wl * 16 + m16) * PCH + mt * 16 + q * 4] = v;   // Pt[d][f]
        }
        __syncthreads();
        f32x4 acc2[4] = {};
#pragma unroll
        for (int ks = 0; ks < K2 / 32; ++ks) {
            f16x8 b = *(const f16x8*)&Pt[(wl * 16 + m16) * PCH + ks * 32 + q * 8];
#pragma unroll
            for (int mt = 0; mt < 4; ++mt) {
                f16x8 a = *(const f16x8*)&Ws[(mt * 16 + m16) * PCH + ks * 32 + q * 8];
                acc2[mt] = __builtin_amdgcn_mfma_f32_16x16x32_f16(a, b, acc2[mt], 0, 0, 0);
            }
        }
#pragma unroll
        for (int mt = 0; mt < 4; ++mt) accF[mt] = acc2[mt];
        __syncthreads();               // Pt fully consumed before yT overwrite
    } else {
#pragma unroll
        for (int mt = 0; mt < 4; ++mt) accF[mt] = acc1[mt % MTILES];
    }
    f16* yT = As[wg];
#pragma unroll
    for (int mt = 0; mt < 4; ++mt)
#pragma unroll
        for (int r = 0; r < 4; ++r) {
            int of = mt * 16 + q * 4 + r;
            float v = fmaxf(accF[mt][r] + bs[of], 0.f);
            yT[of * PCH + wl * 16 + m16] = (f16)v;
        }
    __syncthreads();
    if constexpr (!OUT_NM) {
        for (int idx = tl * 4; idx < 4096; idx += 1024) {
            int of = idx >> 6, n = idx & 63;
            *(f16x4*)&outp[((size_t)g * 64 + of) * 256 + wg * 64 + n] =
                *(const f16x4*)&yT[of * PCH + n];
        }
    } else {
        int n = tl >> 2, of0 = (tl & 3) * 16;
        f16x8 v0, v1;
        for (int i = 0; i < 8; ++i) v0[i] = yT[(of0 + i) * PCH + n];
        for (int i = 0; i < 8; ++i) v1[i] = yT[(of0 + 8 + i) * PCH + n];
        size_t base = ((size_t)(g * 256 + wg * 64 + n)) * 64 + of0;
        *(f16x8*)&outp[base] = v0;
        *(f16x8*)&outp[base + 8] = v1;
    }
}

// --------------- t^T[g][64][256] = Wg1t[64][224] . cat^T[224][256] -----------
#define PB 40
__global__ __launch_bounds__(256) void k_catgemm(const f16* __restrict__ lat,
                                                 const f16* __restrict__ rawT,
                                                 const f16* __restrict__ h1t,
                                                 const f16* __restrict__ h3t,
                                                 const f16* __restrict__ wg1t,
                                                 f16* __restrict__ tt) {
    __shared__ f16 Wsb[64 * PB];
    __shared__ f16 Bt[64 * PB];
    __shared__ f16 yT[64 * PCH];
    const int g = blockIdx.x >> 2, nb = blockIdx.x & 3;
    const int t = threadIdx.x, w = t >> 6, lane = t & 63, m16 = lane & 15, q = lane >> 4;
    f32x4 acc[4] = {};
    for (int kc = 0; kc < 7; ++kc) {
        for (int idx = t * 4; idx < 2048; idx += 1024) {
            int of = idx >> 5, k = idx & 31;
            *(f16x4*)&Wsb[of * PB + k] = *(const f16x4*)&wg1t[of * 224 + kc * 32 + k];
        }
        {
            int kr = t >> 3, n8 = (t & 7) * 8;
            int kin = kc * 32 + kr;
            const f16* sp = nullptr;
            if (kin < 64)       sp = lat  + ((size_t)g * 64 + kin) * 256;
            else if (kin < 80)  sp = rawT + ((size_t)g * 16 + (kin - 64)) * 256;
            else if (kin < 144) sp = h1t  + ((size_t)g * 64 + (kin - 80)) * 256;
            else if (kin < 208) sp = h3t  + ((size_t)g * 64 + (kin - 144)) * 256;
            f16x8 v = {};
            if (sp) v = *(const f16x8*)&sp[nb * 64 + n8];
            for (int i = 0; i < 8; ++i) Bt[(n8 + i) * PB + kr] = v[i];
        }
        __syncthreads();
        f16x8 b = *(const f16x8*)&Bt[(w * 16 + m16) * PB + q * 8];
#pragma unroll
        for (int mt = 0; mt < 4; ++mt) {
            f16x8 a = *(const f16x8*)&Wsb[(mt * 16 + m16) * PB + q * 8];
            acc[mt] = __builtin_amdgcn_mfma_f32_16x16x32_f16(a, b, acc[mt], 0, 0, 0);
        }
        __syncthreads();
    }
#pragma unroll
    for (int mt = 0; mt < 4; ++mt)
#pragma unroll
        for (int r = 0; r < 4; ++r)
            yT[(mt * 16 + q * 4 + r) * PCH + w * 16 + m16] = (f16)acc[mt][r];
    __syncthreads();
    for (int idx = t * 4; idx < 4096; idx += 1024) {
        int of = idx >> 6, n = idx & 63;
        *(f16x4*)&tt[((size_t)g * 64 + of) * 256 + nb * 64 + n] =
            *(const f16x4*)&yT[of * PCH + n];
    }
}

// ------------------------------- Wmu|Wlv -> WT f16 [256 jj][16384 k] ---------
__global__ __launch_bounds__(256) void k_wcast(const float* __restrict__ Wmu,
                                               const float* __restrict__ Wlv,
                                               f16* __restrict__ WT) {
    __shared__ float tile[32][33];
    const int bx = blockIdx.x;          // 512 k-tiles x 8 j-tiles
    const int kt = bx >> 3, jt = bx & 7;
    const int k0 = kt * 32, j0 = (jt & 3) * 32;
    const float* Wsel = (jt < 4) ? Wmu : Wlv;
    const int t = threadIdx.x;
    const int jl = t & 31, kl0 = t >> 5;
    for (int p = 0; p < 4; ++p) {
        int kl = kl0 + p * 8;
        tile[kl][jl] = Wsel[(size_t)(k0 + kl) * ZD + j0 + jl];
    }
    __syncthreads();
    const int kl2 = t & 31, jl0 = t >> 5;
    for (int p = 0; p < 4; ++p) {
        int jw = jl0 + p * 8;
        WT[(size_t)(jt * 32 + jw) * KFLAT + k0 + kl2] = (f16)tile[kl2][jw];
    }
}

// --------------- Wdec permute-cast: Wdpt[h*256+n][k] = Wdec[k][n*64+h] -------
__global__ __launch_bounds__(256) void k_wdp(const float* __restrict__ Wdec,
                                             f16* __restrict__ Wdpt) {
    __shared__ float ls[4][2080];       // jl stored at jl + (jl>>6): stride-65 reads
    const int kc = blockIdx.x >> 3, nc = blockIdx.x & 7;   // grid 256
    const int k0 = kc * 4, n0 = nc * 32;
    const int t = threadIdx.x;
    for (int idx = t; idx < 8192; idx += 256) {
        int kk = idx >> 11, jl = idx & 2047;
        ls[kk][jl + (jl >> 6)] = Wdec[(size_t)(k0 + kk) * KFLAT + n0 * 64 + jl];
    }
    __syncthreads();
    for (int p = 0; p < 8; ++p) {
        int lin = p * 256 + t;          // 0..2047
        int h = lin >> 5, nl = lin & 31;
        int js = nl * 65 + h;
        f16x4 v = {(f16)ls[0][js], (f16)ls[1][js], (f16)ls[2][js], (f16)ls[3][js]};
        *(f16x4*)&Wdpt[(size_t)(h * 256 + n0 + nl) * ZD + k0] = v;
    }
}

// ------------------------------------- mu/logvar MFMA split-K GEMM -----------
#define BKP 136
__global__ __launch_bounds__(256) void k_mulv_mfma(const f16* __restrict__ h4b,
                                                   const f16* __restrict__ WT,
                                                   float* __restrict__ part) {
    __shared__ f16 Ab[64 * BKP];
    __shared__ f16 Bb[64 * BKP];
    const int bx = blockIdx.x;
    const int kc = bx & 63, jt = (bx >> 6) & 3, gt = bx >> 8;
    const int t = threadIdx.x;
    const int w = t >> 6, lane = t & 63;
    const int m16 = lane & 15, q = lane >> 4;
    f32x4 acc[4] = {};
    const int k0base = kc * 256;
    for (int ks = 0; ks < 2; ++ks) {
        const int k0 = k0base + ks * 128;
#pragma unroll
        for (int p = 0; p < 4; ++p) {
            int oct = t + p * 256;
            int r = oct >> 4, c8 = oct & 15;
            *(f16x8*)&Ab[r * BKP + c8 * 8] =
                *(const f16x8*)&h4b[(size_t)(gt * 64 + r) * KFLAT + k0 + c8 * 8];
            *(f16x8*)&Bb[r * BKP + c8 * 8] =
                *(const f16x8*)&WT[(size_t)(jt * 64 + r) * KFLAT + k0 + c8 * 8];
        }
        __syncthreads();
#pragma unroll
        for (int kk = 0; kk < 4; ++kk) {
            f16x8 a = *(const f16x8*)&Ab[(w * 16 + m16) * BKP + kk * 32 + q * 8];
#pragma unroll
            for (int nt = 0; nt < 4; ++nt) {
                f16x8 b = *(const f16x8*)&Bb[(nt * 16 + m16) * BKP + kk * 32 + q * 8];
                acc[nt] = __builtin_amdgcn_mfma_f32_16x16x32_f16(a, b, acc[nt], 0, 0, 0);
            }
        }
        __syncthreads();
    }
    const int pb = kc << 16;
#pragma unroll
    for (int nt = 0; nt < 4; ++nt) {
        const int jj = jt * 64 + nt * 16 + m16;
#pragma unroll
        for (int r = 0; r < 4; ++r) {
            int g = gt * 64 + w * 16 + q * 4 + r;
            part[pb + g * 256 + jj] = acc[nt][r];
        }
    }
}

// reduce partials -> mu, logvar (d_out) and z (f16).
__global__ __launch_bounds__(256) void k_reduce(const float* __restrict__ part,
                                                const float* __restrict__ bmu,
                                                const float* __restrict__ blv,
                                                const float* __restrict__ eps,
                                                float* __restrict__ out,
                                                f16* __restrict__ zb) {
    const int idx = blockIdx.x * 256 + threadIdx.x;
    const int g = idx >> 7, j = idx & 127;
    float mu = bmu[j], lv = blv[j];
    for (int kc = 0; kc < 64; ++kc) {
        mu += part[(kc << 16) + g * 256 + j];
        lv += part[(kc << 16) + g * 256 + 128 + j];
    }
    out[1048576 + idx] = mu;
    out[1048576 + 32768 + idx] = lv;
    zb[idx] = (f16)(mu + eps[idx] * expf(0.5f * lv));
}

// ----------- latt[g][h*256+n] = (z @ Wdec)[g][n*64+h] + bdec, via MFMA -------
#define DKP 136
__global__ __launch_bounds__(256) void k_decgemm(const f16* __restrict__ zb,
                                                 const f16* __restrict__ Wdpt,
                                                 const float* __restrict__ bdec,
                                                 f16* __restrict__ latt) {
    __shared__ f16 Az[64 * DKP];
    __shared__ f16 Bz[128 * DKP];
    const int gt = blockIdx.x >> 7, jt = blockIdx.x & 127;   // grid 512
    const int t = threadIdx.x, w = t >> 6, lane = t & 63, m16 = lane & 15, q = lane >> 4;
    for (int idx = t * 8; idx < 64 * 128; idx += 2048) {
        int r = idx >> 7, c = idx & 127;
        *(f16x8*)&Az[r * DKP + c] = *(const f16x8*)&zb[(gt * 64 + r) * ZD + c];
    }
    for (int idx = t * 8; idx < 128 * 128; idx += 2048) {
        int r = idx >> 7, c = idx & 127;
        *(f16x8*)&Bz[r * DKP + c] = *(const f16x8*)&Wdpt[((size_t)jt * 128 + r) * ZD + c];
    }
    __syncthreads();
    f32x4 acc[4][2] = {};
#pragma unroll
    for (int kk = 0; kk < 4; ++kk) {
        f16x8 b0 = *(const f16x8*)&Bz[(w * 32 + m16) * DKP + kk * 32 + q * 8];
        f16x8 b1 = *(const f16x8*)&Bz[(w * 32 + 16 + m16) * DKP + kk * 32 + q * 8];
#pragma unroll
        for (int mt = 0; mt < 4; ++mt) {
            f16x8 a = *(const f16x8*)&Az[(mt * 16 + m16) * DKP + kk * 32 + q * 8];
            acc[mt][0] = __builtin_amdgcn_mfma_f32_16x16x32_f16(a, b0, acc[mt][0], 0, 0, 0);
            acc[mt][1] = __builtin_amdgcn_mfma_f32_16x16x32_f16(a, b1, acc[mt][1], 0, 0, 0);
        }
    }
#pragma unroll
    for (int nt = 0; nt < 2; ++nt) {
        int jg = jt * 128 + w * 32 + nt * 16 + m16;
        int h = jg >> 8, n = jg & 255;
        float bd = bdec[n * 64 + h];
#pragma unroll
        for (int mt = 0; mt < 4; ++mt)
#pragma unroll
            for (int r = 0; r < 4; ++r) {
                int gg = gt * 64 + mt * 16 + q * 4 + r;
                latt[(size_t)gg * KFLAT + jg] = (f16)(acc[mt][nt][r] + bd);
            }
    }
}

// ---------------------- recon = x2^T @ Wout + bout (col0 = raw) --------------
__global__ __launch_bounds__(256) void k_gemmout(const f16* __restrict__ x2t,
                                                 const float* __restrict__ Wout,
                                                 const float* __restrict__ bout,
                                                 const float* __restrict__ raw,
                                                 float* __restrict__ out) {
    __shared__ float WL[1024];
    const int g = blockIdx.x, t = threadIdx.x;
    for (int i = t; i < 1024; i += 256) WL[i] = Wout[i];
    __syncthreads();
    float acc[16];
    for (int of = 0; of < 16; ++of) acc[of] = bout[of];
    const f16* xp = x2t + (size_t)g * 64 * 256 + t;
#pragma unroll 4
    for (int f = 0; f < 64; ++f) {
        float xv = (float)xp[f * 256];
        for (int of = 0; of < 16; ++of) acc[of] += xv * WL[f * 16 + of];
    }
    size_t ob = ((size_t)(g * 256 + t)) * 16;
    acc[0] = raw[ob];
    for (int of4 = 0; of4 < 16; of4 += 4)
        *(float4*)&out[ob + of4] = make_float4(acc[of4], acc[of4 + 1], acc[of4 + 2], acc[of4 + 3]);
}

// ----------------------------------------------------------------- launch ----
extern "C" void kernel_launch(void* const* d_in, const int* in_sizes, int n_in,
                              void* d_out, int out_size, void* d_ws, size_t ws_size,
                              hipStream_t stream) {
    const float* raw  = (const float*)d_in[0];
    const int*   src  = (const int*)d_in[1];
    const int*   dst  = (const int*)d_in[2];
    const float* eps  = (const float*)d_in[3];
    const float* W1   = (const float*)d_in[4];
    const float* b1   = (const float*)d_in[5];
    const float* W2   = (const float*)d_in[6];
    const float* b2   = (const float*)d_in[7];
    const float* W3   = (const float*)d_in[8];
    const float* b3   = (const float*)d_in[9];
    const float* W4   = (const float*)d_in[10];
    const float* b4   = (const float*)d_in[11];
    const float* Wmu  = (const float*)d_in[12];
    const float* bmu  = (const float*)d_in[13];
    const float* Wlv  = (const float*)d_in[14];
    const float* blv  = (const float*)d_in[15];
    const float* Wdec = (const float*)d_in[16];
    const float* bdec = (const float*)d_in[17];
    const float* Wg1  = (const float*)d_in[18];
    const float* bg1  = (const float*)d_in[19];
    const float* Wg2  = (const float*)d_in[20];
    const float* bg2  = (const float*)d_in[21];
    const float* Wout = (const float*)d_in[22];
    const float* bout = (const float*)d_in[23];
    float* out = (float*)d_out;

    // workspace carve-up (~125 MB)
    char* p = (char*)d_ws;
    float* ns = (float*)p;            p += (size_t)NN * 4;
    float* nd = (float*)p;            p += (size_t)NN * 4;
    int*   rp = (int*)p;              p += (size_t)65792 * 4;
    unsigned char* cols8 = (unsigned char*)p;  p += NE;
    f16* Ahat = (f16*)p;              p += (size_t)NG * 256 * 256 * 2;   // 32 MB
    f16* WT   = (f16*)p;              p += (size_t)256 * KFLAT * 2;      // 8 MB
    f16* Wdpt = (f16*)p;              p += (size_t)KFLAT * ZD * 2;       // 4 MB
    f16* wb   = (f16*)p;              p += 65536;                        // 64 KB
    f16* zb   = (f16*)p;              p += 65536;                        // 64 KB
    f16* rawT = (f16*)p;              p += (size_t)NG * 16 * 256 * 2;    // 2 MB
    f16* h1t  = (f16*)p;              p += (size_t)NN * 64 * 2;          // 8 MB each
    f16* h2t  = (f16*)p;              p += (size_t)NN * 64 * 2;
    f16* h3t  = (f16*)p;              p += (size_t)NN * 64 * 2;
    f16* h4b  = (f16*)p;              p += (size_t)NN * 64 * 2;
    f16* latt = (f16*)p;              p += (size_t)NN * 64 * 2;
    f16* tt   = (f16*)p;              p += (size_t)NN * 64 * 2;
    f16* x1t  = (f16*)p;              p += (size_t)NN * 64 * 2;
    f16* x2t  = (f16*)p;              p += (size_t)NN * 64 * 2;
    float* part = (float*)p;          p += (size_t)64 * 65536 * 4;       // 16 MB

    f16* w1t  = wb;
    f16* w2t  = wb + 2048;
    f16* w3t  = wb + 6144;
    f16* w4t  = wb + 10240;
    f16* wg2t = wb + 14336;
    f16* wg1t = wb + 18432;

    // fused preprocessing: degrees/norms/CSR in one kernel, then dense Ahat
    k_graph<<<NG, 256, 0, stream>>>(src, dst, ns, nd, rp, cols8);
    k_build_ahat<<<NG * 8, 256, 0, stream>>>(rp, cols8, ns, nd, Ahat);

    // one-time casts / transposes
    k_xpose<16><<<NG * 4, 256, 0, stream>>>(raw, rawT);
    k_wtr<<<128, 256, 0, stream>>>(W1, W2, W3, W4, Wg2, Wg1, wb);
    k_wcast<<<4096, 256, 0, stream>>>(Wmu, Wlv, WT);
    k_wdp<<<256, 256, 0, stream>>>(Wdec, Wdpt);

    // encoder convs (whole-graph blocks, x loaded once)
    k_conv<1, true, false><<<NG, 1024, 0, stream>>>(rawT, Ahat, w1t, b1, h1t);
    k_conv<4, true, false><<<NG, 1024, 0, stream>>>(h1t, Ahat, w2t, b2, h2t);
    k_conv<4, true, false><<<NG, 1024, 0, stream>>>(h2t, Ahat, w3t, b3, h3t);
    k_conv<4, true, true ><<<NG, 1024, 0, stream>>>(h3t, Ahat, w4t, b4, h4b);

    // mu/logvar -> z -> latent (all MFMA)
    k_mulv_mfma<<<1024, 256, 0, stream>>>(h4b, WT, part);
    k_reduce<<<128, 256, 0, stream>>>(part, bmu, blv, eps, out, zb);
    k_decgemm<<<512, 256, 0, stream>>>(zb, Wdpt, bdec, latt);

    // decoder: t = cat @ Wg1 ; x1 = relu(Ahat@t + bg1) ; g2 conv ; out gemm
    k_catgemm<<<NG * 4, 256, 0, stream>>>(latt, rawT, h1t, h3t, wg1t, tt);
    k_conv<4, false, false><<<NG, 1024, 0, stream>>>(tt, Ahat, nullptr, bg1, x1t);
    k_conv<4, true, false><<<NG, 1024, 0, stream>>>(x1t, Ahat, wg2t, bg2, x2t);
    k_gemmout<<<NG, 256, 0, stream>>>(x2t, Wout, bout, raw, out);
}

// Round 10
// 268.042 us; speedup vs baseline: 8.1092x; 1.0888x over previous
//
#include <hip/hip_runtime.h>
#include <math.h>

// Problem constants (match reference setup_inputs()).
#define NG   256        // graphs
#define NP   256        // nodes per graph
#define NN   65536      // total nodes
#define NE   1048576    // edges
#define EPG  4096       // edges per graph
#define INF  16         // input feats
#define HID  64         // hidden
#define ZD   128        // latent dim
#define KFLAT 16384     // NP*HID

typedef _Float16 f16;
typedef f16  f16x8 __attribute__((ext_vector_type(8)));
typedef f16  f16x4 __attribute__((ext_vector_type(4)));
typedef float f32x4 __attribute__((ext_vector_type(4)));

#define XPCH 264  // LDS pitch (f16) for whole-graph 64x256 feature buffers
#define PCH  72   // LDS pitch (f16) for 64-wide staging tiles

// -------- fused per-graph preprocessing + dense normalized adjacency ---------
// One block per graph; everything in LDS. Ahat[g][d][s] = nd[d]*sum(ns[s]).
__global__ __launch_bounds__(256) void k_graph_ahat(const int* __restrict__ src,
                                                    const int* __restrict__ dst,
                                                    f16* __restrict__ Ahat) {
    __shared__ unsigned short eds[EPG];            // 8 KB
    __shared__ int cs_l[NP], cd_l[NP], cnt[NP], buf[NP];
    __shared__ float ns_l[NP], nd_l[NP];
    __shared__ unsigned char cols_l[EPG];          // 4 KB
    __shared__ float acc[32 * 256];                // 32 KB
    const int g = blockIdx.x, t = threadIdx.x;
    cs_l[t] = 0; cd_l[t] = 0;
    __syncthreads();
    for (int i = t; i < EPG; i += 256) {
        int s = src[g * EPG + i] & 255, d = dst[g * EPG + i] & 255;
        eds[i] = (unsigned short)((s << 8) | d);
        atomicAdd(&cs_l[s], 1);
        atomicAdd(&cd_l[d], 1);
    }
    __syncthreads();
    ns_l[t] = rsqrtf((float)max(cs_l[t], 1));
    nd_l[t] = rsqrtf((float)max(cd_l[t], 1));
    const int v0 = cd_l[t];
    buf[t] = v0;
    __syncthreads();
    for (int off = 1; off < NP; off <<= 1) {
        int v = (t >= off) ? buf[t - off] : 0;
        __syncthreads();
        buf[t] += v;
        __syncthreads();
    }
    const int rpl = buf[t] - v0;                   // exclusive row start
    cd_l[t] = rpl;
    cnt[t] = 0;
    __syncthreads();
    for (int i = t; i < EPG; i += 256) {
        int e = eds[i], s = e >> 8, d = e & 255;
        int p = atomicAdd(&cnt[d], 1);
        cols_l[cd_l[d] + p] = (unsigned char)s;
    }
    __syncthreads();
    for (int ch = 0; ch < 8; ++ch) {
        for (int idx = t; idx < 8192; idx += 256) acc[idx] = 0.f;
        __syncthreads();
        {
            int dl = t >> 3, j = t & 7;            // 32 rows x 8 threads
            int d = ch * 32 + dl;
            int e0 = cd_l[d];
            int e1 = (d < 255) ? cd_l[d + 1] : EPG;
            for (int e = e0 + j; e < e1; e += 8) {
                int s = cols_l[e];
                atomicAdd(&acc[dl * 256 + s], ns_l[s]);
            }
        }
        __syncthreads();
        for (int idx = t; idx < 8192; idx += 256) {
            int dl = idx >> 8, s = idx & 255;
            Ahat[(((size_t)(g * 256 + ch * 32 + dl)) << 8) | s] =
                (f16)(acc[idx] * nd_l[ch * 32 + dl]);
        }
        __syncthreads();
    }
}

// -------------- fused one-time casts/transposes (blockIdx ranges) ------------
// [0,1024): raw -> rawT f16 feat-major; [1024,1152): small weights -> wb;
// [1152,5248): Wmu|Wlv -> WT; [5248,5504): Wdec -> Wdpt (permuted).
__global__ __launch_bounds__(256) void k_prep(const float* __restrict__ raw,
                                              const float* __restrict__ W1,
                                              const float* __restrict__ W2,
                                              const float* __restrict__ W3,
                                              const float* __restrict__ W4,
                                              const float* __restrict__ Wg2,
                                              const float* __restrict__ Wg1,
                                              const float* __restrict__ Wmu,
                                              const float* __restrict__ Wlv,
                                              const float* __restrict__ Wdec,
                                              f16* __restrict__ rawT,
                                              f16* __restrict__ wb,
                                              f16* __restrict__ WT,
                                              f16* __restrict__ Wdpt) {
    __shared__ float lsb[4 * 2080];                // 33.3 KB, shared by branches
    const int bx = blockIdx.x, t = threadIdx.x;
    if (bx < 1024) {                               // ---- rawT xpose (F=16)
        const int g = bx >> 2, nb = bx & 3;
        for (int idx = t; idx < 64 * 16; idx += 256) {
            int n = idx >> 4, f = idx & 15;
            lsb[n * 17 + f] = raw[((size_t)(g * 256 + nb * 64 + n)) * 16 + f];
        }
        __syncthreads();
        int f = t >> 4, n0 = (t & 15) * 4;
        f16x4 v;
        for (int j = 0; j < 4; ++j) v[j] = (f16)lsb[(n0 + j) * 17 + f];
        *(f16x4*)&rawT[((size_t)g * 16 + f) * 256 + nb * 64 + n0] = v;
    } else if (bx < 1152) {                        // ---- small weights
        int idx = (bx - 1024) * 256 + t;
        const float* srcp; int off, K2, srcK;
        if (idx < 2048)       { srcp = W1;  off = 0;     K2 = 32;  srcK = 16;  }
        else if (idx < 6144)  { srcp = W2;  off = 2048;  K2 = 64;  srcK = 64;  }
        else if (idx < 10240) { srcp = W3;  off = 6144;  K2 = 64;  srcK = 64;  }
        else if (idx < 14336) { srcp = W4;  off = 10240; K2 = 64;  srcK = 64;  }
        else if (idx < 18432) { srcp = Wg2; off = 14336; K2 = 64;  srcK = 64;  }
        else                  { srcp = Wg1; off = 18432; K2 = 224; srcK = 208; }
        int l = idx - off, of = l / K2, k = l % K2;
        wb[idx] = (k < srcK) ? (f16)srcp[k * 64 + of] : (f16)0.f;
    } else if (bx < 5248) {                        // ---- WT (Wmu|Wlv transposed)
        const int b2 = bx - 1152;
        const int kt = b2 >> 3, jt = b2 & 7;
        const int k0 = kt * 32, j0 = (jt & 3) * 32;
        const float* Wsel = (jt < 4) ? Wmu : Wlv;
        const int jl = t & 31, kl0 = t >> 5;
        for (int p = 0; p < 4; ++p) {
            int kl = kl0 + p * 8;
            lsb[kl * 33 + jl] = Wsel[(size_t)(k0 + kl) * ZD + j0 + jl];
        }
        __syncthreads();
        const int kl2 = t & 31, jl0 = t >> 5;
        for (int p = 0; p < 4; ++p) {
            int jw = jl0 + p * 8;
            WT[(size_t)(jt * 32 + jw) * KFLAT + k0 + kl2] = (f16)lsb[kl2 * 33 + jw];
        }
    } else {                                       // ---- Wdpt permute-cast
        const int b2 = bx - 5248;
        const int kc = b2 >> 3, nc = b2 & 7;
        const int k0 = kc * 4, n0 = nc * 32;
        float (*ls4)[2080] = (float(*)[2080])lsb;
        for (int idx = t; idx < 8192; idx += 256) {
            int kk = idx >> 11, jl = idx & 2047;
            ls4[kk][jl + (jl >> 6)] = Wdec[(size_t)(k0 + kk) * KFLAT + n0 * 64 + jl];
        }
        __syncthreads();
        for (int p = 0; p < 8; ++p) {
            int lin = p * 256 + t;
            int h = lin >> 5, nl = lin & 31;
            int js = nl * 65 + h;
            f16x4 v = {(f16)ls4[0][js], (f16)ls4[1][js], (f16)ls4[2][js], (f16)ls4[3][js]};
            *(f16x4*)&Wdpt[(size_t)(h * 256 + n0 + nl) * ZD + k0] = v;
        }
    }
}

// -------------------- fused encoder: 4 GraphConvs in one kernel --------------
// Grid NG, 1024 thr (4 wave-groups = 4 dst chunks). Whole-graph features
// double-buffered in LDS; Ahat streamed per conv. Writes h1t, h3t, h4b only.
__global__ __launch_bounds__(1024) void k_enc(const f16* __restrict__ rawT,
                                              const f16* __restrict__ Ahat,
                                              const f16* __restrict__ wb,
                                              const float* __restrict__ b1,
                                              const float* __restrict__ b2,
                                              const float* __restrict__ b3,
                                              const float* __restrict__ b4,
                                              f16* __restrict__ h1t,
                                              f16* __restrict__ h3t,
                                              f16* __restrict__ h4b) {
    __shared__ f16 XY[2][64 * XPCH];   // 67.6 KB
    __shared__ f16 As[4][64 * PCH];    // 36.9 KB, aliased as Pt per group
    __shared__ f16 Ws[64 * PCH];
    __shared__ float bs[64];
    const int g = blockIdx.x, t = threadIdx.x;
    const int wg = t >> 8, tl = t & 255, wl = (t >> 6) & 3;
    const int lane = t & 63, m16 = lane & 15, q = lane >> 4;
    // load rawT (16 feats) into XY[0]
    for (int idx = t * 8; idx < 16 * 256; idx += 8192) {
        int f = idx >> 8, n = idx & 255;
        *(f16x8*)&XY[0][f * XPCH + n] =
            *(const f16x8*)&rawT[((size_t)g * 16 + f) * 256 + n];
    }
    const int woff[4] = {0, 2048, 6144, 10240};
    const float* bptr[4] = {b1, b2, b3, b4};
    int cur = 0;
    for (int c = 0; c < 4; ++c) {
        const int MT = (c == 0) ? 1 : 4;
        const int K2 = (c == 0) ? 32 : 64;
        const f16* wt = wb + woff[c];
        if (t < 64) bs[t] = bptr[c][t];
        for (int idx = t * 4; idx < 64 * K2; idx += 4096) {
            int of = idx / K2, k = idx % K2;
            *(f16x4*)&Ws[of * PCH + k] = *(const f16x4*)&wt[of * K2 + k];
        }
        f32x4 acc1[4] = {};
        for (int kc = 0; kc < 4; ++kc) {
            for (int idx = tl * 4; idx < 4096; idx += 1024) {
                int d = idx >> 6, s = idx & 63;
                *(f16x4*)&As[wg][d * PCH + s] =
                    *(const f16x4*)&Ahat[((size_t)(g * 256 + wg * 64 + d)) * 256 + kc * 64 + s];
            }
            __syncthreads();
#pragma unroll
            for (int ks = 0; ks < 2; ++ks) {
                f16x8 b = *(const f16x8*)&As[wg][(wl * 16 + m16) * PCH + ks * 32 + q * 8];
                for (int mt = 0; mt < MT; ++mt) {
                    f16x8 a = *(const f16x8*)&XY[cur][(mt * 16 + m16) * XPCH + kc * 64 + ks * 32 + q * 8];
                    acc1[mt] = __builtin_amdgcn_mfma_f32_16x16x32_f16(a, b, acc1[mt], 0, 0, 0);
                }
            }
            __syncthreads();
        }
        // stage 2: (agg)@W via Pt = As[wg]
        {
            f16* Pt = As[wg];
            if (MT == 1)
                for (int idx = tl; idx < 1024; idx += 256)
                    Pt[(idx >> 4) * PCH + 16 + (idx & 15)] = (f16)0.f;
            for (int mt = 0; mt < MT; ++mt) {
                f16x4 v = {(f16)acc1[mt][0], (f16)acc1[mt][1],
                           (f16)acc1[mt][2], (f16)acc1[mt][3]};
                *(f16x4*)&Pt[(wl * 16 + m16) * PCH + mt * 16 + q * 4] = v;
            }
            __syncthreads();
            f32x4 acc2[4] = {};
            for (int ks = 0; ks < K2 / 32; ++ks) {
                f16x8 b = *(const f16x8*)&Pt[(wl * 16 + m16) * PCH + ks * 32 + q * 8];
#pragma unroll
                for (int mt = 0; mt < 4; ++mt) {
                    f16x8 a = *(const f16x8*)&Ws[(mt * 16 + m16) * PCH + ks * 32 + q * 8];
                    acc2[mt] = __builtin_amdgcn_mfma_f32_16x16x32_f16(a, b, acc2[mt], 0, 0, 0);
                }
            }
            f16* Yf = XY[cur ^ 1];
#pragma unroll
            for (int mt = 0; mt < 4; ++mt)
#pragma unroll
                for (int r = 0; r < 4; ++r) {
                    int of = mt * 16 + q * 4 + r;
                    float v = fmaxf(acc2[mt][r] + bs[of], 0.f);
                    Yf[of * XPCH + wg * 64 + wl * 16 + m16] = (f16)v;
                }
        }
        __syncthreads();
        cur ^= 1;
        const f16* Yv = XY[cur];
        if (c == 0) {
            for (int idx = t * 8; idx < 64 * 256; idx += 8192) {
                int of = idx >> 8, n = idx & 255;
                *(f16x8*)&h1t[((size_t)g * 64 + of) * 256 + n] =
                    *(const f16x8*)&Yv[of * XPCH + n];
            }
        } else if (c == 2) {
            for (int idx = t * 8; idx < 64 * 256; idx += 8192) {
                int of = idx >> 8, n = idx & 255;
                *(f16x8*)&h3t[((size_t)g * 64 + of) * 256 + n] =
                    *(const f16x8*)&Yv[of * XPCH + n];
            }
        } else if (c == 3) {
            int n = (t >> 2) & 255, of0 = (t & 3) * 16;
            f16x8 v0, v1;
            for (int i = 0; i < 8; ++i) v0[i] = Yv[(of0 + i) * XPCH + n];
            for (int i = 0; i < 8; ++i) v1[i] = Yv[(of0 + 8 + i) * XPCH + n];
            size_t base = ((size_t)(g * 256 + n)) * 64 + of0;
            *(f16x8*)&h4b[base] = v0;
            *(f16x8*)&h4b[base + 8] = v1;
        }
    }
}

// ------------------------------------- mu/logvar MFMA split-K GEMM -----------
#define BKP 136
__global__ __launch_bounds__(256) void k_mulv_mfma(const f16* __restrict__ h4b,
                                                   const f16* __restrict__ WT,
                                                   float* __restrict__ part) {
    __shared__ f16 Ab[64 * BKP];
    __shared__ f16 Bb[64 * BKP];
    const int bx = blockIdx.x;
    const int kc = bx & 63, jt = (bx >> 6) & 3, gt = bx >> 8;
    const int t = threadIdx.x;
    const int w = t >> 6, lane = t & 63;
    const int m16 = lane & 15, q = lane >> 4;
    f32x4 acc[4] = {};
    const int k0base = kc * 256;
    for (int ks = 0; ks < 2; ++ks) {
        const int k0 = k0base + ks * 128;
#pragma unroll
        for (int p = 0; p < 4; ++p) {
            int oct = t + p * 256;
            int r = oct >> 4, c8 = oct & 15;
            *(f16x8*)&Ab[r * BKP + c8 * 8] =
                *(const f16x8*)&h4b[(size_t)(gt * 64 + r) * KFLAT + k0 + c8 * 8];
            *(f16x8*)&Bb[r * BKP + c8 * 8] =
                *(const f16x8*)&WT[(size_t)(jt * 64 + r) * KFLAT + k0 + c8 * 8];
        }
        __syncthreads();
#pragma unroll
        for (int kk = 0; kk < 4; ++kk) {
            f16x8 a = *(const f16x8*)&Ab[(w * 16 + m16) * BKP + kk * 32 + q * 8];
#pragma unroll
            for (int nt = 0; nt < 4; ++nt) {
                f16x8 b = *(const f16x8*)&Bb[(nt * 16 + m16) * BKP + kk * 32 + q * 8];
                acc[nt] = __builtin_amdgcn_mfma_f32_16x16x32_f16(a, b, acc[nt], 0, 0, 0);
            }
        }
        __syncthreads();
    }
    const int pb = kc << 16;
#pragma unroll
    for (int nt = 0; nt < 4; ++nt) {
        const int jj = jt * 64 + nt * 16 + m16;
#pragma unroll
        for (int r = 0; r < 4; ++r) {
            int g = gt * 64 + w * 16 + q * 4 + r;
            part[pb + g * 256 + jj] = acc[nt][r];
        }
    }
}

// reduce partials -> mu, logvar (d_out) and z (f16).
__global__ __launch_bounds__(256) void k_reduce(const float* __restrict__ part,
                                                const float* __restrict__ bmu,
                                                const float* __restrict__ blv,
                                                const float* __restrict__ eps,
                                                float* __restrict__ out,
                                                f16* __restrict__ zb) {
    const int idx = blockIdx.x * 256 + threadIdx.x;
    const int g = idx >> 7, j = idx & 127;
    float mu = bmu[j], lv = blv[j];
    for (int kc = 0; kc < 64; ++kc) {
        mu += part[(kc << 16) + g * 256 + j];
        lv += part[(kc << 16) + g * 256 + 128 + j];
    }
    out[1048576 + idx] = mu;
    out[1048576 + 32768 + idx] = lv;
    zb[idx] = (f16)(mu + eps[idx] * expf(0.5f * lv));
}

// ----------- latt[g][h*256+n] = (z @ Wdec)[g][n*64+h] + bdec, via MFMA -------
#define DKP 136
__global__ __launch_bounds__(256) void k_decgemm(const f16* __restrict__ zb,
                                                 const f16* __restrict__ Wdpt,
                                                 const float* __restrict__ bdec,
                                                 f16* __restrict__ latt) {
    __shared__ f16 Az[64 * DKP];
    __shared__ f16 Bz[128 * DKP];
    const int gt = blockIdx.x >> 7, jt = blockIdx.x & 127;   // grid 512
    const int t = threadIdx.x, w = t >> 6, lane = t & 63, m16 = lane & 15, q = lane >> 4;
    for (int idx = t * 8; idx < 64 * 128; idx += 2048) {
        int r = idx >> 7, c = idx & 127;
        *(f16x8*)&Az[r * DKP + c] = *(const f16x8*)&zb[(gt * 64 + r) * ZD + c];
    }
    for (int idx = t * 8; idx < 128 * 128; idx += 2048) {
        int r = idx >> 7, c = idx & 127;
        *(f16x8*)&Bz[r * DKP + c] = *(const f16x8*)&Wdpt[((size_t)jt * 128 + r) * ZD + c];
    }
    __syncthreads();
    f32x4 acc[4][2] = {};
#pragma unroll
    for (int kk = 0; kk < 4; ++kk) {
        f16x8 b0 = *(const f16x8*)&Bz[(w * 32 + m16) * DKP + kk * 32 + q * 8];
        f16x8 b1 = *(const f16x8*)&Bz[(w * 32 + 16 + m16) * DKP + kk * 32 + q * 8];
#pragma unroll
        for (int mt = 0; mt < 4; ++mt) {
            f16x8 a = *(const f16x8*)&Az[(mt * 16 + m16) * DKP + kk * 32 + q * 8];
            acc[mt][0] = __builtin_amdgcn_mfma_f32_16x16x32_f16(a, b0, acc[mt][0], 0, 0, 0);
            acc[mt][1] = __builtin_amdgcn_mfma_f32_16x16x32_f16(a, b1, acc[mt][1], 0, 0, 0);
        }
    }
#pragma unroll
    for (int nt = 0; nt < 2; ++nt) {
        int jg = jt * 128 + w * 32 + nt * 16 + m16;
        int h = jg >> 8, n = jg & 255;
        float bd = bdec[n * 64 + h];
#pragma unroll
        for (int mt = 0; mt < 4; ++mt)
#pragma unroll
            for (int r = 0; r < 4; ++r) {
                int gg = gt * 64 + mt * 16 + q * 4 + r;
                latt[(size_t)gg * KFLAT + jg] = (f16)(acc[mt][nt][r] + bd);
            }
    }
}

// ----------------- fused decoder: catgemm, g1, g2, out GEMM ------------------
#define PB 40
__global__ __launch_bounds__(1024) void k_decfused(const f16* __restrict__ latt,
                                                   const f16* __restrict__ rawT,
                                                   const f16* __restrict__ h1t,
                                                   const f16* __restrict__ h3t,
                                                   const f16* __restrict__ Ahat,
                                                   const f16* __restrict__ wb,
                                                   const float* __restrict__ bg1,
                                                   const float* __restrict__ bg2,
                                                   const float* __restrict__ Wout,
                                                   const float* __restrict__ bout,
                                                   const float* __restrict__ raw,
                                                   float* __restrict__ out) {
    __shared__ f16 XY[2][64 * XPCH];   // 67.6 KB
    __shared__ f16 As[4][64 * PCH];    // 36.9 KB
    __shared__ f16 Ws[64 * PCH];
    __shared__ f16 Wsb[64 * PB];
    __shared__ f16 Bt[4][64 * PB];
    __shared__ float WL[1024];
    __shared__ float bs[64];
    const int g = blockIdx.x, t = threadIdx.x;
    const int wg = t >> 8, tl = t & 255, wl = (t >> 6) & 3;
    const int lane = t & 63, m16 = lane & 15, q = lane >> 4;
    const f16* wg1t = wb + 18432;
    const f16* wg2t = wb + 14336;
    // ---- phase 1: t^T = Wg1t . cat^T -> XY[0]
    {
        f32x4 acc[4] = {};
        for (int kc = 0; kc < 7; ++kc) {
            for (int idx = t * 4; idx < 2048; idx += 4096) {
                int of = idx >> 5, k = idx & 31;
                *(f16x4*)&Wsb[of * PB + k] = *(const f16x4*)&wg1t[of * 224 + kc * 32 + k];
            }
            {
                int kr = tl >> 3, n8 = (tl & 7) * 8;
                int kin = kc * 32 + kr;
                const f16* sp = nullptr;
                if (kin < 64)       sp = latt + ((size_t)g * 64 + kin) * 256;
                else if (kin < 80)  sp = rawT + ((size_t)g * 16 + (kin - 64)) * 256;
                else if (kin < 144) sp = h1t  + ((size_t)g * 64 + (kin - 80)) * 256;
                else if (kin < 208) sp = h3t  + ((size_t)g * 64 + (kin - 144)) * 256;
                f16x8 v = {};
                if (sp) v = *(const f16x8*)&sp[wg * 64 + n8];
                for (int i = 0; i < 8; ++i) Bt[wg][(n8 + i) * PB + kr] = v[i];
            }
            __syncthreads();
            f16x8 b = *(const f16x8*)&Bt[wg][(wl * 16 + m16) * PB + q * 8];
#pragma unroll
            for (int mt = 0; mt < 4; ++mt) {
                f16x8 a = *(const f16x8*)&Wsb[(mt * 16 + m16) * PB + q * 8];
                acc[mt] = __builtin_amdgcn_mfma_f32_16x16x32_f16(a, b, acc[mt], 0, 0, 0);
            }
            __syncthreads();
        }
#pragma unroll
        for (int mt = 0; mt < 4; ++mt)
#pragma unroll
            for (int r = 0; r < 4; ++r)
                XY[0][(mt * 16 + q * 4 + r) * XPCH + wg * 64 + wl * 16 + m16] =
                    (f16)acc[mt][r];
        __syncthreads();
    }
    // ---- phase 2: x1 = relu(Ahat @ t + bg1) -> XY[1] (gather-only)
    {
        if (t < 64) bs[t] = bg1[t];
        f32x4 acc1[4] = {};
        for (int kc = 0; kc < 4; ++kc) {
            for (int idx = tl * 4; idx < 4096; idx += 1024) {
                int d = idx >> 6, s = idx & 63;
                *(f16x4*)&As[wg][d * PCH + s] =
                    *(const f16x4*)&Ahat[((size_t)(g * 256 + wg * 64 + d)) * 256 + kc * 64 + s];
            }
            __syncthreads();
#pragma unroll
            for (int ks = 0; ks < 2; ++ks) {
                f16x8 b = *(const f16x8*)&As[wg][(wl * 16 + m16) * PCH + ks * 32 + q * 8];
#pragma unroll
                for (int mt = 0; mt < 4; ++mt) {
                    f16x8 a = *(const f16x8*)&XY[0][(mt * 16 + m16) * XPCH + kc * 64 + ks * 32 + q * 8];
                    acc1[mt] = __builtin_amdgcn_mfma_f32_16x16x32_f16(a, b, acc1[mt], 0, 0, 0);
                }
            }
            __syncthreads();
        }
#pragma unroll
        for (int mt = 0; mt < 4; ++mt)
#pragma unroll
            for (int r = 0; r < 4; ++r) {
                int of = mt * 16 + q * 4 + r;
                float v = fmaxf(acc1[mt][r] + bs[of], 0.f);
                XY[1][of * XPCH + wg * 64 + wl * 16 + m16] = (f16)v;
            }
        __syncthreads();
    }
    // ---- phase 3: x2 = relu((Ahat @ x1)@Wg2 + bg2) -> XY[0]
    {
        if (t < 64) bs[t] = bg2[t];
        for (int idx = t * 4; idx < 4096; idx += 4096) {
            int of = idx >> 6, k = idx & 63;
            *(f16x4*)&Ws[of * PCH + k] = *(const f16x4*)&wg2t[of * 64 + k];
        }
        f32x4 acc1[4] = {};
        for (int kc = 0; kc < 4; ++kc) {
            for (int idx = tl * 4; idx < 4096; idx += 1024) {
                int d = idx >> 6, s = idx & 63;
                *(f16x4*)&As[wg][d * PCH + s] =
                    *(const f16x4*)&Ahat[((size_t)(g * 256 + wg * 64 + d)) * 256 + kc * 64 + s];
            }
            __syncthreads();
#pragma unroll
            for (int ks = 0; ks < 2; ++ks) {
                f16x8 b = *(const f16x8*)&As[wg][(wl * 16 + m16) * PCH + ks * 32 + q * 8];
#pragma unroll
                for (int mt = 0; mt < 4; ++mt) {
                    f16x8 a = *(const f16x8*)&XY[1][(mt * 16 + m16) * XPCH + kc * 64 + ks * 32 + q * 8];
                    acc1[mt] = __builtin_amdgcn_mfma_f32_16x16x32_f16(a, b, acc1[mt], 0, 0, 0);
                }
            }
            __syncthreads();
        }
        f16* Pt = As[wg];
#pragma unroll
        for (int mt = 0; mt < 4; ++mt) {
            f16x4 v = {(f16)acc1[mt][0], (f16)acc1[mt][1],
                       (f16)acc1[mt][2], (f16)acc1[mt][3]};
            *(f16x4*)&Pt[(wl * 16 + m16) * PCH + mt * 16 + q * 4] = v;
        }
        __syncthreads();
        f32x4 acc2[4] = {};
#pragma unroll
        for (int ks = 0; ks < 2; ++ks) {
            f16x8 b = *(const f16x8*)&Pt[(wl * 16 + m16) * PCH + ks * 32 + q * 8];
#pragma unroll
            for (int mt = 0; mt < 4; ++mt) {
                f16x8 a = *(const f16x8*)&Ws[(mt * 16 + m16) * PCH + ks * 32 + q * 8];
                acc2[mt] = __builtin_amdgcn_mfma_f32_16x16x32_f16(a, b, acc2[mt], 0, 0, 0);
            }
        }
#pragma unroll
        for (int mt = 0; mt < 4; ++mt)
#pragma unroll
            for (int r = 0; r < 4; ++r) {
                int of = mt * 16 + q * 4 + r;
                float v = fmaxf(acc2[mt][r] + bs[of], 0.f);
                XY[0][of * XPCH + wg * 64 + wl * 16 + m16] = (f16)v;
            }
        __syncthreads();
    }
    // ---- phase 4: recon = x2^T @ Wout + bout (col0 = raw)
    {
        WL[t & 1023] = Wout[t & 1023];
        __syncthreads();
        int n = t & 255, og = t >> 8;
        float acc4[4];
        for (int j = 0; j < 4; ++j) acc4[j] = bout[og * 4 + j];
#pragma unroll 4
        for (int f = 0; f < 64; ++f) {
            float xv = (float)XY[0][f * XPCH + n];
            for (int j = 0; j < 4; ++j) acc4[j] += xv * WL[f * 16 + og * 4 + j];
        }
        size_t ob = ((size_t)(g * 256 + n)) * 16 + og * 4;
        if (og == 0) acc4[0] = raw[((size_t)(g * 256 + n)) * 16];
        *(float4*)&out[ob] = make_float4(acc4[0], acc4[1], acc4[2], acc4[3]);
    }
}

// ----------------------------------------------------------------- launch ----
extern "C" void kernel_launch(void* const* d_in, const int* in_sizes, int n_in,
                              void* d_out, int out_size, void* d_ws, size_t ws_size,
                              hipStream_t stream) {
    const float* raw  = (const float*)d_in[0];
    const int*   src  = (const int*)d_in[1];
    const int*   dst  = (const int*)d_in[2];
    const float* eps  = (const float*)d_in[3];
    const float* W1   = (const float*)d_in[4];
    const float* b1   = (const float*)d_in[5];
    const float* W2   = (const float*)d_in[6];
    const float* b2   = (const float*)d_in[7];
    const float* W3   = (const float*)d_in[8];
    const float* b3   = (const float*)d_in[9];
    const float* W4   = (const float*)d_in[10];
    const float* b4   = (const float*)d_in[11];
    const float* Wmu  = (const float*)d_in[12];
    const float* bmu  = (const float*)d_in[13];
    const float* Wlv  = (const float*)d_in[14];
    const float* blv  = (const float*)d_in[15];
    const float* Wdec = (const float*)d_in[16];
    const float* bdec = (const float*)d_in[17];
    const float* Wg1  = (const float*)d_in[18];
    const float* bg1  = (const float*)d_in[19];
    const float* Wg2  = (const float*)d_in[20];
    const float* bg2  = (const float*)d_in[21];
    const float* Wout = (const float*)d_in[22];
    const float* bout = (const float*)d_in[23];
    float* out = (float*)d_out;

    // workspace carve-up (~95 MB)
    char* p = (char*)d_ws;
    f16* Ahat = (f16*)p;              p += (size_t)NG * 256 * 256 * 2;   // 32 MB
    f16* WT   = (f16*)p;              p += (size_t)256 * KFLAT * 2;      // 8 MB
    f16* Wdpt = (f16*)p;              p += (size_t)KFLAT * ZD * 2;       // 4 MB
    f16* wb   = (f16*)p;              p += 65536;                        // 64 KB
    f16* zb   = (f16*)p;              p += 65536;                        // 64 KB
    f16* rawT = (f16*)p;              p += (size_t)NG * 16 * 256 * 2;    // 2 MB
    f16* h1t  = (f16*)p;              p += (size_t)NN * 64 * 2;          // 8 MB
    f16* h3t  = (f16*)p;              p += (size_t)NN * 64 * 2;
    f16* h4b  = (f16*)p;              p += (size_t)NN * 64 * 2;
    f16* latt = (f16*)p;              p += (size_t)NN * 64 * 2;
    float* part = (float*)p;          p += (size_t)64 * 65536 * 4;       // 16 MB

    // preprocessing (2 launches)
    k_graph_ahat<<<NG, 256, 0, stream>>>(src, dst, Ahat);
    k_prep<<<5504, 256, 0, stream>>>(raw, W1, W2, W3, W4, Wg2, Wg1, Wmu, Wlv, Wdec,
                                     rawT, wb, WT, Wdpt);

    // encoder (1 launch: conv1..conv4 fused)
    k_enc<<<NG, 1024, 0, stream>>>(rawT, Ahat, wb, b1, b2, b3, b4, h1t, h3t, h4b);

    // bottleneck: mu/logvar -> z -> latent
    k_mulv_mfma<<<1024, 256, 0, stream>>>(h4b, WT, part);
    k_reduce<<<128, 256, 0, stream>>>(part, bmu, blv, eps, out, zb);
    k_decgemm<<<512, 256, 0, stream>>>(zb, Wdpt, bdec, latt);

    // decoder (1 launch: catgemm + g1 + g2 + out GEMM fused)
    k_decfused<<<NG, 1024, 0, stream>>>(latt, rawT, h1t, h3t, Ahat, wb,
                                        bg1, bg2, Wout, bout, raw, out);
}